// Round 17
// baseline (554.891 us; speedup 1.0000x reference)
//
#include <hip/hip_runtime.h>
#include <cstddef>

#define B_SZ 8
#define N_PTS 1024
#define KNN_K 20
#define CAT_C 512
#define BN_EPS 1e-5f

typedef unsigned short u16;
typedef unsigned int u32;
typedef __bf16 bf16;
typedef __bf16 bf16x8 __attribute__((ext_vector_type(8)));
typedef float f32x4 __attribute__((ext_vector_type(4)));

// ---------------- transpose x (B,3,N) -> feat0 (B,N,4) (col 3 pre-zeroed) ----------------
__global__ __launch_bounds__(256) void transpose_x(const float* __restrict__ x,
                                                   float* __restrict__ feat0) {
  int t = blockIdx.x * 256 + threadIdx.x;
  if (t >= B_SZ * 3 * N_PTS) return;
  int b = t / (3 * N_PTS);
  int r = t - b * 3 * N_PTS;
  int c = r / N_PTS;
  int n = r - c * N_PTS;
  feat0[((size_t)(b * N_PTS + n)) * 4 + c] = x[t];
}

// ---------------- squared norms per point (exact fp32) ----------------
__global__ __launch_bounds__(256) void xnorm_kernel(const float* __restrict__ feat, int lda,
                                                    int C, float* __restrict__ x2) {
  int p = blockIdx.x * 256 + threadIdx.x;
  if (p >= 8192) return;
  const float* r = feat + (size_t)p * lda;
  float s = 0.f;
  for (int c = 0; c < C; c += 4) {
    float4 v = *(const float4*)(r + c);
    s = fmaf(v.x, v.x, s); s = fmaf(v.y, v.y, s);
    s = fmaf(v.z, v.z, s); s = fmaf(v.w, v.w, s);
  }
  x2[p] = s;
}

// ---------------- triple-split features into bf16 h/m/l, [8192][128] zero-padded --------
__global__ __launch_bounds__(256) void split_pack(const float* __restrict__ feat, int lda,
                                                  int C, bf16* __restrict__ packH,
                                                  bf16* __restrict__ packM,
                                                  bf16* __restrict__ packL) {
  int t = blockIdx.x * 256 + threadIdx.x;     // 8192*16 threads, 8 k's each
  if (t >= 8192 * 16) return;
  int p = t >> 4, k0 = (t & 15) * 8;
  bf16x8 h, m, l;
  #pragma unroll
  for (int e = 0; e < 8; ++e) {
    int k = k0 + e;
    float v = (k < C) ? feat[(size_t)p * lda + k] : 0.f;
    bf16 hb = (bf16)v;       float r1 = v - (float)hb;
    bf16 mb = (bf16)r1;      float r2 = r1 - (float)mb;
    bf16 lb = (bf16)r2;
    h[e] = hb; m[e] = mb; l[e] = lb;
  }
  *(bf16x8*)(packH + (size_t)p * 128 + k0) = h;
  *(bf16x8*)(packM + (size_t)p * 128 + k0) = m;
  *(bf16x8*)(packL + (size_t)p * 128 + k0) = l;
}

// ---- DPP u32-min reduce stage (identity 0x7fffffff), tree verified in R11/R13 ----
#define DPP_MIN_STAGE(CTRL)                                                          \
  {                                                                                  \
    int nb = __builtin_amdgcn_update_dpp((int)0x7fffffff, mc,                        \
                                         (CTRL), 0xF, 0xF, false);                   \
    mc = (nb < mc) ? nb : mc;                                                        \
  }

// ---------------- KNN: triple-split MFMA distances (R15/R16 passer) + radix select
// (R13 passer). Block = 1024 thr / 16 waves = 16 rows x 1024 cols; wave w owns cols
// w*64..+63 for MFMA (4 fragments) and row w for selection. Distances -> Ds (LDS),
// then each wave loads its row to registers; after a barrier the Ds region is reused
// for the per-wave 256-bin radix histogram + aux. Radix finds exact 20th-largest key
// T; emit all >T (order-free: downstream k-reductions commutative), then r smallest
// cols among ==T via DPP-min (exact jax top_k tie semantics).
__global__ __launch_bounds__(1024) void knn_mfma(const bf16* __restrict__ packH,
                                                 const bf16* __restrict__ packM,
                                                 const bf16* __restrict__ packL,
                                                 const float* __restrict__ x2,
                                                 int nks,
                                                 int* __restrict__ idxout) {
  __shared__ u16 Ah[16 * 128];        // 4KB each, row stride 256B, XOR-swizzled
  __shared__ u16 Am[16 * 128];
  __shared__ u16 Al[16 * 128];
  __shared__ float Ds[16 * 1028];     // 65.8KB; later reused: hist[16][256] + aux[16][8]
  int tid = threadIdx.x;
  int w = tid >> 6, lane = tid & 63;
  int row0 = blockIdx.x * 16;         // 512 blocks
  int b = row0 >> 10;

  if (tid < 256) {
    int r = tid >> 4;                 // 0..15
    int cc = (tid & 15) * 8;          // k: 0,8,...,120
    int byte = r * 256 + ((cc * 2) ^ ((r & 7) << 4));
    *(bf16x8*)((char*)Ah + byte) = *(const bf16x8*)(packH + (size_t)(row0 + r) * 128 + cc);
    *(bf16x8*)((char*)Am + byte) = *(const bf16x8*)(packM + (size_t)(row0 + r) * 128 + cc);
    *(bf16x8*)((char*)Al + byte) = *(const bf16x8*)(packL + (size_t)(row0 + r) * 128 + cc);
  }
  __syncthreads();

  int lrow = lane & 15, kgrp = lane >> 4;
  const bf16* bH = packH + (size_t)b * 1024 * 128;
  const bf16* bM = packM + (size_t)b * 1024 * 128;
  const bf16* bL = packL + (size_t)b * 1024 * 128;
  int abase = lrow * 256;

  f32x4 acc[4];
  #pragma unroll
  for (int f = 0; f < 4; ++f) acc[f] = (f32x4){0.f, 0.f, 0.f, 0.f};

  for (int ks = 0; ks < nks; ++ks) {
    int kb = (ks * 32 + kgrp * 8) * 2;
    int aoff = abase + (kb ^ ((lrow & 7) << 4));
    bf16x8 a_h = *(const bf16x8*)((const char*)Ah + aoff);
    bf16x8 a_m = *(const bf16x8*)((const char*)Am + aoff);
    bf16x8 a_l = *(const bf16x8*)((const char*)Al + aoff);
    int kbase = ks * 32 + kgrp * 8;
    #pragma unroll
    for (int f = 0; f < 4; ++f) {
      int col = w * 64 + f * 16 + lrow;
      bf16x8 b_h = *(const bf16x8*)(bH + (size_t)col * 128 + kbase);
      bf16x8 b_m = *(const bf16x8*)(bM + (size_t)col * 128 + kbase);
      bf16x8 b_l = *(const bf16x8*)(bL + (size_t)col * 128 + kbase);
      acc[f] = __builtin_amdgcn_mfma_f32_16x16x32_bf16(a_h, b_h, acc[f], 0, 0, 0);
      acc[f] = __builtin_amdgcn_mfma_f32_16x16x32_bf16(a_h, b_m, acc[f], 0, 0, 0);
      acc[f] = __builtin_amdgcn_mfma_f32_16x16x32_bf16(a_m, b_h, acc[f], 0, 0, 0);
      acc[f] = __builtin_amdgcn_mfma_f32_16x16x32_bf16(a_m, b_m, acc[f], 0, 0, 0);
      acc[f] = __builtin_amdgcn_mfma_f32_16x16x32_bf16(a_h, b_l, acc[f], 0, 0, 0);
      acc[f] = __builtin_amdgcn_mfma_f32_16x16x32_bf16(a_l, b_h, acc[f], 0, 0, 0);
      acc[f] = __builtin_amdgcn_mfma_f32_16x16x32_bf16(a_m, b_l, acc[f], 0, 0, 0);
      acc[f] = __builtin_amdgcn_mfma_f32_16x16x32_bf16(a_l, b_m, acc[f], 0, 0, 0);
    }
  }
  // D epilogue (m89-verified layout: row=(lane>>4)*4+r, col=lane&15)
  #pragma unroll
  for (int f = 0; f < 4; ++f) {
    int col = w * 64 + f * 16 + lrow;
    #pragma unroll
    for (int r = 0; r < 4; ++r)
      Ds[(kgrp * 4 + r) * 1028 + col] = acc[f][r];
  }
  __syncthreads();

  // load row w's distances to registers as monotone u32 keys (same fp expression
  // as all passing rounds; +0.0f canonicalizes -0)
  const float* x2b = x2 + b * N_PTS;
  int row = row0 + w;
  float x2n = x2[row];
  u32 uv[16];
  #pragma unroll
  for (int j = 0; j < 16; ++j) {
    float d = Ds[w * 1028 + j * 64 + lane];
    float v = ((2.f * d - x2n) - x2b[j * 64 + lane]) + 0.0f;
    u32 u = __float_as_uint(v);
    uv[j] = u ^ ((u32)(-(int)(u >> 31)) | 0x80000000u);
  }
  __syncthreads();   // all rows consumed -> Ds reusable as hist/aux

  // per-wave LDS slices inside Ds (disjoint; wave-synchronous, no barriers needed)
  u32* hist = (u32*)Ds + w * 256;            // 256 bins; slot g counts digit 255-g
  volatile u32* aux = (u32*)Ds + 16 * 256 + w * 8;  // [0]=emit cnt, [1]=digit, [2]=above

  u32 maskj = 0xFFFFu;
  int need = KNN_K;
  u32 T = 0;
  #pragma unroll
  for (int pass = 0; pass < 4; ++pass) {
    int shift = 24 - 8 * pass;
    hist[lane * 4 + 0] = 0; hist[lane * 4 + 1] = 0;
    hist[lane * 4 + 2] = 0; hist[lane * 4 + 3] = 0;
    #pragma unroll
    for (int j = 0; j < 16; ++j) {
      if (maskj & (1u << j)) {
        u32 d = (uv[j] >> shift) & 255u;
        atomicAdd(&hist[255u - d], 1u);
      }
    }
    u32 c0 = hist[lane * 4 + 0], c1 = hist[lane * 4 + 1];
    u32 c2 = hist[lane * 4 + 2], c3 = hist[lane * 4 + 3];
    u32 s = c0 + c1 + c2 + c3;
    u32 P = s;
    #pragma unroll
    for (int off2 = 1; off2 < 64; off2 <<= 1) {
      u32 t = (u32)__shfl_up((int)P, off2, 64);
      if (lane >= off2) P += t;
    }
    u32 E = P - s;
    if ((int)E < need && need <= (int)P) {
      u32 cum = E, dsel, above;
      if ((int)(cum + c0) >= need)                { dsel = 255u - (u32)(lane * 4 + 0); above = cum; }
      else if ((int)(cum + c0 + c1) >= need)      { dsel = 255u - (u32)(lane * 4 + 1); above = cum + c0; }
      else if ((int)(cum + c0 + c1 + c2) >= need) { dsel = 255u - (u32)(lane * 4 + 2); above = cum + c0 + c1; }
      else                                        { dsel = 255u - (u32)(lane * 4 + 3); above = cum + c0 + c1 + c2; }
      aux[1] = dsel; aux[2] = above;
    }
    u32 dstar = aux[1];
    u32 above = aux[2];
    need -= (int)above;
    T = (T << 8) | dstar;
    u32 nm = 0;
    #pragma unroll
    for (int j = 0; j < 16; ++j)
      if ((maskj & (1u << j)) && (((uv[j] >> shift) & 255u) == dstar)) nm |= (1u << j);
    maskj = nm;
  }

  // emit: all keys > T at atomic-assigned slots (order-free), then r smallest
  // cols among == T (exact top_k tie-break: smallest index first)
  if (lane == 0) aux[0] = 0;
  int base = row * KNN_K;
  #pragma unroll
  for (int j = 0; j < 16; ++j) {
    if (uv[j] > T) {
      u32 pos = atomicAdd((u32*)&aux[0], 1u);
      idxout[base + pos] = j * 64 + lane;
    }
  }
  int tieBase = KNN_K - need;
  int last = -1;
  for (int t = 0; t < need; ++t) {
    int mc = 0x7fffffff;
    #pragma unroll
    for (int j = 15; j >= 0; --j) {
      int col = j * 64 + lane;
      if (uv[j] == T && col > last) mc = col;
    }
    DPP_MIN_STAGE(0x111)
    DPP_MIN_STAGE(0x112)
    DPP_MIN_STAGE(0x114)
    DPP_MIN_STAGE(0x118)
    DPP_MIN_STAGE(0x142)
    DPP_MIN_STAGE(0x143)
    int wmin = __builtin_amdgcn_readlane(mc, 63);
    if (lane == 0) idxout[base + tieBase + t] = wmin;
    last = wmin;
  }
}

// ---------------- build combined weight Wc (fp32): [w1-w2 | w2], K=C rows x 2O cols ----------------
__global__ __launch_bounds__(256) void build_wc(const float* __restrict__ w, int C, int O,
                                                float* __restrict__ wc) {
  int t = blockIdx.x * 256 + threadIdx.x;
  int twoO = 2 * O;
  if (t >= C * twoO) return;
  int c = t / twoO, j = t - c * twoO;
  float v;
  if (j < O) v = w[j * (2 * C) + c] - w[j * (2 * C) + C + c];
  else       v = w[(j - O) * (2 * C) + C + c];
  wc[t] = v;
}

// ---------------- fp32 GEMM (edge layers): C[M,N] = A[M,K](lda) * B[K,N] ----------------
__global__ __launch_bounds__(256) void gemm_kernel(const float* __restrict__ A, int lda,
                                                   const float* __restrict__ Bm,
                                                   float* __restrict__ Cm,
                                                   int M, int N, int K) {
  __shared__ float As[16][64];
  __shared__ float Bs[16][68];
  int tx = threadIdx.x & 15, ty = threadIdx.x >> 4;
  int bn0 = blockIdx.x * 64, bm0 = blockIdx.y * 64;
  float acc[4][4];
  #pragma unroll
  for (int i = 0; i < 4; ++i)
    #pragma unroll
    for (int j = 0; j < 4; ++j) acc[i][j] = 0.f;

  for (int k0 = 0; k0 < K; k0 += 16) {
    {
      int t = threadIdx.x;
      int m = t >> 2, kb = (t & 3) * 4;
      const float* ap = A + (size_t)(bm0 + m) * lda + k0 + kb;
      #pragma unroll
      for (int i = 0; i < 4; ++i) As[kb + i][m] = (k0 + kb + i < K) ? ap[i] : 0.f;
      int r = t >> 4, c4 = (t & 15) * 4;
      float4 bv = make_float4(0.f, 0.f, 0.f, 0.f);
      if (k0 + r < K) bv = *(const float4*)(Bm + (size_t)(k0 + r) * N + bn0 + c4);
      *(float4*)&Bs[r][c4] = bv;
    }
    __syncthreads();
    #pragma unroll
    for (int k = 0; k < 16; ++k) {
      float a0[4];
      #pragma unroll
      for (int i = 0; i < 4; ++i) a0[i] = As[k][ty * 4 + i];
      float4 bv = *(const float4*)&Bs[k][tx * 4];
      float b0[4] = {bv.x, bv.y, bv.z, bv.w};
      #pragma unroll
      for (int i = 0; i < 4; ++i)
        #pragma unroll
        for (int j = 0; j < 4; ++j) acc[i][j] = fmaf(a0[i], b0[j], acc[i][j]);
    }
    __syncthreads();
  }
  #pragma unroll
  for (int i = 0; i < 4; ++i) {
    float4 v = make_float4(acc[i][0], acc[i][1], acc[i][2], acc[i][3]);
    *(float4*)(Cm + (size_t)(bm0 + ty * 4 + i) * N + bn0 + tx * 4) = v;
  }
}

// ---------------- split fp32 -> bf16 hi/lo MFMA GEMM for layer 5, fused reduction ----------------
__device__ inline void split8(const float* __restrict__ p, bf16x8* hv, bf16x8* lv) {
  float4 a0 = *(const float4*)p, a1 = *(const float4*)(p + 4);
  float v[8] = {a0.x, a0.y, a0.z, a0.w, a1.x, a1.y, a1.z, a1.w};
  bf16x8 h, l;
  #pragma unroll
  for (int j = 0; j < 8; ++j) {
    bf16 hj = (bf16)v[j];
    h[j] = hj;
    l[j] = (bf16)(v[j] - (float)hj);
  }
  *hv = h; *lv = l;
}

__global__ __launch_bounds__(256) void gemm_split_red(const float* __restrict__ A, int lda,
                                                      const float* __restrict__ Bt, int ldb,
                                                      float* __restrict__ parts, int K) {
  __shared__ u16 Ah[128 * 64];
  __shared__ u16 Al[128 * 64];
  __shared__ u16 Bh[128 * 64];
  __shared__ u16 Bl[128 * 64];
  int tid = threadIdx.x;
  int wave = tid >> 6, lane = tid & 63;
  int wr = wave >> 1, wc = wave & 1;
  int bn0 = blockIdx.x * 128, bm0 = blockIdx.y * 128;
  int lrow = lane & 15;
  int kgrp = lane >> 4;

  f32x4 acc[4][4];
  #pragma unroll
  for (int i = 0; i < 4; ++i)
    #pragma unroll
    for (int j = 0; j < 4; ++j) acc[i][j] = (f32x4){0.f, 0.f, 0.f, 0.f};

  for (int k0 = 0; k0 < K; k0 += 64) {
    #pragma unroll
    for (int i = 0; i < 4; ++i) {
      int chunk = tid + i * 256;
      int row = chunk >> 3;
      int cc = (chunk & 7) * 8;
      int byte = row * 128 + ((cc * 2) ^ ((row & 7) << 4));
      bf16x8 h, l;
      split8(A + (size_t)(bm0 + row) * lda + k0 + cc, &h, &l);
      *(bf16x8*)((char*)Ah + byte) = h;
      *(bf16x8*)((char*)Al + byte) = l;
      split8(Bt + (size_t)(bn0 + row) * ldb + k0 + cc, &h, &l);
      *(bf16x8*)((char*)Bh + byte) = h;
      *(bf16x8*)((char*)Bl + byte) = l;
    }
    __syncthreads();
    #pragma unroll
    for (int kk = 0; kk < 64; kk += 32) {
      int kb = (kk + kgrp * 8) * 2;
      bf16x8 afh[4], afl[4], bfh[4], bfl[4];
      #pragma unroll
      for (int f = 0; f < 4; ++f) {
        int arow = wr * 64 + f * 16 + lrow;
        int abyte = arow * 128 + (kb ^ ((arow & 7) << 4));
        afh[f] = *(const bf16x8*)((const char*)Ah + abyte);
        afl[f] = *(const bf16x8*)((const char*)Al + abyte);
        int brow = wc * 64 + f * 16 + lrow;
        int bbyte = brow * 128 + (kb ^ ((brow & 7) << 4));
        bfh[f] = *(const bf16x8*)((const char*)Bh + bbyte);
        bfl[f] = *(const bf16x8*)((const char*)Bl + bbyte);
      }
      #pragma unroll
      for (int fm = 0; fm < 4; ++fm)
        #pragma unroll
        for (int fn = 0; fn < 4; ++fn) {
          acc[fm][fn] = __builtin_amdgcn_mfma_f32_16x16x32_bf16(afh[fm], bfh[fn], acc[fm][fn], 0, 0, 0);
          acc[fm][fn] = __builtin_amdgcn_mfma_f32_16x16x32_bf16(afl[fm], bfh[fn], acc[fm][fn], 0, 0, 0);
          acc[fm][fn] = __builtin_amdgcn_mfma_f32_16x16x32_bf16(afh[fm], bfl[fn], acc[fm][fn], 0, 0, 0);
        }
    }
    __syncthreads();
  }

  float* scratch = (float*)Ah;
  int contrib = wr * 4 + kgrp;
  #pragma unroll
  for (int fn = 0; fn < 4; ++fn) {
    float mx = -3.4e38f, mn = 3.4e38f, s1 = 0.f, s2 = 0.f;
    #pragma unroll
    for (int fm = 0; fm < 4; ++fm)
      #pragma unroll
      for (int r = 0; r < 4; ++r) {
        float v = acc[fm][fn][r];
        mx = fmaxf(mx, v); mn = fminf(mn, v);
        s1 += v; s2 = fmaf(v, v, s2);
      }
    int col = wc * 64 + fn * 16 + lrow;
    float* sp = scratch + (contrib * 128 + col) * 4;
    sp[0] = mx; sp[1] = mn; sp[2] = s1; sp[3] = s2;
  }
  __syncthreads();
  if (tid < 128) {
    float mx = -3.4e38f, mn = 3.4e38f, s1 = 0.f, s2 = 0.f;
    #pragma unroll
    for (int c2 = 0; c2 < 8; ++c2) {
      const float* sp = scratch + (c2 * 128 + tid) * 4;
      mx = fmaxf(mx, sp[0]); mn = fminf(mn, sp[1]);
      s1 += sp[2]; s2 += sp[3];
    }
    size_t o = (size_t)blockIdx.y * 1024 + bn0 + tid;
    parts[o] = mx;
    parts[65536 + o] = mn;
    parts[131072 + o] = s1;
    parts[196608 + o] = s2;
  }
}

// ---------------- edge aggregation: h = a + y[idx]; max/min over k + channel sums ----------------
__global__ __launch_bounds__(256) void aggregate_kernel(const float* __restrict__ ay,
                                                        const int* __restrict__ idxb, int O,
                                                        float* __restrict__ mx,
                                                        float* __restrict__ mn,
                                                        float* __restrict__ sumsbin) {
  __shared__ float ls[2][256];
  for (int i = threadIdx.x; i < 512; i += 256) ((float*)ls)[i] = 0.f;
  __syncthreads();

  int warp = threadIdx.x >> 6, lane = threadIdx.x & 63;
  int pt = blockIdx.x * 4 + warp;
  int b = pt >> 10;
  int twoO = 2 * O;
  int U = O >> 6;
  const float* ayrow = ay + (size_t)pt * twoO;

  float av[4], s1[4], s2[4], vmx[4], vmn[4];
  for (int u = 0; u < U; ++u) {
    av[u] = ayrow[u * 64 + lane];
    s1[u] = 0.f; s2[u] = 0.f; vmx[u] = -3.4e38f; vmn[u] = 3.4e38f;
  }
  const int* ip = idxb + pt * KNN_K;
  for (int k = 0; k < KNN_K; ++k) {
    int j = ip[k];
    const float* yrow = ay + (size_t)(b * N_PTS + j) * twoO + O;
    for (int u = 0; u < U; ++u) {
      float v = av[u] + yrow[u * 64 + lane];
      s1[u] += v; s2[u] = fmaf(v, v, s2[u]);
      vmx[u] = fmaxf(vmx[u], v); vmn[u] = fminf(vmn[u], v);
    }
  }
  for (int u = 0; u < U; ++u) {
    int o = u * 64 + lane;
    mx[(size_t)pt * O + o] = vmx[u];
    mn[(size_t)pt * O + o] = vmn[u];
    atomicAdd(&ls[0][o], s1[u]);
    atomicAdd(&ls[1][o], s2[u]);
  }
  __syncthreads();
  int bin = blockIdx.x & 63;
  float* gb = sumsbin + (size_t)bin * 512;
  for (int o = threadIdx.x; o < O; o += 256) {
    atomicAdd(&gb[o], ls[0][o]);
    atomicAdd(&gb[256 + o], ls[1][o]);
  }
}

__global__ __launch_bounds__(256) void reduce_bins(const float* __restrict__ sumsbin,
                                                   float* __restrict__ sums, int O) {
  int o = threadIdx.x;
  if (o >= O) return;
  float a = 0.f, c = 0.f;
  for (int bin = 0; bin < 64; ++bin) {
    a += sumsbin[bin * 512 + o];
    c += sumsbin[bin * 512 + 256 + o];
  }
  sums[o] = a;
  sums[256 + o] = c;
}

// ---------------- finalize edge layer: BN + relu on (max or min depending on sign) ----------------
__global__ __launch_bounds__(256) void finalize_edge(const float* __restrict__ mx,
                                                     const float* __restrict__ mn,
                                                     const float* __restrict__ sums,
                                                     const float* __restrict__ g,
                                                     const float* __restrict__ beta,
                                                     int oshift,
                                                     float* __restrict__ outseg,
                                                     float cnt_inv) {
  int tid = blockIdx.x * 256 + threadIdx.x;
  int pt = tid >> oshift;
  int o = tid & ((1 << oshift) - 1);
  float s1 = sums[o], s2 = sums[256 + o];
  float mean = s1 * cnt_inv;
  float var = s2 * cnt_inv - mean * mean;
  float rstd = rsqrtf(var + BN_EPS);
  float sc = g[o] * rstd;
  float sel = (sc >= 0.f) ? mx[tid] : mn[tid];
  float v = (sel - mean) * sc + beta[o];
  outseg[(size_t)pt * CAT_C + o] = fmaxf(v, 0.f);
}

// ---------------- layer 5 finalize from tile partials ----------------
__global__ __launch_bounds__(256) void finalize5_fused(const float* __restrict__ parts,
                                                       const float* __restrict__ g,
                                                       const float* __restrict__ beta,
                                                       float* __restrict__ out) {
  int tid = blockIdx.x * 256 + threadIdx.x;
  int b = tid >> 10, o = tid & 1023;
  const float* pmx = parts;
  const float* pmn = parts + 65536;
  const float* ps1 = parts + 131072;
  const float* ps2 = parts + 196608;
  float s1 = 0.f, s2 = 0.f;
  for (int t = 0; t < 64; ++t) { s1 += ps1[t * 1024 + o]; s2 += ps2[t * 1024 + o]; }
  float mx = -3.4e38f, mn = 3.4e38f;
  #pragma unroll
  for (int t = 0; t < 8; ++t) {
    mx = fmaxf(mx, pmx[(b * 8 + t) * 1024 + o]);
    mn = fminf(mn, pmn[(b * 8 + t) * 1024 + o]);
  }
  float mean = s1 * (1.0f / 8192.0f);
  float var = s2 * (1.0f / 8192.0f) - mean * mean;
  float rstd = rsqrtf(var + BN_EPS);
  float sc = g[o] * rstd;
  float sel = (sc >= 0.f) ? mx : mn;
  float v = (sel - mean) * sc + beta[o];
  out[tid] = fmaxf(v, 0.f);
}

extern "C" void kernel_launch(void* const* d_in, const int* in_sizes, int n_in,
                              void* d_out, int out_size, void* d_ws, size_t ws_size,
                              hipStream_t stream) {
  const float* x = (const float*)d_in[0];
  const float* w[5]  = {(const float*)d_in[1], (const float*)d_in[4], (const float*)d_in[7],
                        (const float*)d_in[10], (const float*)d_in[13]};
  const float* gg[5] = {(const float*)d_in[2], (const float*)d_in[5], (const float*)d_in[8],
                        (const float*)d_in[11], (const float*)d_in[14]};
  const float* bb[5] = {(const float*)d_in[3], (const float*)d_in[6], (const float*)d_in[9],
                        (const float*)d_in[12], (const float*)d_in[15]};
  float* out = (float*)d_out;

  float* W = (float*)d_ws;
  size_t off = 0;
  float* feat0   = W + off; off += (size_t)B_SZ * N_PTS * 4;   // stride-4 padded
  float* catbuf  = W + off; off += (size_t)8192 * CAT_C;
  int*   idxbuf  = (int*)(W + off); off += (size_t)8192 * KNN_K;
  float* aybuf   = W + off; off += (size_t)8192 * 1024;
  float* mxbuf   = W + off; off += (size_t)8192 * 256;
  float* mnbuf   = W + off; off += (size_t)8192 * 256;
  float* wcbuf   = W + off; off += (size_t)512 * 1024;
  float* sumsbin = W + off; off += (size_t)64 * 512;
  float* sums    = W + off; off += 512;
  float* parts   = W + off; off += (size_t)4 * 64 * 1024;
  float* x2buf   = W + off; off += 8192;
  bf16*  packH   = (bf16*)(W + off); off += (size_t)8192 * 128 / 2;   // 2MB
  bf16*  packM   = (bf16*)(W + off); off += (size_t)8192 * 128 / 2;   // 2MB
  bf16*  packL   = (bf16*)(W + off); off += (size_t)8192 * 128 / 2;   // 2MB

  hipMemsetAsync(feat0, 0, (size_t)B_SZ * N_PTS * 4 * sizeof(float), stream);
  transpose_x<<<(B_SZ * 3 * N_PTS + 255) / 256, 256, 0, stream>>>(x, feat0);

  const int Cs[4] = {4, 64, 64, 128};   // layer-0 padded to 4 (pad=0, values unchanged)
  const int Ks[4] = {3, 64, 64, 128};   // true K for the edge GEMM
  const int Os[4] = {64, 64, 128, 256};
  const int osh[4] = {6, 6, 7, 8};
  const int segin[4] = {0, 0, 64, 128};
  const int segout[4] = {0, 64, 128, 256};

  for (int l = 0; l < 4; ++l) {
    int C = Cs[l], O = Os[l], twoO = 2 * O;
    const float* featin = (l == 0) ? feat0 : (catbuf + segin[l]);
    int lda = (l == 0) ? 4 : CAT_C;
    int nks = (C + 31) / 32;            // 1,2,2,4

    xnorm_kernel<<<32, 256, 0, stream>>>(featin, lda, C, x2buf);
    split_pack<<<512, 256, 0, stream>>>(featin, lda, C, packH, packM, packL);
    knn_mfma<<<512, 1024, 0, stream>>>(packH, packM, packL, x2buf, nks, idxbuf);

    build_wc<<<(Ks[l] * twoO + 255) / 256, 256, 0, stream>>>(w[l], Ks[l], O, wcbuf);
    gemm_kernel<<<dim3(twoO / 64, 8192 / 64), 256, 0, stream>>>(featin, lda, wcbuf, aybuf,
                                                                8192, twoO, Ks[l]);
    hipMemsetAsync(sumsbin, 0, (size_t)64 * 512 * sizeof(float), stream);
    aggregate_kernel<<<2048, 256, 0, stream>>>(aybuf, idxbuf, O, mxbuf, mnbuf, sumsbin);
    reduce_bins<<<1, 256, 0, stream>>>(sumsbin, sums, O);
    finalize_edge<<<(8192 * O) / 256, 256, 0, stream>>>(mxbuf, mnbuf, sums, gg[l], bb[l],
                                                        osh[l], catbuf + segout[l],
                                                        1.0f / (8192.0f * KNN_K));
  }

  // layer 5: h5 = cat * w5^T via split-bf16 MFMA with fused per-tile reduction
  gemm_split_red<<<dim3(1024 / 128, 8192 / 128), 256, 0, stream>>>(catbuf, CAT_C, w[4], 512,
                                                                   parts, 512);
  finalize5_fused<<<8192 / 256, 256, 0, stream>>>(parts, gg[4], bb[4], out);
}

// Round 18
// 486.179 us; speedup vs baseline: 1.1413x; 1.1413x over previous
//
#include <hip/hip_runtime.h>
#include <cstddef>

#define B_SZ 8
#define N_PTS 1024
#define KNN_K 20
#define CAT_C 512
#define BN_EPS 1e-5f

typedef unsigned short u16;
typedef unsigned int u32;
typedef __bf16 bf16;
typedef __bf16 bf16x8 __attribute__((ext_vector_type(8)));
typedef float f32x4 __attribute__((ext_vector_type(4)));

// ---------------- transpose x (B,3,N) -> feat0 (B,N,4) (col 3 pre-zeroed) ----------------
__global__ __launch_bounds__(256) void transpose_x(const float* __restrict__ x,
                                                   float* __restrict__ feat0) {
  int t = blockIdx.x * 256 + threadIdx.x;
  if (t >= B_SZ * 3 * N_PTS) return;
  int b = t / (3 * N_PTS);
  int r = t - b * 3 * N_PTS;
  int c = r / N_PTS;
  int n = r - c * N_PTS;
  feat0[((size_t)(b * N_PTS + n)) * 4 + c] = x[t];
}

// ---------------- squared norms per point (exact fp32) ----------------
__global__ __launch_bounds__(256) void xnorm_kernel(const float* __restrict__ feat, int lda,
                                                    int C, float* __restrict__ x2) {
  int p = blockIdx.x * 256 + threadIdx.x;
  if (p >= 8192) return;
  const float* r = feat + (size_t)p * lda;
  float s = 0.f;
  for (int c = 0; c < C; c += 4) {
    float4 v = *(const float4*)(r + c);
    s = fmaf(v.x, v.x, s); s = fmaf(v.y, v.y, s);
    s = fmaf(v.z, v.z, s); s = fmaf(v.w, v.w, s);
  }
  x2[p] = s;
}

// ---------------- triple-split features, B-coalesced layout --------------------------
// pack[( (b*16 + q) * 1024 + col ) * 8 + e] = feat value at point (b,col), k = q*8+e
// (zero-padded past C). q = ks*4 + kgrp, so an MFMA wave's B-fragment load is 16
// consecutive cols x 16B = 256B contiguous per (f, kgrp) group.
__global__ __launch_bounds__(256) void split_pack(const float* __restrict__ feat, int lda,
                                                  int C, bf16* __restrict__ packH,
                                                  bf16* __restrict__ packM,
                                                  bf16* __restrict__ packL) {
  int t = blockIdx.x * 256 + threadIdx.x;     // 8192*16 threads, 8 k's each
  if (t >= 8192 * 16) return;
  int p = t >> 4, c = t & 15;                 // p = global point, c = q plane
  int b = p >> 10, col = p & 1023;
  int k0 = c * 8;
  bf16x8 h, m, l;
  #pragma unroll
  for (int e = 0; e < 8; ++e) {
    int k = k0 + e;
    float v = (k < C) ? feat[(size_t)p * lda + k] : 0.f;
    bf16 hb = (bf16)v;       float r1 = v - (float)hb;
    bf16 mb = (bf16)r1;      float r2 = r1 - (float)mb;
    bf16 lb = (bf16)r2;
    h[e] = hb; m[e] = mb; l[e] = lb;
  }
  size_t dst = ((size_t)(b * 16 + c) * 1024 + col) * 8;
  *(bf16x8*)(packH + dst) = h;
  *(bf16x8*)(packM + dst) = m;
  *(bf16x8*)(packL + dst) = l;
}

// ---- DPP value-reduce stages (tree verified bit-exact in R10/R11/R16) ----
#define DPP_MAX_STAGE(CTRL)                                                          \
  {                                                                                  \
    int nb = __builtin_amdgcn_update_dpp((int)0xFF800000, __float_as_int(mx),        \
                                         (CTRL), 0xF, 0xF, false);                   \
    mx = fmaxf(mx, __int_as_float(nb));                                              \
  }
#define DPP_MIN_STAGE(CTRL)                                                          \
  {                                                                                  \
    int nb = __builtin_amdgcn_update_dpp((int)0x7fffffff, mc,                        \
                                         (CTRL), 0xF, 0xF, false);                   \
    mc = (nb < mc) ? nb : mc;                                                        \
  }

// ---------------- KNN: triple-split MFMA distances + R16 DPP selection ----------------
// Block = 1024 thr / 16 waves = 16 rows x 1024 cols; wave w owns cols w*64..+63 for
// MFMA (4 fragments) and row w for selection. B loads now fully coalesced (256B
// contiguous per 16-lane group) via the [b][q][col] pack layout — R17's scatter
// cost 4x HBM over-fetch (FETCH 24.8MB vs 6MB of packs). Selection = R16 passer
// (deterministic; R17 radix showed a 40ms outlier = replay-fragile).
__global__ __launch_bounds__(1024) void knn_mfma(const bf16* __restrict__ packH,
                                                 const bf16* __restrict__ packM,
                                                 const bf16* __restrict__ packL,
                                                 const float* __restrict__ x2,
                                                 int nks,
                                                 int* __restrict__ idxout) {
  __shared__ u16 Ah[16 * 128];        // 4KB each, row stride 256B, XOR-swizzled
  __shared__ u16 Am[16 * 128];
  __shared__ u16 Al[16 * 128];
  __shared__ float Ds[16 * 1028];     // 65.8KB, padded stride
  int tid = threadIdx.x;
  int w = tid >> 6, lane = tid & 63;
  int row0 = blockIdx.x * 16;         // 512 blocks
  int b = row0 >> 10;
  int col0 = row0 & 1023;             // local point index of this block's rows

  if (tid < 256) {
    int r = tid >> 4, c = tid & 15;   // c = q plane
    int byte = r * 256 + ((c * 16) ^ ((r & 7) << 4));
    size_t src = ((size_t)(b * 16 + c) * 1024 + col0 + r) * 8;
    *(bf16x8*)((char*)Ah + byte) = *(const bf16x8*)(packH + src);
    *(bf16x8*)((char*)Am + byte) = *(const bf16x8*)(packM + src);
    *(bf16x8*)((char*)Al + byte) = *(const bf16x8*)(packL + src);
  }
  __syncthreads();

  int lrow = lane & 15, kgrp = lane >> 4;
  int abase = lrow * 256;

  f32x4 acc[4];
  #pragma unroll
  for (int f = 0; f < 4; ++f) acc[f] = (f32x4){0.f, 0.f, 0.f, 0.f};

  for (int ks = 0; ks < nks; ++ks) {
    int kb = (ks * 32 + kgrp * 8) * 2;
    int aoff = abase + (kb ^ ((lrow & 7) << 4));
    bf16x8 a_h = *(const bf16x8*)((const char*)Ah + aoff);
    bf16x8 a_m = *(const bf16x8*)((const char*)Am + aoff);
    bf16x8 a_l = *(const bf16x8*)((const char*)Al + aoff);
    int q = ks * 4 + kgrp;
    size_t pbase = (size_t)(b * 16 + q) * 1024;
    #pragma unroll
    for (int f = 0; f < 4; ++f) {
      int col = w * 64 + f * 16 + lrow;
      bf16x8 b_h = *(const bf16x8*)(packH + (pbase + col) * 8);
      bf16x8 b_m = *(const bf16x8*)(packM + (pbase + col) * 8);
      bf16x8 b_l = *(const bf16x8*)(packL + (pbase + col) * 8);
      acc[f] = __builtin_amdgcn_mfma_f32_16x16x32_bf16(a_h, b_h, acc[f], 0, 0, 0);
      acc[f] = __builtin_amdgcn_mfma_f32_16x16x32_bf16(a_h, b_m, acc[f], 0, 0, 0);
      acc[f] = __builtin_amdgcn_mfma_f32_16x16x32_bf16(a_m, b_h, acc[f], 0, 0, 0);
      acc[f] = __builtin_amdgcn_mfma_f32_16x16x32_bf16(a_m, b_m, acc[f], 0, 0, 0);
      acc[f] = __builtin_amdgcn_mfma_f32_16x16x32_bf16(a_h, b_l, acc[f], 0, 0, 0);
      acc[f] = __builtin_amdgcn_mfma_f32_16x16x32_bf16(a_l, b_h, acc[f], 0, 0, 0);
      acc[f] = __builtin_amdgcn_mfma_f32_16x16x32_bf16(a_m, b_l, acc[f], 0, 0, 0);
      acc[f] = __builtin_amdgcn_mfma_f32_16x16x32_bf16(a_l, b_m, acc[f], 0, 0, 0);
    }
  }
  // D epilogue (m89-verified layout: row=(lane>>4)*4+r, col=lane&15)
  #pragma unroll
  for (int f = 0; f < 4; ++f) {
    int col = w * 64 + f * 16 + lrow;
    #pragma unroll
    for (int r = 0; r < 4; ++r)
      Ds[(kgrp * 4 + r) * 1028 + col] = acc[f][r];
  }
  __syncthreads();

  // selection: wave w handles row w (R16 passer, verbatim semantics)
  const float* x2b = x2 + b * N_PTS;
  int row = row0 + w;
  float x2n = x2[row];
  float accv[16];
  #pragma unroll
  for (int j = 0; j < 16; ++j) {
    float d = Ds[w * 1028 + j * 64 + lane];
    accv[j] = (2.f * d - x2n) - x2b[j * 64 + lane];
  }

  for (int rr = 0; rr < KNN_K; ++rr) {
    float m01 = fmaxf(accv[0], accv[1]),   m23 = fmaxf(accv[2], accv[3]);
    float m45 = fmaxf(accv[4], accv[5]),   m67 = fmaxf(accv[6], accv[7]);
    float m89 = fmaxf(accv[8], accv[9]),   mab = fmaxf(accv[10], accv[11]);
    float mcd = fmaxf(accv[12], accv[13]), mef = fmaxf(accv[14], accv[15]);
    float mx = fmaxf(fmaxf(fmaxf(m01, m23), fmaxf(m45, m67)),
                     fmaxf(fmaxf(m89, mab), fmaxf(mcd, mef)));
    DPP_MAX_STAGE(0x111)
    DPP_MAX_STAGE(0x112)
    DPP_MAX_STAGE(0x114)
    DPP_MAX_STAGE(0x118)
    DPP_MAX_STAGE(0x142)
    DPP_MAX_STAGE(0x143)
    mx = __int_as_float(__builtin_amdgcn_readlane(__float_as_int(mx), 63));

    int jloc = 16;
    #pragma unroll
    for (int j = 15; j >= 0; --j)
      if (accv[j] == mx) jloc = j;
    int mc = (jloc < 16) ? ((jloc << 6) | lane) : 0x7fffffff;
    DPP_MIN_STAGE(0x111)
    DPP_MIN_STAGE(0x112)
    DPP_MIN_STAGE(0x114)
    DPP_MIN_STAGE(0x118)
    DPP_MIN_STAGE(0x142)
    DPP_MIN_STAGE(0x143)
    int si = __builtin_amdgcn_readlane(mc, 63);

    int jj = si >> 6, ln = si & 63;
    bool isln = (lane == ln);
    #pragma unroll
    for (int j = 0; j < 16; ++j)
      if (j == jj && isln) accv[j] = -3.4e38f;
    if (lane == 0) idxout[row * KNN_K + rr] = si;
  }
}

// ---------------- build combined weight Wc (fp32): [w1-w2 | w2], K=C rows x 2O cols ----------------
__global__ __launch_bounds__(256) void build_wc(const float* __restrict__ w, int C, int O,
                                                float* __restrict__ wc) {
  int t = blockIdx.x * 256 + threadIdx.x;
  int twoO = 2 * O;
  if (t >= C * twoO) return;
  int c = t / twoO, j = t - c * twoO;
  float v;
  if (j < O) v = w[j * (2 * C) + c] - w[j * (2 * C) + C + c];
  else       v = w[(j - O) * (2 * C) + C + c];
  wc[t] = v;
}

// ---------------- fp32 GEMM (edge layers): C[M,N] = A[M,K](lda) * B[K,N] ----------------
__global__ __launch_bounds__(256) void gemm_kernel(const float* __restrict__ A, int lda,
                                                   const float* __restrict__ Bm,
                                                   float* __restrict__ Cm,
                                                   int M, int N, int K) {
  __shared__ float As[16][64];
  __shared__ float Bs[16][68];
  int tx = threadIdx.x & 15, ty = threadIdx.x >> 4;
  int bn0 = blockIdx.x * 64, bm0 = blockIdx.y * 64;
  float acc[4][4];
  #pragma unroll
  for (int i = 0; i < 4; ++i)
    #pragma unroll
    for (int j = 0; j < 4; ++j) acc[i][j] = 0.f;

  for (int k0 = 0; k0 < K; k0 += 16) {
    {
      int t = threadIdx.x;
      int m = t >> 2, kb = (t & 3) * 4;
      const float* ap = A + (size_t)(bm0 + m) * lda + k0 + kb;
      #pragma unroll
      for (int i = 0; i < 4; ++i) As[kb + i][m] = (k0 + kb + i < K) ? ap[i] : 0.f;
      int r = t >> 4, c4 = (t & 15) * 4;
      float4 bv = make_float4(0.f, 0.f, 0.f, 0.f);
      if (k0 + r < K) bv = *(const float4*)(Bm + (size_t)(k0 + r) * N + bn0 + c4);
      *(float4*)&Bs[r][c4] = bv;
    }
    __syncthreads();
    #pragma unroll
    for (int k = 0; k < 16; ++k) {
      float a0[4];
      #pragma unroll
      for (int i = 0; i < 4; ++i) a0[i] = As[k][ty * 4 + i];
      float4 bv = *(const float4*)&Bs[k][tx * 4];
      float b0[4] = {bv.x, bv.y, bv.z, bv.w};
      #pragma unroll
      for (int i = 0; i < 4; ++i)
        #pragma unroll
        for (int j = 0; j < 4; ++j) acc[i][j] = fmaf(a0[i], b0[j], acc[i][j]);
    }
    __syncthreads();
  }
  #pragma unroll
  for (int i = 0; i < 4; ++i) {
    float4 v = make_float4(acc[i][0], acc[i][1], acc[i][2], acc[i][3]);
    *(float4*)(Cm + (size_t)(bm0 + ty * 4 + i) * N + bn0 + tx * 4) = v;
  }
}

// ---------------- split fp32 -> bf16 hi/lo MFMA GEMM for layer 5, fused reduction ----------------
__device__ inline void split8(const float* __restrict__ p, bf16x8* hv, bf16x8* lv) {
  float4 a0 = *(const float4*)p, a1 = *(const float4*)(p + 4);
  float v[8] = {a0.x, a0.y, a0.z, a0.w, a1.x, a1.y, a1.z, a1.w};
  bf16x8 h, l;
  #pragma unroll
  for (int j = 0; j < 8; ++j) {
    bf16 hj = (bf16)v[j];
    h[j] = hj;
    l[j] = (bf16)(v[j] - (float)hj);
  }
  *hv = h; *lv = l;
}

__global__ __launch_bounds__(256) void gemm_split_red(const float* __restrict__ A, int lda,
                                                      const float* __restrict__ Bt, int ldb,
                                                      float* __restrict__ parts, int K) {
  __shared__ u16 Ah[128 * 64];
  __shared__ u16 Al[128 * 64];
  __shared__ u16 Bh[128 * 64];
  __shared__ u16 Bl[128 * 64];
  int tid = threadIdx.x;
  int wave = tid >> 6, lane = tid & 63;
  int wr = wave >> 1, wc = wave & 1;
  int bn0 = blockIdx.x * 128, bm0 = blockIdx.y * 128;
  int lrow = lane & 15;
  int kgrp = lane >> 4;

  f32x4 acc[4][4];
  #pragma unroll
  for (int i = 0; i < 4; ++i)
    #pragma unroll
    for (int j = 0; j < 4; ++j) acc[i][j] = (f32x4){0.f, 0.f, 0.f, 0.f};

  for (int k0 = 0; k0 < K; k0 += 64) {
    #pragma unroll
    for (int i = 0; i < 4; ++i) {
      int chunk = tid + i * 256;
      int row = chunk >> 3;
      int cc = (chunk & 7) * 8;
      int byte = row * 128 + ((cc * 2) ^ ((row & 7) << 4));
      bf16x8 h, l;
      split8(A + (size_t)(bm0 + row) * lda + k0 + cc, &h, &l);
      *(bf16x8*)((char*)Ah + byte) = h;
      *(bf16x8*)((char*)Al + byte) = l;
      split8(Bt + (size_t)(bn0 + row) * ldb + k0 + cc, &h, &l);
      *(bf16x8*)((char*)Bh + byte) = h;
      *(bf16x8*)((char*)Bl + byte) = l;
    }
    __syncthreads();
    #pragma unroll
    for (int kk = 0; kk < 64; kk += 32) {
      int kb = (kk + kgrp * 8) * 2;
      bf16x8 afh[4], afl[4], bfh[4], bfl[4];
      #pragma unroll
      for (int f = 0; f < 4; ++f) {
        int arow = wr * 64 + f * 16 + lrow;
        int abyte = arow * 128 + (kb ^ ((arow & 7) << 4));
        afh[f] = *(const bf16x8*)((const char*)Ah + abyte);
        afl[f] = *(const bf16x8*)((const char*)Al + abyte);
        int brow = wc * 64 + f * 16 + lrow;
        int bbyte = brow * 128 + (kb ^ ((brow & 7) << 4));
        bfh[f] = *(const bf16x8*)((const char*)Bh + bbyte);
        bfl[f] = *(const bf16x8*)((const char*)Bl + bbyte);
      }
      #pragma unroll
      for (int fm = 0; fm < 4; ++fm)
        #pragma unroll
        for (int fn = 0; fn < 4; ++fn) {
          acc[fm][fn] = __builtin_amdgcn_mfma_f32_16x16x32_bf16(afh[fm], bfh[fn], acc[fm][fn], 0, 0, 0);
          acc[fm][fn] = __builtin_amdgcn_mfma_f32_16x16x32_bf16(afl[fm], bfh[fn], acc[fm][fn], 0, 0, 0);
          acc[fm][fn] = __builtin_amdgcn_mfma_f32_16x16x32_bf16(afh[fm], bfl[fn], acc[fm][fn], 0, 0, 0);
        }
    }
    __syncthreads();
  }

  float* scratch = (float*)Ah;
  int contrib = wr * 4 + kgrp;
  #pragma unroll
  for (int fn = 0; fn < 4; ++fn) {
    float mx = -3.4e38f, mn = 3.4e38f, s1 = 0.f, s2 = 0.f;
    #pragma unroll
    for (int fm = 0; fm < 4; ++fm)
      #pragma unroll
      for (int r = 0; r < 4; ++r) {
        float v = acc[fm][fn][r];
        mx = fmaxf(mx, v); mn = fminf(mn, v);
        s1 += v; s2 = fmaf(v, v, s2);
      }
    int col = wc * 64 + fn * 16 + lrow;
    float* sp = scratch + (contrib * 128 + col) * 4;
    sp[0] = mx; sp[1] = mn; sp[2] = s1; sp[3] = s2;
  }
  __syncthreads();
  if (tid < 128) {
    float mx = -3.4e38f, mn = 3.4e38f, s1 = 0.f, s2 = 0.f;
    #pragma unroll
    for (int c2 = 0; c2 < 8; ++c2) {
      const float* sp = scratch + (c2 * 128 + tid) * 4;
      mx = fmaxf(mx, sp[0]); mn = fminf(mn, sp[1]);
      s1 += sp[2]; s2 += sp[3];
    }
    size_t o = (size_t)blockIdx.y * 1024 + bn0 + tid;
    parts[o] = mx;
    parts[65536 + o] = mn;
    parts[131072 + o] = s1;
    parts[196608 + o] = s2;
  }
}

// ---------------- edge aggregation: h = a + y[idx]; max/min over k + channel sums ----------------
__global__ __launch_bounds__(256) void aggregate_kernel(const float* __restrict__ ay,
                                                        const int* __restrict__ idxb, int O,
                                                        float* __restrict__ mx,
                                                        float* __restrict__ mn,
                                                        float* __restrict__ sumsbin) {
  __shared__ float ls[2][256];
  for (int i = threadIdx.x; i < 512; i += 256) ((float*)ls)[i] = 0.f;
  __syncthreads();

  int warp = threadIdx.x >> 6, lane = threadIdx.x & 63;
  int pt = blockIdx.x * 4 + warp;
  int b = pt >> 10;
  int twoO = 2 * O;
  int U = O >> 6;
  const float* ayrow = ay + (size_t)pt * twoO;

  float av[4], s1[4], s2[4], vmx[4], vmn[4];
  for (int u = 0; u < U; ++u) {
    av[u] = ayrow[u * 64 + lane];
    s1[u] = 0.f; s2[u] = 0.f; vmx[u] = -3.4e38f; vmn[u] = 3.4e38f;
  }
  const int* ip = idxb + pt * KNN_K;
  for (int k = 0; k < KNN_K; ++k) {
    int j = ip[k];
    const float* yrow = ay + (size_t)(b * N_PTS + j) * twoO + O;
    for (int u = 0; u < U; ++u) {
      float v = av[u] + yrow[u * 64 + lane];
      s1[u] += v; s2[u] = fmaf(v, v, s2[u]);
      vmx[u] = fmaxf(vmx[u], v); vmn[u] = fminf(vmn[u], v);
    }
  }
  for (int u = 0; u < U; ++u) {
    int o = u * 64 + lane;
    mx[(size_t)pt * O + o] = vmx[u];
    mn[(size_t)pt * O + o] = vmn[u];
    atomicAdd(&ls[0][o], s1[u]);
    atomicAdd(&ls[1][o], s2[u]);
  }
  __syncthreads();
  int bin = blockIdx.x & 63;
  float* gb = sumsbin + (size_t)bin * 512;
  for (int o = threadIdx.x; o < O; o += 256) {
    atomicAdd(&gb[o], ls[0][o]);
    atomicAdd(&gb[256 + o], ls[1][o]);
  }
}

__global__ __launch_bounds__(256) void reduce_bins(const float* __restrict__ sumsbin,
                                                   float* __restrict__ sums, int O) {
  int o = threadIdx.x;
  if (o >= O) return;
  float a = 0.f, c = 0.f;
  for (int bin = 0; bin < 64; ++bin) {
    a += sumsbin[bin * 512 + o];
    c += sumsbin[bin * 512 + 256 + o];
  }
  sums[o] = a;
  sums[256 + o] = c;
}

// ---------------- finalize edge layer: BN + relu on (max or min depending on sign) ----------------
__global__ __launch_bounds__(256) void finalize_edge(const float* __restrict__ mx,
                                                     const float* __restrict__ mn,
                                                     const float* __restrict__ sums,
                                                     const float* __restrict__ g,
                                                     const float* __restrict__ beta,
                                                     int oshift,
                                                     float* __restrict__ outseg,
                                                     float cnt_inv) {
  int tid = blockIdx.x * 256 + threadIdx.x;
  int pt = tid >> oshift;
  int o = tid & ((1 << oshift) - 1);
  float s1 = sums[o], s2 = sums[256 + o];
  float mean = s1 * cnt_inv;
  float var = s2 * cnt_inv - mean * mean;
  float rstd = rsqrtf(var + BN_EPS);
  float sc = g[o] * rstd;
  float sel = (sc >= 0.f) ? mx[tid] : mn[tid];
  float v = (sel - mean) * sc + beta[o];
  outseg[(size_t)pt * CAT_C + o] = fmaxf(v, 0.f);
}

// ---------------- layer 5 finalize from tile partials ----------------
__global__ __launch_bounds__(256) void finalize5_fused(const float* __restrict__ parts,
                                                       const float* __restrict__ g,
                                                       const float* __restrict__ beta,
                                                       float* __restrict__ out) {
  int tid = blockIdx.x * 256 + threadIdx.x;
  int b = tid >> 10, o = tid & 1023;
  const float* pmx = parts;
  const float* pmn = parts + 65536;
  const float* ps1 = parts + 131072;
  const float* ps2 = parts + 196608;
  float s1 = 0.f, s2 = 0.f;
  for (int t = 0; t < 64; ++t) { s1 += ps1[t * 1024 + o]; s2 += ps2[t * 1024 + o]; }
  float mx = -3.4e38f, mn = 3.4e38f;
  #pragma unroll
  for (int t = 0; t < 8; ++t) {
    mx = fmaxf(mx, pmx[(b * 8 + t) * 1024 + o]);
    mn = fminf(mn, pmn[(b * 8 + t) * 1024 + o]);
  }
  float mean = s1 * (1.0f / 8192.0f);
  float var = s2 * (1.0f / 8192.0f) - mean * mean;
  float rstd = rsqrtf(var + BN_EPS);
  float sc = g[o] * rstd;
  float sel = (sc >= 0.f) ? mx : mn;
  float v = (sel - mean) * sc + beta[o];
  out[tid] = fmaxf(v, 0.f);
}

extern "C" void kernel_launch(void* const* d_in, const int* in_sizes, int n_in,
                              void* d_out, int out_size, void* d_ws, size_t ws_size,
                              hipStream_t stream) {
  const float* x = (const float*)d_in[0];
  const float* w[5]  = {(const float*)d_in[1], (const float*)d_in[4], (const float*)d_in[7],
                        (const float*)d_in[10], (const float*)d_in[13]};
  const float* gg[5] = {(const float*)d_in[2], (const float*)d_in[5], (const float*)d_in[8],
                        (const float*)d_in[11], (const float*)d_in[14]};
  const float* bb[5] = {(const float*)d_in[3], (const float*)d_in[6], (const float*)d_in[9],
                        (const float*)d_in[12], (const float*)d_in[15]};
  float* out = (float*)d_out;

  float* W = (float*)d_ws;
  size_t off = 0;
  float* feat0   = W + off; off += (size_t)B_SZ * N_PTS * 4;   // stride-4 padded
  float* catbuf  = W + off; off += (size_t)8192 * CAT_C;
  int*   idxbuf  = (int*)(W + off); off += (size_t)8192 * KNN_K;
  float* aybuf   = W + off; off += (size_t)8192 * 1024;
  float* mxbuf   = W + off; off += (size_t)8192 * 256;
  float* mnbuf   = W + off; off += (size_t)8192 * 256;
  float* wcbuf   = W + off; off += (size_t)512 * 1024;
  float* sumsbin = W + off; off += (size_t)64 * 512;
  float* sums    = W + off; off += 512;
  float* parts   = W + off; off += (size_t)4 * 64 * 1024;
  float* x2buf   = W + off; off += 8192;
  bf16*  packH   = (bf16*)(W + off); off += (size_t)8192 * 128 / 2;   // 2MB
  bf16*  packM   = (bf16*)(W + off); off += (size_t)8192 * 128 / 2;   // 2MB
  bf16*  packL   = (bf16*)(W + off); off += (size_t)8192 * 128 / 2;   // 2MB

  hipMemsetAsync(feat0, 0, (size_t)B_SZ * N_PTS * 4 * sizeof(float), stream);
  transpose_x<<<(B_SZ * 3 * N_PTS + 255) / 256, 256, 0, stream>>>(x, feat0);

  const int Cs[4] = {4, 64, 64, 128};   // layer-0 padded to 4 (pad=0, values unchanged)
  const int Ks[4] = {3, 64, 64, 128};   // true K for the edge GEMM
  const int Os[4] = {64, 64, 128, 256};
  const int osh[4] = {6, 6, 7, 8};
  const int segin[4] = {0, 0, 64, 128};
  const int segout[4] = {0, 64, 128, 256};

  for (int l = 0; l < 4; ++l) {
    int C = Cs[l], O = Os[l], twoO = 2 * O;
    const float* featin = (l == 0) ? feat0 : (catbuf + segin[l]);
    int lda = (l == 0) ? 4 : CAT_C;
    int nks = (C + 31) / 32;            // 1,2,2,4

    xnorm_kernel<<<32, 256, 0, stream>>>(featin, lda, C, x2buf);
    split_pack<<<512, 256, 0, stream>>>(featin, lda, C, packH, packM, packL);
    knn_mfma<<<512, 1024, 0, stream>>>(packH, packM, packL, x2buf, nks, idxbuf);

    build_wc<<<(Ks[l] * twoO + 255) / 256, 256, 0, stream>>>(w[l], Ks[l], O, wcbuf);
    gemm_kernel<<<dim3(twoO / 64, 8192 / 64), 256, 0, stream>>>(featin, lda, wcbuf, aybuf,
                                                                8192, twoO, Ks[l]);
    hipMemsetAsync(sumsbin, 0, (size_t)64 * 512 * sizeof(float), stream);
    aggregate_kernel<<<2048, 256, 0, stream>>>(aybuf, idxbuf, O, mxbuf, mnbuf, sumsbin);
    reduce_bins<<<1, 256, 0, stream>>>(sumsbin, sums, O);
    finalize_edge<<<(8192 * O) / 256, 256, 0, stream>>>(mxbuf, mnbuf, sums, gg[l], bb[l],
                                                        osh[l], catbuf + segout[l],
                                                        1.0f / (8192.0f * KNN_K));
  }

  // layer 5: h5 = cat * w5^T via split-bf16 MFMA with fused per-tile reduction
  gemm_split_red<<<dim3(1024 / 128, 8192 / 128), 256, 0, stream>>>(catbuf, CAT_C, w[4], 512,
                                                                   parts, 512);
  finalize5_fused<<<8192 / 256, 256, 0, stream>>>(parts, gg[4], bb[4], out);
}

// Round 19
// 474.637 us; speedup vs baseline: 1.1691x; 1.0243x over previous
//
#include <hip/hip_runtime.h>
#include <cstddef>

#define B_SZ 8
#define N_PTS 1024
#define KNN_K 20
#define CAT_C 512
#define BN_EPS 1e-5f

typedef unsigned short u16;
typedef unsigned int u32;
typedef __bf16 bf16;
typedef __bf16 bf16x8 __attribute__((ext_vector_type(8)));
typedef float f32x4 __attribute__((ext_vector_type(4)));

// ---------------- transpose x (B,3,N) -> feat0 (B,N,4) (col 3 pre-zeroed) ----------------
__global__ __launch_bounds__(256) void transpose_x(const float* __restrict__ x,
                                                   float* __restrict__ feat0) {
  int t = blockIdx.x * 256 + threadIdx.x;
  if (t >= B_SZ * 3 * N_PTS) return;
  int b = t / (3 * N_PTS);
  int r = t - b * 3 * N_PTS;
  int c = r / N_PTS;
  int n = r - c * N_PTS;
  feat0[((size_t)(b * N_PTS + n)) * 4 + c] = x[t];
}

// ---------------- squared norms per point (exact fp32) ----------------
__global__ __launch_bounds__(256) void xnorm_kernel(const float* __restrict__ feat, int lda,
                                                    int C, float* __restrict__ x2) {
  int p = blockIdx.x * 256 + threadIdx.x;
  if (p >= 8192) return;
  const float* r = feat + (size_t)p * lda;
  float s = 0.f;
  for (int c = 0; c < C; c += 4) {
    float4 v = *(const float4*)(r + c);
    s = fmaf(v.x, v.x, s); s = fmaf(v.y, v.y, s);
    s = fmaf(v.z, v.z, s); s = fmaf(v.w, v.w, s);
  }
  x2[p] = s;
}

// ---------------- triple-split features, B-coalesced layout --------------------------
__global__ __launch_bounds__(256) void split_pack(const float* __restrict__ feat, int lda,
                                                  int C, bf16* __restrict__ packH,
                                                  bf16* __restrict__ packM,
                                                  bf16* __restrict__ packL) {
  int t = blockIdx.x * 256 + threadIdx.x;     // 8192*16 threads, 8 k's each
  if (t >= 8192 * 16) return;
  int p = t >> 4, c = t & 15;                 // p = global point, c = q plane
  int b = p >> 10, col = p & 1023;
  int k0 = c * 8;
  bf16x8 h, m, l;
  #pragma unroll
  for (int e = 0; e < 8; ++e) {
    int k = k0 + e;
    float v = (k < C) ? feat[(size_t)p * lda + k] : 0.f;
    bf16 hb = (bf16)v;       float r1 = v - (float)hb;
    bf16 mb = (bf16)r1;      float r2 = r1 - (float)mb;
    bf16 lb = (bf16)r2;
    h[e] = hb; m[e] = mb; l[e] = lb;
  }
  size_t dst = ((size_t)(b * 16 + c) * 1024 + col) * 8;
  *(bf16x8*)(packH + dst) = h;
  *(bf16x8*)(packM + dst) = m;
  *(bf16x8*)(packL + dst) = l;
}

// ---- DPP value-reduce stages (tree verified bit-exact in R10/R11/R16) ----
#define DPP_MAX_STAGE(CTRL)                                                          \
  {                                                                                  \
    int nb = __builtin_amdgcn_update_dpp((int)0xFF800000, __float_as_int(mx),        \
                                         (CTRL), 0xF, 0xF, false);                   \
    mx = fmaxf(mx, __int_as_float(nb));                                              \
  }
#define DPP_MIN_STAGE(CTRL)                                                          \
  {                                                                                  \
    int nb = __builtin_amdgcn_update_dpp((int)0x7fffffff, mc,                        \
                                         (CTRL), 0xF, 0xF, false);                   \
    mc = (nb < mc) ? nb : mc;                                                        \
  }

// ---------------- KNN: triple-split MFMA distances + R16 DPP selection ----------------
// XCD swizzle: blocks with bid%8==r handle batch r (64 blocks/batch; %8 dispatch
// heuristic makes each batch's 768KB packs XCD-L2-resident).
__global__ __launch_bounds__(1024) void knn_mfma(const bf16* __restrict__ packH,
                                                 const bf16* __restrict__ packM,
                                                 const bf16* __restrict__ packL,
                                                 const float* __restrict__ x2,
                                                 int nks,
                                                 int* __restrict__ idxout) {
  __shared__ u16 Ah[16 * 128];        // 4KB each, row stride 256B, XOR-swizzled
  __shared__ u16 Am[16 * 128];
  __shared__ u16 Al[16 * 128];
  __shared__ float Ds[16 * 1028];     // 65.8KB, padded stride
  int tid = threadIdx.x;
  int w = tid >> 6, lane = tid & 63;
  int bid = blockIdx.x;
  int swz = (bid & 7) * 64 + (bid >> 3);   // 512 blocks -> batch = bid&7
  int row0 = swz * 16;
  int b = row0 >> 10;
  int col0 = row0 & 1023;

  if (tid < 256) {
    int r = tid >> 4, c = tid & 15;   // c = q plane
    int byte = r * 256 + ((c * 16) ^ ((r & 7) << 4));
    size_t src = ((size_t)(b * 16 + c) * 1024 + col0 + r) * 8;
    *(bf16x8*)((char*)Ah + byte) = *(const bf16x8*)(packH + src);
    *(bf16x8*)((char*)Am + byte) = *(const bf16x8*)(packM + src);
    *(bf16x8*)((char*)Al + byte) = *(const bf16x8*)(packL + src);
  }
  __syncthreads();

  int lrow = lane & 15, kgrp = lane >> 4;
  int abase = lrow * 256;

  f32x4 acc[4];
  #pragma unroll
  for (int f = 0; f < 4; ++f) acc[f] = (f32x4){0.f, 0.f, 0.f, 0.f};

  for (int ks = 0; ks < nks; ++ks) {
    int kb = (ks * 32 + kgrp * 8) * 2;
    int aoff = abase + (kb ^ ((lrow & 7) << 4));
    bf16x8 a_h = *(const bf16x8*)((const char*)Ah + aoff);
    bf16x8 a_m = *(const bf16x8*)((const char*)Am + aoff);
    bf16x8 a_l = *(const bf16x8*)((const char*)Al + aoff);
    int q = ks * 4 + kgrp;
    size_t pbase = (size_t)(b * 16 + q) * 1024;
    #pragma unroll
    for (int f = 0; f < 4; ++f) {
      int col = w * 64 + f * 16 + lrow;
      bf16x8 b_h = *(const bf16x8*)(packH + (pbase + col) * 8);
      bf16x8 b_m = *(const bf16x8*)(packM + (pbase + col) * 8);
      bf16x8 b_l = *(const bf16x8*)(packL + (pbase + col) * 8);
      acc[f] = __builtin_amdgcn_mfma_f32_16x16x32_bf16(a_h, b_h, acc[f], 0, 0, 0);
      acc[f] = __builtin_amdgcn_mfma_f32_16x16x32_bf16(a_h, b_m, acc[f], 0, 0, 0);
      acc[f] = __builtin_amdgcn_mfma_f32_16x16x32_bf16(a_m, b_h, acc[f], 0, 0, 0);
      acc[f] = __builtin_amdgcn_mfma_f32_16x16x32_bf16(a_m, b_m, acc[f], 0, 0, 0);
      acc[f] = __builtin_amdgcn_mfma_f32_16x16x32_bf16(a_h, b_l, acc[f], 0, 0, 0);
      acc[f] = __builtin_amdgcn_mfma_f32_16x16x32_bf16(a_l, b_h, acc[f], 0, 0, 0);
      acc[f] = __builtin_amdgcn_mfma_f32_16x16x32_bf16(a_m, b_l, acc[f], 0, 0, 0);
      acc[f] = __builtin_amdgcn_mfma_f32_16x16x32_bf16(a_l, b_m, acc[f], 0, 0, 0);
    }
  }
  // D epilogue (m89-verified layout: row=(lane>>4)*4+r, col=lane&15)
  #pragma unroll
  for (int f = 0; f < 4; ++f) {
    int col = w * 64 + f * 16 + lrow;
    #pragma unroll
    for (int r = 0; r < 4; ++r)
      Ds[(kgrp * 4 + r) * 1028 + col] = acc[f][r];
  }
  __syncthreads();

  // selection: wave w handles row w (R16 passer, verbatim semantics)
  const float* x2b = x2 + b * N_PTS;
  int row = row0 + w;
  float x2n = x2[row];
  float accv[16];
  #pragma unroll
  for (int j = 0; j < 16; ++j) {
    float d = Ds[w * 1028 + j * 64 + lane];
    accv[j] = (2.f * d - x2n) - x2b[j * 64 + lane];
  }

  for (int rr = 0; rr < KNN_K; ++rr) {
    float m01 = fmaxf(accv[0], accv[1]),   m23 = fmaxf(accv[2], accv[3]);
    float m45 = fmaxf(accv[4], accv[5]),   m67 = fmaxf(accv[6], accv[7]);
    float m89 = fmaxf(accv[8], accv[9]),   mab = fmaxf(accv[10], accv[11]);
    float mcd = fmaxf(accv[12], accv[13]), mef = fmaxf(accv[14], accv[15]);
    float mx = fmaxf(fmaxf(fmaxf(m01, m23), fmaxf(m45, m67)),
                     fmaxf(fmaxf(m89, mab), fmaxf(mcd, mef)));
    DPP_MAX_STAGE(0x111)
    DPP_MAX_STAGE(0x112)
    DPP_MAX_STAGE(0x114)
    DPP_MAX_STAGE(0x118)
    DPP_MAX_STAGE(0x142)
    DPP_MAX_STAGE(0x143)
    mx = __int_as_float(__builtin_amdgcn_readlane(__float_as_int(mx), 63));

    int jloc = 16;
    #pragma unroll
    for (int j = 15; j >= 0; --j)
      if (accv[j] == mx) jloc = j;
    int mc = (jloc < 16) ? ((jloc << 6) | lane) : 0x7fffffff;
    DPP_MIN_STAGE(0x111)
    DPP_MIN_STAGE(0x112)
    DPP_MIN_STAGE(0x114)
    DPP_MIN_STAGE(0x118)
    DPP_MIN_STAGE(0x142)
    DPP_MIN_STAGE(0x143)
    int si = __builtin_amdgcn_readlane(mc, 63);

    int jj = si >> 6, ln = si & 63;
    bool isln = (lane == ln);
    #pragma unroll
    for (int j = 0; j < 16; ++j)
      if (j == jj && isln) accv[j] = -3.4e38f;
    if (lane == 0) idxout[row * KNN_K + rr] = si;
  }
}

// ---------------- build combined weight Wc (fp32): [w1-w2 | w2], K=C rows x 2O cols ----------------
__global__ __launch_bounds__(256) void build_wc(const float* __restrict__ w, int C, int O,
                                                float* __restrict__ wc) {
  int t = blockIdx.x * 256 + threadIdx.x;
  int twoO = 2 * O;
  if (t >= C * twoO) return;
  int c = t / twoO, j = t - c * twoO;
  float v;
  if (j < O) v = w[j * (2 * C) + c] - w[j * (2 * C) + C + c];
  else       v = w[(j - O) * (2 * C) + C + c];
  wc[t] = v;
}

// ---------------- fp32 GEMM (edge layers): C[M,N] = A[M,K](lda) * B[K,N] ----------------
__global__ __launch_bounds__(256) void gemm_kernel(const float* __restrict__ A, int lda,
                                                   const float* __restrict__ Bm,
                                                   float* __restrict__ Cm,
                                                   int M, int N, int K) {
  __shared__ float As[16][64];
  __shared__ float Bs[16][68];
  int tx = threadIdx.x & 15, ty = threadIdx.x >> 4;
  int bn0 = blockIdx.x * 64, bm0 = blockIdx.y * 64;
  float acc[4][4];
  #pragma unroll
  for (int i = 0; i < 4; ++i)
    #pragma unroll
    for (int j = 0; j < 4; ++j) acc[i][j] = 0.f;

  for (int k0 = 0; k0 < K; k0 += 16) {
    {
      int t = threadIdx.x;
      int m = t >> 2, kb = (t & 3) * 4;
      const float* ap = A + (size_t)(bm0 + m) * lda + k0 + kb;
      #pragma unroll
      for (int i = 0; i < 4; ++i) As[kb + i][m] = (k0 + kb + i < K) ? ap[i] : 0.f;
      int r = t >> 4, c4 = (t & 15) * 4;
      float4 bv = make_float4(0.f, 0.f, 0.f, 0.f);
      if (k0 + r < K) bv = *(const float4*)(Bm + (size_t)(k0 + r) * N + bn0 + c4);
      *(float4*)&Bs[r][c4] = bv;
    }
    __syncthreads();
    #pragma unroll
    for (int k = 0; k < 16; ++k) {
      float a0[4];
      #pragma unroll
      for (int i = 0; i < 4; ++i) a0[i] = As[k][ty * 4 + i];
      float4 bv = *(const float4*)&Bs[k][tx * 4];
      float b0[4] = {bv.x, bv.y, bv.z, bv.w};
      #pragma unroll
      for (int i = 0; i < 4; ++i)
        #pragma unroll
        for (int j = 0; j < 4; ++j) acc[i][j] = fmaf(a0[i], b0[j], acc[i][j]);
    }
    __syncthreads();
  }
  #pragma unroll
  for (int i = 0; i < 4; ++i) {
    float4 v = make_float4(acc[i][0], acc[i][1], acc[i][2], acc[i][3]);
    *(float4*)(Cm + (size_t)(bm0 + ty * 4 + i) * N + bn0 + tx * 4) = v;
  }
}

// ---------------- split fp32 -> bf16 hi/lo MFMA GEMM for layer 5, fused reduction ----------------
__device__ inline void split8(const float* __restrict__ p, bf16x8* hv, bf16x8* lv) {
  float4 a0 = *(const float4*)p, a1 = *(const float4*)(p + 4);
  float v[8] = {a0.x, a0.y, a0.z, a0.w, a1.x, a1.y, a1.z, a1.w};
  bf16x8 h, l;
  #pragma unroll
  for (int j = 0; j < 8; ++j) {
    bf16 hj = (bf16)v[j];
    h[j] = hj;
    l[j] = (bf16)(v[j] - (float)hj);
  }
  *hv = h; *lv = l;
}

__global__ __launch_bounds__(256) void gemm_split_red(const float* __restrict__ A, int lda,
                                                      const float* __restrict__ Bt, int ldb,
                                                      float* __restrict__ parts, int K) {
  __shared__ u16 Ah[128 * 64];
  __shared__ u16 Al[128 * 64];
  __shared__ u16 Bh[128 * 64];
  __shared__ u16 Bl[128 * 64];
  int tid = threadIdx.x;
  int wave = tid >> 6, lane = tid & 63;
  int wr = wave >> 1, wc = wave & 1;
  int bn0 = blockIdx.x * 128, bm0 = blockIdx.y * 128;
  int lrow = lane & 15;
  int kgrp = lane >> 4;

  f32x4 acc[4][4];
  #pragma unroll
  for (int i = 0; i < 4; ++i)
    #pragma unroll
    for (int j = 0; j < 4; ++j) acc[i][j] = (f32x4){0.f, 0.f, 0.f, 0.f};

  for (int k0 = 0; k0 < K; k0 += 64) {
    #pragma unroll
    for (int i = 0; i < 4; ++i) {
      int chunk = tid + i * 256;
      int row = chunk >> 3;
      int cc = (chunk & 7) * 8;
      int byte = row * 128 + ((cc * 2) ^ ((row & 7) << 4));
      bf16x8 h, l;
      split8(A + (size_t)(bm0 + row) * lda + k0 + cc, &h, &l);
      *(bf16x8*)((char*)Ah + byte) = h;
      *(bf16x8*)((char*)Al + byte) = l;
      split8(Bt + (size_t)(bn0 + row) * ldb + k0 + cc, &h, &l);
      *(bf16x8*)((char*)Bh + byte) = h;
      *(bf16x8*)((char*)Bl + byte) = l;
    }
    __syncthreads();
    #pragma unroll
    for (int kk = 0; kk < 64; kk += 32) {
      int kb = (kk + kgrp * 8) * 2;
      bf16x8 afh[4], afl[4], bfh[4], bfl[4];
      #pragma unroll
      for (int f = 0; f < 4; ++f) {
        int arow = wr * 64 + f * 16 + lrow;
        int abyte = arow * 128 + (kb ^ ((arow & 7) << 4));
        afh[f] = *(const bf16x8*)((const char*)Ah + abyte);
        afl[f] = *(const bf16x8*)((const char*)Al + abyte);
        int brow = wc * 64 + f * 16 + lrow;
        int bbyte = brow * 128 + (kb ^ ((brow & 7) << 4));
        bfh[f] = *(const bf16x8*)((const char*)Bh + bbyte);
        bfl[f] = *(const bf16x8*)((const char*)Bl + bbyte);
      }
      #pragma unroll
      for (int fm = 0; fm < 4; ++fm)
        #pragma unroll
        for (int fn = 0; fn < 4; ++fn) {
          acc[fm][fn] = __builtin_amdgcn_mfma_f32_16x16x32_bf16(afh[fm], bfh[fn], acc[fm][fn], 0, 0, 0);
          acc[fm][fn] = __builtin_amdgcn_mfma_f32_16x16x32_bf16(afl[fm], bfh[fn], acc[fm][fn], 0, 0, 0);
          acc[fm][fn] = __builtin_amdgcn_mfma_f32_16x16x32_bf16(afh[fm], bfl[fn], acc[fm][fn], 0, 0, 0);
        }
    }
    __syncthreads();
  }

  float* scratch = (float*)Ah;
  int contrib = wr * 4 + kgrp;
  #pragma unroll
  for (int fn = 0; fn < 4; ++fn) {
    float mx = -3.4e38f, mn = 3.4e38f, s1 = 0.f, s2 = 0.f;
    #pragma unroll
    for (int fm = 0; fm < 4; ++fm)
      #pragma unroll
      for (int r = 0; r < 4; ++r) {
        float v = acc[fm][fn][r];
        mx = fmaxf(mx, v); mn = fminf(mn, v);
        s1 += v; s2 = fmaf(v, v, s2);
      }
    int col = wc * 64 + fn * 16 + lrow;
    float* sp = scratch + (contrib * 128 + col) * 4;
    sp[0] = mx; sp[1] = mn; sp[2] = s1; sp[3] = s2;
  }
  __syncthreads();
  if (tid < 128) {
    float mx = -3.4e38f, mn = 3.4e38f, s1 = 0.f, s2 = 0.f;
    #pragma unroll
    for (int c2 = 0; c2 < 8; ++c2) {
      const float* sp = scratch + (c2 * 128 + tid) * 4;
      mx = fmaxf(mx, sp[0]); mn = fminf(mn, sp[1]);
      s1 += sp[2]; s2 += sp[3];
    }
    size_t o = (size_t)blockIdx.y * 1024 + bn0 + tid;
    parts[o] = mx;
    parts[65536 + o] = mn;
    parts[131072 + o] = s1;
    parts[196608 + o] = s2;
  }
}

// ---------------- edge aggregation: y-stats over k, combine with a analytically --------
// max_k(a+y) = a + max_k y (a constant over k); s1_h = 20a + s1_y;
// s2_h = s2_y + a*(2*s1_y + 20*a). XCD swizzle: blocks with bid%8==r handle batch r
// (batch y-region = 2MB, fits one XCD's 4MB L2 -> gathers become L2 hits).
__global__ __launch_bounds__(256) void aggregate_kernel(const float* __restrict__ ay,
                                                        const int* __restrict__ idxb, int O,
                                                        float* __restrict__ mx,
                                                        float* __restrict__ mn,
                                                        float* __restrict__ sumsbin) {
  __shared__ float ls[2][256];
  for (int i = threadIdx.x; i < 512; i += 256) ((float*)ls)[i] = 0.f;
  __syncthreads();

  int warp = threadIdx.x >> 6, lane = threadIdx.x & 63;
  int bid = blockIdx.x;
  int swz = (bid & 7) * 256 + (bid >> 3);   // 2048 blocks -> batch = bid&7
  int pt = swz * 4 + warp;                  // 0..8191
  int b = pt >> 10;
  int twoO = 2 * O;
  int U = O >> 6;
  const float* ayrow = ay + (size_t)pt * twoO;

  float s1[4], s2[4], vmx[4], vmn[4];
  for (int u = 0; u < U; ++u) {
    s1[u] = 0.f; s2[u] = 0.f; vmx[u] = -3.4e38f; vmn[u] = 3.4e38f;
  }
  const int* ip = idxb + pt * KNN_K;
  for (int k = 0; k < KNN_K; ++k) {
    int j = ip[k];
    const float* yrow = ay + (size_t)(b * N_PTS + j) * twoO + O;
    for (int u = 0; u < U; ++u) {
      float v = yrow[u * 64 + lane];
      s1[u] += v; s2[u] = fmaf(v, v, s2[u]);
      vmx[u] = fmaxf(vmx[u], v); vmn[u] = fminf(vmn[u], v);
    }
  }
  for (int u = 0; u < U; ++u) {
    int o = u * 64 + lane;
    float a = ayrow[u * 64 + lane];
    mx[(size_t)pt * O + o] = a + vmx[u];
    mn[(size_t)pt * O + o] = a + vmn[u];
    atomicAdd(&ls[0][o], fmaf(20.f, a, s1[u]));
    atomicAdd(&ls[1][o], s2[u] + a * fmaf(20.f, a, 2.f * s1[u]));
  }
  __syncthreads();
  int bin = blockIdx.x & 63;
  float* gb = sumsbin + (size_t)bin * 512;
  for (int o = threadIdx.x; o < O; o += 256) {
    atomicAdd(&gb[o], ls[0][o]);
    atomicAdd(&gb[256 + o], ls[1][o]);
  }
}

__global__ __launch_bounds__(256) void reduce_bins(const float* __restrict__ sumsbin,
                                                   float* __restrict__ sums, int O) {
  int o = threadIdx.x;
  if (o >= O) return;
  float a = 0.f, c = 0.f;
  for (int bin = 0; bin < 64; ++bin) {
    a += sumsbin[bin * 512 + o];
    c += sumsbin[bin * 512 + 256 + o];
  }
  sums[o] = a;
  sums[256 + o] = c;
}

// ---------------- finalize edge layer: BN + relu on (max or min depending on sign) ----------------
__global__ __launch_bounds__(256) void finalize_edge(const float* __restrict__ mx,
                                                     const float* __restrict__ mn,
                                                     const float* __restrict__ sums,
                                                     const float* __restrict__ g,
                                                     const float* __restrict__ beta,
                                                     int oshift,
                                                     float* __restrict__ outseg,
                                                     float cnt_inv) {
  int tid = blockIdx.x * 256 + threadIdx.x;
  int pt = tid >> oshift;
  int o = tid & ((1 << oshift) - 1);
  float s1 = sums[o], s2 = sums[256 + o];
  float mean = s1 * cnt_inv;
  float var = s2 * cnt_inv - mean * mean;
  float rstd = rsqrtf(var + BN_EPS);
  float sc = g[o] * rstd;
  float sel = (sc >= 0.f) ? mx[tid] : mn[tid];
  float v = (sel - mean) * sc + beta[o];
  outseg[(size_t)pt * CAT_C + o] = fmaxf(v, 0.f);
}

// ---------------- layer 5 finalize from tile partials ----------------
__global__ __launch_bounds__(256) void finalize5_fused(const float* __restrict__ parts,
                                                       const float* __restrict__ g,
                                                       const float* __restrict__ beta,
                                                       float* __restrict__ out) {
  int tid = blockIdx.x * 256 + threadIdx.x;
  int b = tid >> 10, o = tid & 1023;
  const float* pmx = parts;
  const float* pmn = parts + 65536;
  const float* ps1 = parts + 131072;
  const float* ps2 = parts + 196608;
  float s1 = 0.f, s2 = 0.f;
  for (int t = 0; t < 64; ++t) { s1 += ps1[t * 1024 + o]; s2 += ps2[t * 1024 + o]; }
  float mx = -3.4e38f, mn = 3.4e38f;
  #pragma unroll
  for (int t = 0; t < 8; ++t) {
    mx = fmaxf(mx, pmx[(b * 8 + t) * 1024 + o]);
    mn = fminf(mn, pmn[(b * 8 + t) * 1024 + o]);
  }
  float mean = s1 * (1.0f / 8192.0f);
  float var = s2 * (1.0f / 8192.0f) - mean * mean;
  float rstd = rsqrtf(var + BN_EPS);
  float sc = g[o] * rstd;
  float sel = (sc >= 0.f) ? mx : mn;
  float v = (sel - mean) * sc + beta[o];
  out[tid] = fmaxf(v, 0.f);
}

extern "C" void kernel_launch(void* const* d_in, const int* in_sizes, int n_in,
                              void* d_out, int out_size, void* d_ws, size_t ws_size,
                              hipStream_t stream) {
  const float* x = (const float*)d_in[0];
  const float* w[5]  = {(const float*)d_in[1], (const float*)d_in[4], (const float*)d_in[7],
                        (const float*)d_in[10], (const float*)d_in[13]};
  const float* gg[5] = {(const float*)d_in[2], (const float*)d_in[5], (const float*)d_in[8],
                        (const float*)d_in[11], (const float*)d_in[14]};
  const float* bb[5] = {(const float*)d_in[3], (const float*)d_in[6], (const float*)d_in[9],
                        (const float*)d_in[12], (const float*)d_in[15]};
  float* out = (float*)d_out;

  float* W = (float*)d_ws;
  size_t off = 0;
  float* feat0   = W + off; off += (size_t)B_SZ * N_PTS * 4;   // stride-4 padded
  float* catbuf  = W + off; off += (size_t)8192 * CAT_C;
  int*   idxbuf  = (int*)(W + off); off += (size_t)8192 * KNN_K;
  float* aybuf   = W + off; off += (size_t)8192 * 1024;
  float* mxbuf   = W + off; off += (size_t)8192 * 256;
  float* mnbuf   = W + off; off += (size_t)8192 * 256;
  float* wcbuf   = W + off; off += (size_t)512 * 1024;
  float* sumsbin = W + off; off += (size_t)64 * 512;
  float* sums    = W + off; off += 512;
  float* parts   = W + off; off += (size_t)4 * 64 * 1024;
  float* x2buf   = W + off; off += 8192;
  bf16*  packH   = (bf16*)(W + off); off += (size_t)8192 * 128 / 2;   // 2MB
  bf16*  packM   = (bf16*)(W + off); off += (size_t)8192 * 128 / 2;   // 2MB
  bf16*  packL   = (bf16*)(W + off); off += (size_t)8192 * 128 / 2;   // 2MB

  hipMemsetAsync(feat0, 0, (size_t)B_SZ * N_PTS * 4 * sizeof(float), stream);
  transpose_x<<<(B_SZ * 3 * N_PTS + 255) / 256, 256, 0, stream>>>(x, feat0);

  const int Cs[4] = {4, 64, 64, 128};   // layer-0 padded to 4 (pad=0, values unchanged)
  const int Ks[4] = {3, 64, 64, 128};   // true K for the edge GEMM
  const int Os[4] = {64, 64, 128, 256};
  const int osh[4] = {6, 6, 7, 8};
  const int segin[4] = {0, 0, 64, 128};
  const int segout[4] = {0, 64, 128, 256};

  for (int l = 0; l < 4; ++l) {
    int C = Cs[l], O = Os[l], twoO = 2 * O;
    const float* featin = (l == 0) ? feat0 : (catbuf + segin[l]);
    int lda = (l == 0) ? 4 : CAT_C;
    int nks = (C + 31) / 32;            // 1,2,2,4

    xnorm_kernel<<<32, 256, 0, stream>>>(featin, lda, C, x2buf);
    split_pack<<<512, 256, 0, stream>>>(featin, lda, C, packH, packM, packL);
    knn_mfma<<<512, 1024, 0, stream>>>(packH, packM, packL, x2buf, nks, idxbuf);

    build_wc<<<(Ks[l] * twoO + 255) / 256, 256, 0, stream>>>(w[l], Ks[l], O, wcbuf);
    gemm_kernel<<<dim3(twoO / 64, 8192 / 64), 256, 0, stream>>>(featin, lda, wcbuf, aybuf,
                                                                8192, twoO, Ks[l]);
    hipMemsetAsync(sumsbin, 0, (size_t)64 * 512 * sizeof(float), stream);
    aggregate_kernel<<<2048, 256, 0, stream>>>(aybuf, idxbuf, O, mxbuf, mnbuf, sumsbin);
    reduce_bins<<<1, 256, 0, stream>>>(sumsbin, sums, O);
    finalize_edge<<<(8192 * O) / 256, 256, 0, stream>>>(mxbuf, mnbuf, sums, gg[l], bb[l],
                                                        osh[l], catbuf + segout[l],
                                                        1.0f / (8192.0f * KNN_K));
  }

  // layer 5: h5 = cat * w5^T via split-bf16 MFMA with fused per-tile reduction
  gemm_split_red<<<dim3(1024 / 128, 8192 / 128), 256, 0, stream>>>(catbuf, CAT_C, w[4], 512,
                                                                   parts, 512);
  finalize5_fused<<<8192 / 256, 256, 0, stream>>>(parts, gg[4], bb[4], out);
}

// Round 20
// 387.410 us; speedup vs baseline: 1.4323x; 1.2252x over previous
//
#include <hip/hip_runtime.h>
#include <cstddef>

#define B_SZ 8
#define N_PTS 1024
#define KNN_K 20
#define CAT_C 512
#define BN_EPS 1e-5f

typedef unsigned short u16;
typedef unsigned int u32;
typedef __bf16 bf16;
typedef __bf16 bf16x8 __attribute__((ext_vector_type(8)));
typedef float f32x4 __attribute__((ext_vector_type(4)));

// ---------------- transpose x (B,3,N) -> feat0 (B,N,4) (col 3 pre-zeroed) ----------------
__global__ __launch_bounds__(256) void transpose_x(const float* __restrict__ x,
                                                   float* __restrict__ feat0) {
  int t = blockIdx.x * 256 + threadIdx.x;
  if (t >= B_SZ * 3 * N_PTS) return;
  int b = t / (3 * N_PTS);
  int r = t - b * 3 * N_PTS;
  int c = r / N_PTS;
  int n = r - c * N_PTS;
  feat0[((size_t)(b * N_PTS + n)) * 4 + c] = x[t];
}

// ---------------- squared norms per point (exact fp32) ----------------
__global__ __launch_bounds__(256) void xnorm_kernel(const float* __restrict__ feat, int lda,
                                                    int C, float* __restrict__ x2) {
  int p = blockIdx.x * 256 + threadIdx.x;
  if (p >= 8192) return;
  const float* r = feat + (size_t)p * lda;
  float s = 0.f;
  for (int c = 0; c < C; c += 4) {
    float4 v = *(const float4*)(r + c);
    s = fmaf(v.x, v.x, s); s = fmaf(v.y, v.y, s);
    s = fmaf(v.z, v.z, s); s = fmaf(v.w, v.w, s);
  }
  x2[p] = s;
}

// ---------------- triple-split features, B-coalesced layout --------------------------
__global__ __launch_bounds__(256) void split_pack(const float* __restrict__ feat, int lda,
                                                  int C, bf16* __restrict__ packH,
                                                  bf16* __restrict__ packM,
                                                  bf16* __restrict__ packL) {
  int t = blockIdx.x * 256 + threadIdx.x;     // 8192*16 threads, 8 k's each
  if (t >= 8192 * 16) return;
  int p = t >> 4, c = t & 15;                 // p = global point, c = q plane
  int b = p >> 10, col = p & 1023;
  int k0 = c * 8;
  bf16x8 h, m, l;
  #pragma unroll
  for (int e = 0; e < 8; ++e) {
    int k = k0 + e;
    float v = (k < C) ? feat[(size_t)p * lda + k] : 0.f;
    bf16 hb = (bf16)v;       float r1 = v - (float)hb;
    bf16 mb = (bf16)r1;      float r2 = r1 - (float)mb;
    bf16 lb = (bf16)r2;
    h[e] = hb; m[e] = mb; l[e] = lb;
  }
  size_t dst = ((size_t)(b * 16 + c) * 1024 + col) * 8;
  *(bf16x8*)(packH + dst) = h;
  *(bf16x8*)(packM + dst) = m;
  *(bf16x8*)(packL + dst) = l;
}

// ---- DPP value-reduce stages (tree verified bit-exact in R10/R11/R16) ----
#define DPP_MAX_STAGE(CTRL)                                                          \
  {                                                                                  \
    int nb = __builtin_amdgcn_update_dpp((int)0xFF800000, __float_as_int(mx),        \
                                         (CTRL), 0xF, 0xF, false);                   \
    mx = fmaxf(mx, __int_as_float(nb));                                              \
  }
#define DPP_MIN_STAGE(CTRL)                                                          \
  {                                                                                  \
    int nb = __builtin_amdgcn_update_dpp((int)0x7fffffff, mc,                        \
                                         (CTRL), 0xF, 0xF, false);                   \
    mc = (nb < mc) ? nb : mc;                                                        \
  }

// ---------------- KNN: triple-split MFMA distances + R16 DPP selection ----------------
__global__ __launch_bounds__(1024) void knn_mfma(const bf16* __restrict__ packH,
                                                 const bf16* __restrict__ packM,
                                                 const bf16* __restrict__ packL,
                                                 const float* __restrict__ x2,
                                                 int nks,
                                                 int* __restrict__ idxout) {
  __shared__ u16 Ah[16 * 128];        // 4KB each, row stride 256B, XOR-swizzled
  __shared__ u16 Am[16 * 128];
  __shared__ u16 Al[16 * 128];
  __shared__ float Ds[16 * 1028];     // 65.8KB, padded stride
  int tid = threadIdx.x;
  int w = tid >> 6, lane = tid & 63;
  int bid = blockIdx.x;
  int swz = (bid & 7) * 64 + (bid >> 3);   // 512 blocks -> batch = bid&7
  int row0 = swz * 16;
  int b = row0 >> 10;
  int col0 = row0 & 1023;

  if (tid < 256) {
    int r = tid >> 4, c = tid & 15;   // c = q plane
    int byte = r * 256 + ((c * 16) ^ ((r & 7) << 4));
    size_t src = ((size_t)(b * 16 + c) * 1024 + col0 + r) * 8;
    *(bf16x8*)((char*)Ah + byte) = *(const bf16x8*)(packH + src);
    *(bf16x8*)((char*)Am + byte) = *(const bf16x8*)(packM + src);
    *(bf16x8*)((char*)Al + byte) = *(const bf16x8*)(packL + src);
  }
  __syncthreads();

  int lrow = lane & 15, kgrp = lane >> 4;
  int abase = lrow * 256;

  f32x4 acc[4];
  #pragma unroll
  for (int f = 0; f < 4; ++f) acc[f] = (f32x4){0.f, 0.f, 0.f, 0.f};

  for (int ks = 0; ks < nks; ++ks) {
    int kb = (ks * 32 + kgrp * 8) * 2;
    int aoff = abase + (kb ^ ((lrow & 7) << 4));
    bf16x8 a_h = *(const bf16x8*)((const char*)Ah + aoff);
    bf16x8 a_m = *(const bf16x8*)((const char*)Am + aoff);
    bf16x8 a_l = *(const bf16x8*)((const char*)Al + aoff);
    int q = ks * 4 + kgrp;
    size_t pbase = (size_t)(b * 16 + q) * 1024;
    #pragma unroll
    for (int f = 0; f < 4; ++f) {
      int col = w * 64 + f * 16 + lrow;
      bf16x8 b_h = *(const bf16x8*)(packH + (pbase + col) * 8);
      bf16x8 b_m = *(const bf16x8*)(packM + (pbase + col) * 8);
      bf16x8 b_l = *(const bf16x8*)(packL + (pbase + col) * 8);
      acc[f] = __builtin_amdgcn_mfma_f32_16x16x32_bf16(a_h, b_h, acc[f], 0, 0, 0);
      acc[f] = __builtin_amdgcn_mfma_f32_16x16x32_bf16(a_h, b_m, acc[f], 0, 0, 0);
      acc[f] = __builtin_amdgcn_mfma_f32_16x16x32_bf16(a_m, b_h, acc[f], 0, 0, 0);
      acc[f] = __builtin_amdgcn_mfma_f32_16x16x32_bf16(a_m, b_m, acc[f], 0, 0, 0);
      acc[f] = __builtin_amdgcn_mfma_f32_16x16x32_bf16(a_h, b_l, acc[f], 0, 0, 0);
      acc[f] = __builtin_amdgcn_mfma_f32_16x16x32_bf16(a_l, b_h, acc[f], 0, 0, 0);
      acc[f] = __builtin_amdgcn_mfma_f32_16x16x32_bf16(a_m, b_l, acc[f], 0, 0, 0);
      acc[f] = __builtin_amdgcn_mfma_f32_16x16x32_bf16(a_l, b_m, acc[f], 0, 0, 0);
    }
  }
  // D epilogue (m89-verified layout: row=(lane>>4)*4+r, col=lane&15)
  #pragma unroll
  for (int f = 0; f < 4; ++f) {
    int col = w * 64 + f * 16 + lrow;
    #pragma unroll
    for (int r = 0; r < 4; ++r)
      Ds[(kgrp * 4 + r) * 1028 + col] = acc[f][r];
  }
  __syncthreads();

  // selection: wave w handles row w (R16 passer, verbatim semantics)
  const float* x2b = x2 + b * N_PTS;
  int row = row0 + w;
  float x2n = x2[row];
  float accv[16];
  #pragma unroll
  for (int j = 0; j < 16; ++j) {
    float d = Ds[w * 1028 + j * 64 + lane];
    accv[j] = (2.f * d - x2n) - x2b[j * 64 + lane];
  }

  for (int rr = 0; rr < KNN_K; ++rr) {
    float m01 = fmaxf(accv[0], accv[1]),   m23 = fmaxf(accv[2], accv[3]);
    float m45 = fmaxf(accv[4], accv[5]),   m67 = fmaxf(accv[6], accv[7]);
    float m89 = fmaxf(accv[8], accv[9]),   mab = fmaxf(accv[10], accv[11]);
    float mcd = fmaxf(accv[12], accv[13]), mef = fmaxf(accv[14], accv[15]);
    float mx = fmaxf(fmaxf(fmaxf(m01, m23), fmaxf(m45, m67)),
                     fmaxf(fmaxf(m89, mab), fmaxf(mcd, mef)));
    DPP_MAX_STAGE(0x111)
    DPP_MAX_STAGE(0x112)
    DPP_MAX_STAGE(0x114)
    DPP_MAX_STAGE(0x118)
    DPP_MAX_STAGE(0x142)
    DPP_MAX_STAGE(0x143)
    mx = __int_as_float(__builtin_amdgcn_readlane(__float_as_int(mx), 63));

    int jloc = 16;
    #pragma unroll
    for (int j = 15; j >= 0; --j)
      if (accv[j] == mx) jloc = j;
    int mc = (jloc < 16) ? ((jloc << 6) | lane) : 0x7fffffff;
    DPP_MIN_STAGE(0x111)
    DPP_MIN_STAGE(0x112)
    DPP_MIN_STAGE(0x114)
    DPP_MIN_STAGE(0x118)
    DPP_MIN_STAGE(0x142)
    DPP_MIN_STAGE(0x143)
    int si = __builtin_amdgcn_readlane(mc, 63);

    int jj = si >> 6, ln = si & 63;
    bool isln = (lane == ln);
    #pragma unroll
    for (int j = 0; j < 16; ++j)
      if (j == jj && isln) accv[j] = -3.4e38f;
    if (lane == 0) idxout[row * KNN_K + rr] = si;
  }
}

// ---------------- build combined weight Wc (fp32): [w1-w2 | w2], K=C rows x 2O cols ----------------
__global__ __launch_bounds__(256) void build_wc(const float* __restrict__ w, int C, int O,
                                                float* __restrict__ wc) {
  int t = blockIdx.x * 256 + threadIdx.x;
  int twoO = 2 * O;
  if (t >= C * twoO) return;
  int c = t / twoO, j = t - c * twoO;
  float v;
  if (j < O) v = w[j * (2 * C) + c] - w[j * (2 * C) + C + c];
  else       v = w[(j - O) * (2 * C) + C + c];
  wc[t] = v;
}

// ---------------- fp32 GEMM (edge layers): C[M,N] = A[M,K](lda) * B[K,N] ----------------
__global__ __launch_bounds__(256) void gemm_kernel(const float* __restrict__ A, int lda,
                                                   const float* __restrict__ Bm,
                                                   float* __restrict__ Cm,
                                                   int M, int N, int K) {
  __shared__ float As[16][64];
  __shared__ float Bs[16][68];
  int tx = threadIdx.x & 15, ty = threadIdx.x >> 4;
  int bn0 = blockIdx.x * 64, bm0 = blockIdx.y * 64;
  float acc[4][4];
  #pragma unroll
  for (int i = 0; i < 4; ++i)
    #pragma unroll
    for (int j = 0; j < 4; ++j) acc[i][j] = 0.f;

  for (int k0 = 0; k0 < K; k0 += 16) {
    {
      int t = threadIdx.x;
      int m = t >> 2, kb = (t & 3) * 4;
      const float* ap = A + (size_t)(bm0 + m) * lda + k0 + kb;
      #pragma unroll
      for (int i = 0; i < 4; ++i) As[kb + i][m] = (k0 + kb + i < K) ? ap[i] : 0.f;
      int r = t >> 4, c4 = (t & 15) * 4;
      float4 bv = make_float4(0.f, 0.f, 0.f, 0.f);
      if (k0 + r < K) bv = *(const float4*)(Bm + (size_t)(k0 + r) * N + bn0 + c4);
      *(float4*)&Bs[r][c4] = bv;
    }
    __syncthreads();
    #pragma unroll
    for (int k = 0; k < 16; ++k) {
      float a0[4];
      #pragma unroll
      for (int i = 0; i < 4; ++i) a0[i] = As[k][ty * 4 + i];
      float4 bv = *(const float4*)&Bs[k][tx * 4];
      float b0[4] = {bv.x, bv.y, bv.z, bv.w};
      #pragma unroll
      for (int i = 0; i < 4; ++i)
        #pragma unroll
        for (int j = 0; j < 4; ++j) acc[i][j] = fmaf(a0[i], b0[j], acc[i][j]);
    }
    __syncthreads();
  }
  #pragma unroll
  for (int i = 0; i < 4; ++i) {
    float4 v = make_float4(acc[i][0], acc[i][1], acc[i][2], acc[i][3]);
    *(float4*)(Cm + (size_t)(bm0 + ty * 4 + i) * N + bn0 + tx * 4) = v;
  }
}

// ---------------- split fp32 -> bf16 hi/lo MFMA GEMM for layer 5, fused reduction ----------------
__device__ inline void split8(const float* __restrict__ p, bf16x8* hv, bf16x8* lv) {
  float4 a0 = *(const float4*)p, a1 = *(const float4*)(p + 4);
  float v[8] = {a0.x, a0.y, a0.z, a0.w, a1.x, a1.y, a1.z, a1.w};
  bf16x8 h, l;
  #pragma unroll
  for (int j = 0; j < 8; ++j) {
    bf16 hj = (bf16)v[j];
    h[j] = hj;
    l[j] = (bf16)(v[j] - (float)hj);
  }
  *hv = h; *lv = l;
}

__global__ __launch_bounds__(256) void gemm_split_red(const float* __restrict__ A, int lda,
                                                      const float* __restrict__ Bt, int ldb,
                                                      float* __restrict__ parts, int K) {
  __shared__ u16 Ah[128 * 64];
  __shared__ u16 Al[128 * 64];
  __shared__ u16 Bh[128 * 64];
  __shared__ u16 Bl[128 * 64];
  int tid = threadIdx.x;
  int wave = tid >> 6, lane = tid & 63;
  int wr = wave >> 1, wc = wave & 1;
  int bn0 = blockIdx.x * 128, bm0 = blockIdx.y * 128;
  int lrow = lane & 15;
  int kgrp = lane >> 4;

  f32x4 acc[4][4];
  #pragma unroll
  for (int i = 0; i < 4; ++i)
    #pragma unroll
    for (int j = 0; j < 4; ++j) acc[i][j] = (f32x4){0.f, 0.f, 0.f, 0.f};

  for (int k0 = 0; k0 < K; k0 += 64) {
    #pragma unroll
    for (int i = 0; i < 4; ++i) {
      int chunk = tid + i * 256;
      int row = chunk >> 3;
      int cc = (chunk & 7) * 8;
      int byte = row * 128 + ((cc * 2) ^ ((row & 7) << 4));
      bf16x8 h, l;
      split8(A + (size_t)(bm0 + row) * lda + k0 + cc, &h, &l);
      *(bf16x8*)((char*)Ah + byte) = h;
      *(bf16x8*)((char*)Al + byte) = l;
      split8(Bt + (size_t)(bn0 + row) * ldb + k0 + cc, &h, &l);
      *(bf16x8*)((char*)Bh + byte) = h;
      *(bf16x8*)((char*)Bl + byte) = l;
    }
    __syncthreads();
    #pragma unroll
    for (int kk = 0; kk < 64; kk += 32) {
      int kb = (kk + kgrp * 8) * 2;
      bf16x8 afh[4], afl[4], bfh[4], bfl[4];
      #pragma unroll
      for (int f = 0; f < 4; ++f) {
        int arow = wr * 64 + f * 16 + lrow;
        int abyte = arow * 128 + (kb ^ ((arow & 7) << 4));
        afh[f] = *(const bf16x8*)((const char*)Ah + abyte);
        afl[f] = *(const bf16x8*)((const char*)Al + abyte);
        int brow = wc * 64 + f * 16 + lrow;
        int bbyte = brow * 128 + (kb ^ ((brow & 7) << 4));
        bfh[f] = *(const bf16x8*)((const char*)Bh + bbyte);
        bfl[f] = *(const bf16x8*)((const char*)Bl + bbyte);
      }
      #pragma unroll
      for (int fm = 0; fm < 4; ++fm)
        #pragma unroll
        for (int fn = 0; fn < 4; ++fn) {
          acc[fm][fn] = __builtin_amdgcn_mfma_f32_16x16x32_bf16(afh[fm], bfh[fn], acc[fm][fn], 0, 0, 0);
          acc[fm][fn] = __builtin_amdgcn_mfma_f32_16x16x32_bf16(afl[fm], bfh[fn], acc[fm][fn], 0, 0, 0);
          acc[fm][fn] = __builtin_amdgcn_mfma_f32_16x16x32_bf16(afh[fm], bfl[fn], acc[fm][fn], 0, 0, 0);
        }
    }
    __syncthreads();
  }

  float* scratch = (float*)Ah;
  int contrib = wr * 4 + kgrp;
  #pragma unroll
  for (int fn = 0; fn < 4; ++fn) {
    float mx = -3.4e38f, mn = 3.4e38f, s1 = 0.f, s2 = 0.f;
    #pragma unroll
    for (int fm = 0; fm < 4; ++fm)
      #pragma unroll
      for (int r = 0; r < 4; ++r) {
        float v = acc[fm][fn][r];
        mx = fmaxf(mx, v); mn = fminf(mn, v);
        s1 += v; s2 = fmaf(v, v, s2);
      }
    int col = wc * 64 + fn * 16 + lrow;
    float* sp = scratch + (contrib * 128 + col) * 4;
    sp[0] = mx; sp[1] = mn; sp[2] = s1; sp[3] = s2;
  }
  __syncthreads();
  if (tid < 128) {
    float mx = -3.4e38f, mn = 3.4e38f, s1 = 0.f, s2 = 0.f;
    #pragma unroll
    for (int c2 = 0; c2 < 8; ++c2) {
      const float* sp = scratch + (c2 * 128 + tid) * 4;
      mx = fmaxf(mx, sp[0]); mn = fminf(mn, sp[1]);
      s1 += sp[2]; s2 += sp[3];
    }
    size_t o = (size_t)blockIdx.y * 1024 + bn0 + tid;
    parts[o] = mx;
    parts[65536 + o] = mn;
    parts[131072 + o] = s1;
    parts[196608 + o] = s2;
  }
}

// ---------------- edge aggregation (vectorized): lane owns VW=O/64 channels ----------
// One warp per point; per k ONE float{VW} gather (coalesced 1KB/wave). y-stats over k,
// a combined analytically: max_k(a+y)=a+max_k y; s1_h=20a+s1_y; s2_h=s2_y+a(2 s1_y+20a).
// XCD swizzle: blocks with bid%8==r handle batch r (2MB y-region -> XCD-L2 hits).
template<int VW>
__global__ __launch_bounds__(256) void aggregate_t(const float* __restrict__ ay,
                                                   const int* __restrict__ idxb, int O,
                                                   float* __restrict__ mx,
                                                   float* __restrict__ mn,
                                                   float* __restrict__ sumsbin) {
  __shared__ float ls1[4][256];
  __shared__ float ls2[4][256];
  int warp = threadIdx.x >> 6, lane = threadIdx.x & 63;
  int bid = blockIdx.x;
  int swz = (bid & 7) * 256 + (bid >> 3);   // 2048 blocks -> batch = bid&7
  int pt = swz * 4 + warp;                  // 0..8191
  int b = pt >> 10;
  int twoO = 2 * O;
  int o0 = lane * VW;
  const float* ayrow = ay + (size_t)pt * twoO;

  int idxs[KNN_K];
  const int* ip = idxb + pt * KNN_K;
  #pragma unroll
  for (int k = 0; k < KNN_K; ++k) idxs[k] = ip[k];

  float s1[VW], s2[VW], vmx[VW], vmn[VW];
  #pragma unroll
  for (int u = 0; u < VW; ++u) { s1[u] = 0.f; s2[u] = 0.f; vmx[u] = -3.4e38f; vmn[u] = 3.4e38f; }

  #pragma unroll
  for (int k = 0; k < KNN_K; ++k) {
    const float* yp = ay + (size_t)(b * N_PTS + idxs[k]) * twoO + O + o0;
    float v[VW];
    if (VW == 4)      { float4 t = *(const float4*)yp; v[0] = t.x; v[1] = t.y; v[2] = t.z; v[3] = t.w; }
    else if (VW == 2) { float2 t = *(const float2*)yp; v[0] = t.x; v[1] = t.y; }
    else              { v[0] = yp[0]; }
    #pragma unroll
    for (int u = 0; u < VW; ++u) {
      s1[u] += v[u]; s2[u] = fmaf(v[u], v[u], s2[u]);
      vmx[u] = fmaxf(vmx[u], v[u]); vmn[u] = fminf(vmn[u], v[u]);
    }
  }

  float a[VW], omx[VW], omn[VW];
  if (VW == 4)      { float4 t = *(const float4*)(ayrow + o0); a[0] = t.x; a[1] = t.y; a[2] = t.z; a[3] = t.w; }
  else if (VW == 2) { float2 t = *(const float2*)(ayrow + o0); a[0] = t.x; a[1] = t.y; }
  else              { a[0] = ayrow[o0]; }
  #pragma unroll
  for (int u = 0; u < VW; ++u) {
    omx[u] = a[u] + vmx[u];
    omn[u] = a[u] + vmn[u];
    ls1[warp][o0 + u] = fmaf(20.f, a[u], s1[u]);
    ls2[warp][o0 + u] = s2[u] + a[u] * fmaf(20.f, a[u], 2.f * s1[u]);
  }
  if (VW == 4) {
    *(float4*)(mx + (size_t)pt * O + o0) = make_float4(omx[0], omx[1], omx[2], omx[3]);
    *(float4*)(mn + (size_t)pt * O + o0) = make_float4(omn[0], omn[1], omn[2], omn[3]);
  } else if (VW == 2) {
    *(float2*)(mx + (size_t)pt * O + o0) = make_float2(omx[0], omx[1]);
    *(float2*)(mn + (size_t)pt * O + o0) = make_float2(omn[0], omn[1]);
  } else {
    mx[(size_t)pt * O + o0] = omx[0];
    mn[(size_t)pt * O + o0] = omn[0];
  }
  __syncthreads();
  int bin = blockIdx.x & 63;
  float* gb = sumsbin + (size_t)bin * 512;
  for (int o = threadIdx.x; o < O; o += 256) {
    float t1 = ls1[0][o] + ls1[1][o] + ls1[2][o] + ls1[3][o];
    float t2 = ls2[0][o] + ls2[1][o] + ls2[2][o] + ls2[3][o];
    atomicAdd(&gb[o], t1);
    atomicAdd(&gb[256 + o], t2);
  }
}

__global__ __launch_bounds__(256) void reduce_bins(const float* __restrict__ sumsbin,
                                                   float* __restrict__ sums, int O) {
  int o = threadIdx.x;
  if (o >= O) return;
  float a = 0.f, c = 0.f;
  for (int bin = 0; bin < 64; ++bin) {
    a += sumsbin[bin * 512 + o];
    c += sumsbin[bin * 512 + 256 + o];
  }
  sums[o] = a;
  sums[256 + o] = c;
}

// ---------------- finalize edge layer: BN + relu on (max or min depending on sign) ----------------
__global__ __launch_bounds__(256) void finalize_edge(const float* __restrict__ mx,
                                                     const float* __restrict__ mn,
                                                     const float* __restrict__ sums,
                                                     const float* __restrict__ g,
                                                     const float* __restrict__ beta,
                                                     int oshift,
                                                     float* __restrict__ outseg,
                                                     float cnt_inv) {
  int tid = blockIdx.x * 256 + threadIdx.x;
  int pt = tid >> oshift;
  int o = tid & ((1 << oshift) - 1);
  float s1 = sums[o], s2 = sums[256 + o];
  float mean = s1 * cnt_inv;
  float var = s2 * cnt_inv - mean * mean;
  float rstd = rsqrtf(var + BN_EPS);
  float sc = g[o] * rstd;
  float sel = (sc >= 0.f) ? mx[tid] : mn[tid];
  float v = (sel - mean) * sc + beta[o];
  outseg[(size_t)pt * CAT_C + o] = fmaxf(v, 0.f);
}

// ---------------- layer 5 finalize from tile partials ----------------
__global__ __launch_bounds__(256) void finalize5_fused(const float* __restrict__ parts,
                                                       const float* __restrict__ g,
                                                       const float* __restrict__ beta,
                                                       float* __restrict__ out) {
  int tid = blockIdx.x * 256 + threadIdx.x;
  int b = tid >> 10, o = tid & 1023;
  const float* pmx = parts;
  const float* pmn = parts + 65536;
  const float* ps1 = parts + 131072;
  const float* ps2 = parts + 196608;
  float s1 = 0.f, s2 = 0.f;
  for (int t = 0; t < 64; ++t) { s1 += ps1[t * 1024 + o]; s2 += ps2[t * 1024 + o]; }
  float mx = -3.4e38f, mn = 3.4e38f;
  #pragma unroll
  for (int t = 0; t < 8; ++t) {
    mx = fmaxf(mx, pmx[(b * 8 + t) * 1024 + o]);
    mn = fminf(mn, pmn[(b * 8 + t) * 1024 + o]);
  }
  float mean = s1 * (1.0f / 8192.0f);
  float var = s2 * (1.0f / 8192.0f) - mean * mean;
  float rstd = rsqrtf(var + BN_EPS);
  float sc = g[o] * rstd;
  float sel = (sc >= 0.f) ? mx : mn;
  float v = (sel - mean) * sc + beta[o];
  out[tid] = fmaxf(v, 0.f);
}

extern "C" void kernel_launch(void* const* d_in, const int* in_sizes, int n_in,
                              void* d_out, int out_size, void* d_ws, size_t ws_size,
                              hipStream_t stream) {
  const float* x = (const float*)d_in[0];
  const float* w[5]  = {(const float*)d_in[1], (const float*)d_in[4], (const float*)d_in[7],
                        (const float*)d_in[10], (const float*)d_in[13]};
  const float* gg[5] = {(const float*)d_in[2], (const float*)d_in[5], (const float*)d_in[8],
                        (const float*)d_in[11], (const float*)d_in[14]};
  const float* bb[5] = {(const float*)d_in[3], (const float*)d_in[6], (const float*)d_in[9],
                        (const float*)d_in[12], (const float*)d_in[15]};
  float* out = (float*)d_out;

  float* W = (float*)d_ws;
  size_t off = 0;
  float* feat0   = W + off; off += (size_t)B_SZ * N_PTS * 4;   // stride-4 padded
  float* catbuf  = W + off; off += (size_t)8192 * CAT_C;
  int*   idxbuf  = (int*)(W + off); off += (size_t)8192 * KNN_K;
  float* aybuf   = W + off; off += (size_t)8192 * 1024;
  float* mxbuf   = W + off; off += (size_t)8192 * 256;
  float* mnbuf   = W + off; off += (size_t)8192 * 256;
  float* wcbuf   = W + off; off += (size_t)512 * 1024;
  float* sumsbin = W + off; off += (size_t)64 * 512;
  float* sums    = W + off; off += 512;
  float* parts   = W + off; off += (size_t)4 * 64 * 1024;
  float* x2buf   = W + off; off += 8192;
  bf16*  packH   = (bf16*)(W + off); off += (size_t)8192 * 128 / 2;   // 2MB
  bf16*  packM   = (bf16*)(W + off); off += (size_t)8192 * 128 / 2;   // 2MB
  bf16*  packL   = (bf16*)(W + off); off += (size_t)8192 * 128 / 2;   // 2MB

  hipMemsetAsync(feat0, 0, (size_t)B_SZ * N_PTS * 4 * sizeof(float), stream);
  transpose_x<<<(B_SZ * 3 * N_PTS + 255) / 256, 256, 0, stream>>>(x, feat0);

  const int Cs[4] = {4, 64, 64, 128};   // layer-0 padded to 4 (pad=0, values unchanged)
  const int Ks[4] = {3, 64, 64, 128};   // true K for the edge GEMM
  const int Os[4] = {64, 64, 128, 256};
  const int osh[4] = {6, 6, 7, 8};
  const int segin[4] = {0, 0, 64, 128};
  const int segout[4] = {0, 64, 128, 256};

  for (int l = 0; l < 4; ++l) {
    int C = Cs[l], O = Os[l], twoO = 2 * O;
    const float* featin = (l == 0) ? feat0 : (catbuf + segin[l]);
    int lda = (l == 0) ? 4 : CAT_C;
    int nks = (C + 31) / 32;            // 1,2,2,4

    xnorm_kernel<<<32, 256, 0, stream>>>(featin, lda, C, x2buf);
    split_pack<<<512, 256, 0, stream>>>(featin, lda, C, packH, packM, packL);
    knn_mfma<<<512, 1024, 0, stream>>>(packH, packM, packL, x2buf, nks, idxbuf);

    build_wc<<<(Ks[l] * twoO + 255) / 256, 256, 0, stream>>>(w[l], Ks[l], O, wcbuf);
    gemm_kernel<<<dim3(twoO / 64, 8192 / 64), 256, 0, stream>>>(featin, lda, wcbuf, aybuf,
                                                                8192, twoO, Ks[l]);
    hipMemsetAsync(sumsbin, 0, (size_t)64 * 512 * sizeof(float), stream);
    if (O == 256)
      aggregate_t<4><<<2048, 256, 0, stream>>>(aybuf, idxbuf, O, mxbuf, mnbuf, sumsbin);
    else if (O == 128)
      aggregate_t<2><<<2048, 256, 0, stream>>>(aybuf, idxbuf, O, mxbuf, mnbuf, sumsbin);
    else
      aggregate_t<1><<<2048, 256, 0, stream>>>(aybuf, idxbuf, O, mxbuf, mnbuf, sumsbin);
    reduce_bins<<<1, 256, 0, stream>>>(sumsbin, sums, O);
    finalize_edge<<<(8192 * O) / 256, 256, 0, stream>>>(mxbuf, mnbuf, sums, gg[l], bb[l],
                                                        osh[l], catbuf + segout[l],
                                                        1.0f / (8192.0f * KNN_K));
  }

  // layer 5: h5 = cat * w5^T via split-bf16 MFMA with fused per-tile reduction
  gemm_split_red<<<dim3(1024 / 128, 8192 / 128), 256, 0, stream>>>(catbuf, CAT_C, w[4], 512,
                                                                   parts, 512);
  finalize5_fused<<<8192 / 256, 256, 0, stream>>>(parts, gg[4], bb[4], out);
}

// Round 21
// 370.886 us; speedup vs baseline: 1.4961x; 1.0446x over previous
//
#include <hip/hip_runtime.h>
#include <cstddef>

#define B_SZ 8
#define N_PTS 1024
#define KNN_K 20
#define CAT_C 512
#define BN_EPS 1e-5f

typedef unsigned short u16;
typedef unsigned int u32;
typedef __bf16 bf16;
typedef __bf16 bf16x8 __attribute__((ext_vector_type(8)));
typedef float f32x4 __attribute__((ext_vector_type(4)));

// ---------------- transpose x (B,3,N) -> feat0 (B,N,4) (col 3 pre-zeroed) ----------------
__global__ __launch_bounds__(256) void transpose_x(const float* __restrict__ x,
                                                   float* __restrict__ feat0) {
  int t = blockIdx.x * 256 + threadIdx.x;
  if (t >= B_SZ * 3 * N_PTS) return;
  int b = t / (3 * N_PTS);
  int r = t - b * 3 * N_PTS;
  int c = r / N_PTS;
  int n = r - c * N_PTS;
  feat0[((size_t)(b * N_PTS + n)) * 4 + c] = x[t];
}

// ---------------- squared norms per point (exact fp32) ----------------
__global__ __launch_bounds__(256) void xnorm_kernel(const float* __restrict__ feat, int lda,
                                                    int C, float* __restrict__ x2) {
  int p = blockIdx.x * 256 + threadIdx.x;
  if (p >= 8192) return;
  const float* r = feat + (size_t)p * lda;
  float s = 0.f;
  for (int c = 0; c < C; c += 4) {
    float4 v = *(const float4*)(r + c);
    s = fmaf(v.x, v.x, s); s = fmaf(v.y, v.y, s);
    s = fmaf(v.z, v.z, s); s = fmaf(v.w, v.w, s);
  }
  x2[p] = s;
}

// ---------------- triple-split features, B-coalesced layout --------------------------
__global__ __launch_bounds__(256) void split_pack(const float* __restrict__ feat, int lda,
                                                  int C, bf16* __restrict__ packH,
                                                  bf16* __restrict__ packM,
                                                  bf16* __restrict__ packL) {
  int t = blockIdx.x * 256 + threadIdx.x;     // 8192*16 threads, 8 k's each
  if (t >= 8192 * 16) return;
  int p = t >> 4, c = t & 15;                 // p = global point, c = q plane
  int b = p >> 10, col = p & 1023;
  int k0 = c * 8;
  bf16x8 h, m, l;
  #pragma unroll
  for (int e = 0; e < 8; ++e) {
    int k = k0 + e;
    float v = (k < C) ? feat[(size_t)p * lda + k] : 0.f;
    bf16 hb = (bf16)v;       float r1 = v - (float)hb;
    bf16 mb = (bf16)r1;      float r2 = r1 - (float)mb;
    bf16 lb = (bf16)r2;
    h[e] = hb; m[e] = mb; l[e] = lb;
  }
  size_t dst = ((size_t)(b * 16 + c) * 1024 + col) * 8;
  *(bf16x8*)(packH + dst) = h;
  *(bf16x8*)(packM + dst) = m;
  *(bf16x8*)(packL + dst) = l;
}

// ---- DPP value-reduce stages (tree verified bit-exact in R10/R11/R16) ----
#define DPP_MAX_STAGE(CTRL)                                                          \
  {                                                                                  \
    int nb = __builtin_amdgcn_update_dpp((int)0xFF800000, __float_as_int(mx),        \
                                         (CTRL), 0xF, 0xF, false);                   \
    mx = fmaxf(mx, __int_as_float(nb));                                              \
  }
#define DPP_MIN_STAGE(CTRL)                                                          \
  {                                                                                  \
    int nb = __builtin_amdgcn_update_dpp((int)0x7fffffff, mc,                        \
                                         (CTRL), 0xF, 0xF, false);                   \
    mc = (nb < mc) ? nb : mc;                                                        \
  }

// ---------------- KNN: triple-split MFMA distances + R16 DPP selection ----------------
__global__ __launch_bounds__(1024) void knn_mfma(const bf16* __restrict__ packH,
                                                 const bf16* __restrict__ packM,
                                                 const bf16* __restrict__ packL,
                                                 const float* __restrict__ x2,
                                                 int nks,
                                                 int* __restrict__ idxout) {
  __shared__ u16 Ah[16 * 128];        // 4KB each, row stride 256B, XOR-swizzled
  __shared__ u16 Am[16 * 128];
  __shared__ u16 Al[16 * 128];
  __shared__ float Ds[16 * 1028];     // 65.8KB, padded stride
  int tid = threadIdx.x;
  int w = tid >> 6, lane = tid & 63;
  int bid = blockIdx.x;
  int swz = (bid & 7) * 64 + (bid >> 3);   // 512 blocks -> batch = bid&7
  int row0 = swz * 16;
  int b = row0 >> 10;
  int col0 = row0 & 1023;

  if (tid < 256) {
    int r = tid >> 4, c = tid & 15;   // c = q plane
    int byte = r * 256 + ((c * 16) ^ ((r & 7) << 4));
    size_t src = ((size_t)(b * 16 + c) * 1024 + col0 + r) * 8;
    *(bf16x8*)((char*)Ah + byte) = *(const bf16x8*)(packH + src);
    *(bf16x8*)((char*)Am + byte) = *(const bf16x8*)(packM + src);
    *(bf16x8*)((char*)Al + byte) = *(const bf16x8*)(packL + src);
  }
  __syncthreads();

  int lrow = lane & 15, kgrp = lane >> 4;
  int abase = lrow * 256;

  f32x4 acc[4];
  #pragma unroll
  for (int f = 0; f < 4; ++f) acc[f] = (f32x4){0.f, 0.f, 0.f, 0.f};

  for (int ks = 0; ks < nks; ++ks) {
    int kb = (ks * 32 + kgrp * 8) * 2;
    int aoff = abase + (kb ^ ((lrow & 7) << 4));
    bf16x8 a_h = *(const bf16x8*)((const char*)Ah + aoff);
    bf16x8 a_m = *(const bf16x8*)((const char*)Am + aoff);
    bf16x8 a_l = *(const bf16x8*)((const char*)Al + aoff);
    int q = ks * 4 + kgrp;
    size_t pbase = (size_t)(b * 16 + q) * 1024;
    #pragma unroll
    for (int f = 0; f < 4; ++f) {
      int col = w * 64 + f * 16 + lrow;
      bf16x8 b_h = *(const bf16x8*)(packH + (pbase + col) * 8);
      bf16x8 b_m = *(const bf16x8*)(packM + (pbase + col) * 8);
      bf16x8 b_l = *(const bf16x8*)(packL + (pbase + col) * 8);
      acc[f] = __builtin_amdgcn_mfma_f32_16x16x32_bf16(a_h, b_h, acc[f], 0, 0, 0);
      acc[f] = __builtin_amdgcn_mfma_f32_16x16x32_bf16(a_h, b_m, acc[f], 0, 0, 0);
      acc[f] = __builtin_amdgcn_mfma_f32_16x16x32_bf16(a_m, b_h, acc[f], 0, 0, 0);
      acc[f] = __builtin_amdgcn_mfma_f32_16x16x32_bf16(a_m, b_m, acc[f], 0, 0, 0);
      acc[f] = __builtin_amdgcn_mfma_f32_16x16x32_bf16(a_h, b_l, acc[f], 0, 0, 0);
      acc[f] = __builtin_amdgcn_mfma_f32_16x16x32_bf16(a_l, b_h, acc[f], 0, 0, 0);
      acc[f] = __builtin_amdgcn_mfma_f32_16x16x32_bf16(a_m, b_l, acc[f], 0, 0, 0);
      acc[f] = __builtin_amdgcn_mfma_f32_16x16x32_bf16(a_l, b_m, acc[f], 0, 0, 0);
    }
  }
  // D epilogue (m89-verified layout: row=(lane>>4)*4+r, col=lane&15)
  #pragma unroll
  for (int f = 0; f < 4; ++f) {
    int col = w * 64 + f * 16 + lrow;
    #pragma unroll
    for (int r = 0; r < 4; ++r)
      Ds[(kgrp * 4 + r) * 1028 + col] = acc[f][r];
  }
  __syncthreads();

  // selection: wave w handles row w (R16 passer, verbatim semantics)
  const float* x2b = x2 + b * N_PTS;
  int row = row0 + w;
  float x2n = x2[row];
  float accv[16];
  #pragma unroll
  for (int j = 0; j < 16; ++j) {
    float d = Ds[w * 1028 + j * 64 + lane];
    accv[j] = (2.f * d - x2n) - x2b[j * 64 + lane];
  }

  for (int rr = 0; rr < KNN_K; ++rr) {
    float m01 = fmaxf(accv[0], accv[1]),   m23 = fmaxf(accv[2], accv[3]);
    float m45 = fmaxf(accv[4], accv[5]),   m67 = fmaxf(accv[6], accv[7]);
    float m89 = fmaxf(accv[8], accv[9]),   mab = fmaxf(accv[10], accv[11]);
    float mcd = fmaxf(accv[12], accv[13]), mef = fmaxf(accv[14], accv[15]);
    float mx = fmaxf(fmaxf(fmaxf(m01, m23), fmaxf(m45, m67)),
                     fmaxf(fmaxf(m89, mab), fmaxf(mcd, mef)));
    DPP_MAX_STAGE(0x111)
    DPP_MAX_STAGE(0x112)
    DPP_MAX_STAGE(0x114)
    DPP_MAX_STAGE(0x118)
    DPP_MAX_STAGE(0x142)
    DPP_MAX_STAGE(0x143)
    mx = __int_as_float(__builtin_amdgcn_readlane(__float_as_int(mx), 63));

    int jloc = 16;
    #pragma unroll
    for (int j = 15; j >= 0; --j)
      if (accv[j] == mx) jloc = j;
    int mc = (jloc < 16) ? ((jloc << 6) | lane) : 0x7fffffff;
    DPP_MIN_STAGE(0x111)
    DPP_MIN_STAGE(0x112)
    DPP_MIN_STAGE(0x114)
    DPP_MIN_STAGE(0x118)
    DPP_MIN_STAGE(0x142)
    DPP_MIN_STAGE(0x143)
    int si = __builtin_amdgcn_readlane(mc, 63);

    int jj = si >> 6, ln = si & 63;
    bool isln = (lane == ln);
    #pragma unroll
    for (int j = 0; j < 16; ++j)
      if (j == jj && isln) accv[j] = -3.4e38f;
    if (lane == 0) idxout[row * KNN_K + rr] = si;
  }
}

// ---------------- build transposed combined weight (fp32): wcT[j][c], j in [0,2O) ------
__global__ __launch_bounds__(256) void build_wcT(const float* __restrict__ w, int C, int O,
                                                 float* __restrict__ wcT) {
  int t = blockIdx.x * 256 + threadIdx.x;
  if (t >= 2 * O * C) return;
  int j = t / C, c = t - j * C;
  float v;
  if (j < O) v = w[j * (2 * C) + c] - w[j * (2 * C) + C + c];
  else       v = w[(j - O) * (2 * C) + C + c];
  wcT[t] = v;
}

// ---------------- build combined weight Wc (fp32): [w1-w2 | w2] (layer 0 only) ---------
__global__ __launch_bounds__(256) void build_wc(const float* __restrict__ w, int C, int O,
                                                float* __restrict__ wc) {
  int t = blockIdx.x * 256 + threadIdx.x;
  int twoO = 2 * O;
  if (t >= C * twoO) return;
  int c = t / twoO, j = t - c * twoO;
  float v;
  if (j < O) v = w[j * (2 * C) + c] - w[j * (2 * C) + C + c];
  else       v = w[(j - O) * (2 * C) + C + c];
  wc[t] = v;
}

// ---------------- fp32 GEMM (layer 0 only, K=3): C[M,N] = A[M,K](lda) * B[K,N] ---------
__global__ __launch_bounds__(256) void gemm_kernel(const float* __restrict__ A, int lda,
                                                   const float* __restrict__ Bm,
                                                   float* __restrict__ Cm,
                                                   int M, int N, int K) {
  __shared__ float As[16][64];
  __shared__ float Bs[16][68];
  int tx = threadIdx.x & 15, ty = threadIdx.x >> 4;
  int bn0 = blockIdx.x * 64, bm0 = blockIdx.y * 64;
  float acc[4][4];
  #pragma unroll
  for (int i = 0; i < 4; ++i)
    #pragma unroll
    for (int j = 0; j < 4; ++j) acc[i][j] = 0.f;

  for (int k0 = 0; k0 < K; k0 += 16) {
    {
      int t = threadIdx.x;
      int m = t >> 2, kb = (t & 3) * 4;
      const float* ap = A + (size_t)(bm0 + m) * lda + k0 + kb;
      #pragma unroll
      for (int i = 0; i < 4; ++i) As[kb + i][m] = (k0 + kb + i < K) ? ap[i] : 0.f;
      int r = t >> 4, c4 = (t & 15) * 4;
      float4 bv = make_float4(0.f, 0.f, 0.f, 0.f);
      if (k0 + r < K) bv = *(const float4*)(Bm + (size_t)(k0 + r) * N + bn0 + c4);
      *(float4*)&Bs[r][c4] = bv;
    }
    __syncthreads();
    #pragma unroll
    for (int k = 0; k < 16; ++k) {
      float a0[4];
      #pragma unroll
      for (int i = 0; i < 4; ++i) a0[i] = As[k][ty * 4 + i];
      float4 bv = *(const float4*)&Bs[k][tx * 4];
      float b0[4] = {bv.x, bv.y, bv.z, bv.w};
      #pragma unroll
      for (int i = 0; i < 4; ++i)
        #pragma unroll
        for (int j = 0; j < 4; ++j) acc[i][j] = fmaf(a0[i], b0[j], acc[i][j]);
    }
    __syncthreads();
  }
  #pragma unroll
  for (int i = 0; i < 4; ++i) {
    float4 v = make_float4(acc[i][0], acc[i][1], acc[i][2], acc[i][3]);
    *(float4*)(Cm + (size_t)(bm0 + ty * 4 + i) * N + bn0 + tx * 4) = v;
  }
}

// ---------------- split fp32 -> bf16 hi/lo helpers ----------------
__device__ inline void split8(const float* __restrict__ p, bf16x8* hv, bf16x8* lv) {
  float4 a0 = *(const float4*)p, a1 = *(const float4*)(p + 4);
  float v[8] = {a0.x, a0.y, a0.z, a0.w, a1.x, a1.y, a1.z, a1.w};
  bf16x8 h, l;
  #pragma unroll
  for (int j = 0; j < 8; ++j) {
    bf16 hj = (bf16)v[j];
    h[j] = hj;
    l[j] = (bf16)(v[j] - (float)hj);
  }
  *hv = h; *lv = l;
}

// ---------------- split-bf16 MFMA GEMM, direct C-write (R4-verified passer) ------------
// C[M,N] = A[M,K](lda) * Bt[N,K](ldb)^T, ~fp32 accuracy (Markidis 3-term).
// K%64==0, M%128==0, N%128==0. Used for edge GEMMs l=1..3 (no selection downstream).
__global__ __launch_bounds__(256) void gemm_split(const float* __restrict__ A, int lda,
                                                  const float* __restrict__ Bt, int ldb,
                                                  float* __restrict__ C, int N, int K) {
  __shared__ u16 Ah[128 * 64];
  __shared__ u16 Al[128 * 64];
  __shared__ u16 Bh[128 * 64];
  __shared__ u16 Bl[128 * 64];
  int tid = threadIdx.x;
  int wave = tid >> 6, lane = tid & 63;
  int wr = wave >> 1, wc = wave & 1;
  int bn0 = blockIdx.x * 128, bm0 = blockIdx.y * 128;
  int lrow = lane & 15;
  int kgrp = lane >> 4;

  f32x4 acc[4][4];
  #pragma unroll
  for (int i = 0; i < 4; ++i)
    #pragma unroll
    for (int j = 0; j < 4; ++j) acc[i][j] = (f32x4){0.f, 0.f, 0.f, 0.f};

  for (int k0 = 0; k0 < K; k0 += 64) {
    #pragma unroll
    for (int i = 0; i < 4; ++i) {
      int chunk = tid + i * 256;
      int row = chunk >> 3;
      int cc = (chunk & 7) * 8;
      int byte = row * 128 + ((cc * 2) ^ ((row & 7) << 4));
      bf16x8 h, l;
      split8(A + (size_t)(bm0 + row) * lda + k0 + cc, &h, &l);
      *(bf16x8*)((char*)Ah + byte) = h;
      *(bf16x8*)((char*)Al + byte) = l;
      split8(Bt + (size_t)(bn0 + row) * ldb + k0 + cc, &h, &l);
      *(bf16x8*)((char*)Bh + byte) = h;
      *(bf16x8*)((char*)Bl + byte) = l;
    }
    __syncthreads();
    #pragma unroll
    for (int kk = 0; kk < 64; kk += 32) {
      int kb = (kk + kgrp * 8) * 2;
      bf16x8 afh[4], afl[4], bfh[4], bfl[4];
      #pragma unroll
      for (int f = 0; f < 4; ++f) {
        int arow = wr * 64 + f * 16 + lrow;
        int abyte = arow * 128 + (kb ^ ((arow & 7) << 4));
        afh[f] = *(const bf16x8*)((const char*)Ah + abyte);
        afl[f] = *(const bf16x8*)((const char*)Al + abyte);
        int brow = wc * 64 + f * 16 + lrow;
        int bbyte = brow * 128 + (kb ^ ((brow & 7) << 4));
        bfh[f] = *(const bf16x8*)((const char*)Bh + bbyte);
        bfl[f] = *(const bf16x8*)((const char*)Bl + bbyte);
      }
      #pragma unroll
      for (int fm = 0; fm < 4; ++fm)
        #pragma unroll
        for (int fn = 0; fn < 4; ++fn) {
          acc[fm][fn] = __builtin_amdgcn_mfma_f32_16x16x32_bf16(afh[fm], bfh[fn], acc[fm][fn], 0, 0, 0);
          acc[fm][fn] = __builtin_amdgcn_mfma_f32_16x16x32_bf16(afl[fm], bfh[fn], acc[fm][fn], 0, 0, 0);
          acc[fm][fn] = __builtin_amdgcn_mfma_f32_16x16x32_bf16(afh[fm], bfl[fn], acc[fm][fn], 0, 0, 0);
        }
    }
    __syncthreads();
  }
  // epilogue: D row=(lane>>4)*4+r, col=lane&15 (m89-verified; R4 passer)
  #pragma unroll
  for (int fm = 0; fm < 4; ++fm) {
    int mrow = bm0 + wr * 64 + fm * 16 + kgrp * 4;
    #pragma unroll
    for (int fn = 0; fn < 4; ++fn) {
      int ncol = bn0 + wc * 64 + fn * 16 + lrow;
      #pragma unroll
      for (int r = 0; r < 4; ++r)
        C[(size_t)(mrow + r) * N + ncol] = acc[fm][fn][r];
    }
  }
}

// ---------------- split-bf16 MFMA GEMM for layer 5 with fused reduction ---------------
__global__ __launch_bounds__(256) void gemm_split_red(const float* __restrict__ A, int lda,
                                                      const float* __restrict__ Bt, int ldb,
                                                      float* __restrict__ parts, int K) {
  __shared__ u16 Ah[128 * 64];
  __shared__ u16 Al[128 * 64];
  __shared__ u16 Bh[128 * 64];
  __shared__ u16 Bl[128 * 64];
  int tid = threadIdx.x;
  int wave = tid >> 6, lane = tid & 63;
  int wr = wave >> 1, wc = wave & 1;
  int bn0 = blockIdx.x * 128, bm0 = blockIdx.y * 128;
  int lrow = lane & 15;
  int kgrp = lane >> 4;

  f32x4 acc[4][4];
  #pragma unroll
  for (int i = 0; i < 4; ++i)
    #pragma unroll
    for (int j = 0; j < 4; ++j) acc[i][j] = (f32x4){0.f, 0.f, 0.f, 0.f};

  for (int k0 = 0; k0 < K; k0 += 64) {
    #pragma unroll
    for (int i = 0; i < 4; ++i) {
      int chunk = tid + i * 256;
      int row = chunk >> 3;
      int cc = (chunk & 7) * 8;
      int byte = row * 128 + ((cc * 2) ^ ((row & 7) << 4));
      bf16x8 h, l;
      split8(A + (size_t)(bm0 + row) * lda + k0 + cc, &h, &l);
      *(bf16x8*)((char*)Ah + byte) = h;
      *(bf16x8*)((char*)Al + byte) = l;
      split8(Bt + (size_t)(bn0 + row) * ldb + k0 + cc, &h, &l);
      *(bf16x8*)((char*)Bh + byte) = h;
      *(bf16x8*)((char*)Bl + byte) = l;
    }
    __syncthreads();
    #pragma unroll
    for (int kk = 0; kk < 64; kk += 32) {
      int kb = (kk + kgrp * 8) * 2;
      bf16x8 afh[4], afl[4], bfh[4], bfl[4];
      #pragma unroll
      for (int f = 0; f < 4; ++f) {
        int arow = wr * 64 + f * 16 + lrow;
        int abyte = arow * 128 + (kb ^ ((arow & 7) << 4));
        afh[f] = *(const bf16x8*)((const char*)Ah + abyte);
        afl[f] = *(const bf16x8*)((const char*)Al + abyte);
        int brow = wc * 64 + f * 16 + lrow;
        int bbyte = brow * 128 + (kb ^ ((brow & 7) << 4));
        bfh[f] = *(const bf16x8*)((const char*)Bh + bbyte);
        bfl[f] = *(const bf16x8*)((const char*)Bl + bbyte);
      }
      #pragma unroll
      for (int fm = 0; fm < 4; ++fm)
        #pragma unroll
        for (int fn = 0; fn < 4; ++fn) {
          acc[fm][fn] = __builtin_amdgcn_mfma_f32_16x16x32_bf16(afh[fm], bfh[fn], acc[fm][fn], 0, 0, 0);
          acc[fm][fn] = __builtin_amdgcn_mfma_f32_16x16x32_bf16(afl[fm], bfh[fn], acc[fm][fn], 0, 0, 0);
          acc[fm][fn] = __builtin_amdgcn_mfma_f32_16x16x32_bf16(afh[fm], bfl[fn], acc[fm][fn], 0, 0, 0);
        }
    }
    __syncthreads();
  }

  float* scratch = (float*)Ah;
  int contrib = wr * 4 + kgrp;
  #pragma unroll
  for (int fn = 0; fn < 4; ++fn) {
    float mx = -3.4e38f, mn = 3.4e38f, s1 = 0.f, s2 = 0.f;
    #pragma unroll
    for (int fm = 0; fm < 4; ++fm)
      #pragma unroll
      for (int r = 0; r < 4; ++r) {
        float v = acc[fm][fn][r];
        mx = fmaxf(mx, v); mn = fminf(mn, v);
        s1 += v; s2 = fmaf(v, v, s2);
      }
    int col = wc * 64 + fn * 16 + lrow;
    float* sp = scratch + (contrib * 128 + col) * 4;
    sp[0] = mx; sp[1] = mn; sp[2] = s1; sp[3] = s2;
  }
  __syncthreads();
  if (tid < 128) {
    float mx = -3.4e38f, mn = 3.4e38f, s1 = 0.f, s2 = 0.f;
    #pragma unroll
    for (int c2 = 0; c2 < 8; ++c2) {
      const float* sp = scratch + (c2 * 128 + tid) * 4;
      mx = fmaxf(mx, sp[0]); mn = fminf(mn, sp[1]);
      s1 += sp[2]; s2 += sp[3];
    }
    size_t o = (size_t)blockIdx.y * 1024 + bn0 + tid;
    parts[o] = mx;
    parts[65536 + o] = mn;
    parts[131072 + o] = s1;
    parts[196608 + o] = s2;
  }
}

// ---------------- edge aggregation (vectorized): lane owns VW=O/64 channels ----------
template<int VW>
__global__ __launch_bounds__(256) void aggregate_t(const float* __restrict__ ay,
                                                   const int* __restrict__ idxb, int O,
                                                   float* __restrict__ mx,
                                                   float* __restrict__ mn,
                                                   float* __restrict__ sumsbin) {
  __shared__ float ls1[4][256];
  __shared__ float ls2[4][256];
  int warp = threadIdx.x >> 6, lane = threadIdx.x & 63;
  int bid = blockIdx.x;
  int swz = (bid & 7) * 256 + (bid >> 3);   // 2048 blocks -> batch = bid&7
  int pt = swz * 4 + warp;                  // 0..8191
  int b = pt >> 10;
  int twoO = 2 * O;
  int o0 = lane * VW;
  const float* ayrow = ay + (size_t)pt * twoO;

  int idxs[KNN_K];
  const int* ip = idxb + pt * KNN_K;
  #pragma unroll
  for (int k = 0; k < KNN_K; ++k) idxs[k] = ip[k];

  float s1[VW], s2[VW], vmx[VW], vmn[VW];
  #pragma unroll
  for (int u = 0; u < VW; ++u) { s1[u] = 0.f; s2[u] = 0.f; vmx[u] = -3.4e38f; vmn[u] = 3.4e38f; }

  #pragma unroll
  for (int k = 0; k < KNN_K; ++k) {
    const float* yp = ay + (size_t)(b * N_PTS + idxs[k]) * twoO + O + o0;
    float v[VW];
    if (VW == 4)      { float4 t = *(const float4*)yp; v[0] = t.x; v[1] = t.y; v[2] = t.z; v[3] = t.w; }
    else if (VW == 2) { float2 t = *(const float2*)yp; v[0] = t.x; v[1] = t.y; }
    else              { v[0] = yp[0]; }
    #pragma unroll
    for (int u = 0; u < VW; ++u) {
      s1[u] += v[u]; s2[u] = fmaf(v[u], v[u], s2[u]);
      vmx[u] = fmaxf(vmx[u], v[u]); vmn[u] = fminf(vmn[u], v[u]);
    }
  }

  float a[VW], omx[VW], omn[VW];
  if (VW == 4)      { float4 t = *(const float4*)(ayrow + o0); a[0] = t.x; a[1] = t.y; a[2] = t.z; a[3] = t.w; }
  else if (VW == 2) { float2 t = *(const float2*)(ayrow + o0); a[0] = t.x; a[1] = t.y; }
  else              { a[0] = ayrow[o0]; }
  #pragma unroll
  for (int u = 0; u < VW; ++u) {
    omx[u] = a[u] + vmx[u];
    omn[u] = a[u] + vmn[u];
    ls1[warp][o0 + u] = fmaf(20.f, a[u], s1[u]);
    ls2[warp][o0 + u] = s2[u] + a[u] * fmaf(20.f, a[u], 2.f * s1[u]);
  }
  if (VW == 4) {
    *(float4*)(mx + (size_t)pt * O + o0) = make_float4(omx[0], omx[1], omx[2], omx[3]);
    *(float4*)(mn + (size_t)pt * O + o0) = make_float4(omn[0], omn[1], omn[2], omn[3]);
  } else if (VW == 2) {
    *(float2*)(mx + (size_t)pt * O + o0) = make_float2(omx[0], omx[1]);
    *(float2*)(mn + (size_t)pt * O + o0) = make_float2(omn[0], omn[1]);
  } else {
    mx[(size_t)pt * O + o0] = omx[0];
    mn[(size_t)pt * O + o0] = omn[0];
  }
  __syncthreads();
  int bin = blockIdx.x & 63;
  float* gb = sumsbin + (size_t)bin * 512;
  for (int o = threadIdx.x; o < O; o += 256) {
    float t1 = ls1[0][o] + ls1[1][o] + ls1[2][o] + ls1[3][o];
    float t2 = ls2[0][o] + ls2[1][o] + ls2[2][o] + ls2[3][o];
    atomicAdd(&gb[o], t1);
    atomicAdd(&gb[256 + o], t2);
  }
}

__global__ __launch_bounds__(256) void reduce_bins(const float* __restrict__ sumsbin,
                                                   float* __restrict__ sums, int O) {
  int o = threadIdx.x;
  if (o >= O) return;
  float a = 0.f, c = 0.f;
  for (int bin = 0; bin < 64; ++bin) {
    a += sumsbin[bin * 512 + o];
    c += sumsbin[bin * 512 + 256 + o];
  }
  sums[o] = a;
  sums[256 + o] = c;
}

// ---------------- finalize edge layer: BN + relu on (max or min depending on sign) ----------------
__global__ __launch_bounds__(256) void finalize_edge(const float* __restrict__ mx,
                                                     const float* __restrict__ mn,
                                                     const float* __restrict__ sums,
                                                     const float* __restrict__ g,
                                                     const float* __restrict__ beta,
                                                     int oshift,
                                                     float* __restrict__ outseg,
                                                     float cnt_inv) {
  int tid = blockIdx.x * 256 + threadIdx.x;
  int pt = tid >> oshift;
  int o = tid & ((1 << oshift) - 1);
  float s1 = sums[o], s2 = sums[256 + o];
  float mean = s1 * cnt_inv;
  float var = s2 * cnt_inv - mean * mean;
  float rstd = rsqrtf(var + BN_EPS);
  float sc = g[o] * rstd;
  float sel = (sc >= 0.f) ? mx[tid] : mn[tid];
  float v = (sel - mean) * sc + beta[o];
  outseg[(size_t)pt * CAT_C + o] = fmaxf(v, 0.f);
}

// ---------------- layer 5 finalize from tile partials ----------------
__global__ __launch_bounds__(256) void finalize5_fused(const float* __restrict__ parts,
                                                       const float* __restrict__ g,
                                                       const float* __restrict__ beta,
                                                       float* __restrict__ out) {
  int tid = blockIdx.x * 256 + threadIdx.x;
  int b = tid >> 10, o = tid & 1023;
  const float* pmx = parts;
  const float* pmn = parts + 65536;
  const float* ps1 = parts + 131072;
  const float* ps2 = parts + 196608;
  float s1 = 0.f, s2 = 0.f;
  for (int t = 0; t < 64; ++t) { s1 += ps1[t * 1024 + o]; s2 += ps2[t * 1024 + o]; }
  float mx = -3.4e38f, mn = 3.4e38f;
  #pragma unroll
  for (int t = 0; t < 8; ++t) {
    mx = fmaxf(mx, pmx[(b * 8 + t) * 1024 + o]);
    mn = fminf(mn, pmn[(b * 8 + t) * 1024 + o]);
  }
  float mean = s1 * (1.0f / 8192.0f);
  float var = s2 * (1.0f / 8192.0f) - mean * mean;
  float rstd = rsqrtf(var + BN_EPS);
  float sc = g[o] * rstd;
  float sel = (sc >= 0.f) ? mx : mn;
  float v = (sel - mean) * sc + beta[o];
  out[tid] = fmaxf(v, 0.f);
}

extern "C" void kernel_launch(void* const* d_in, const int* in_sizes, int n_in,
                              void* d_out, int out_size, void* d_ws, size_t ws_size,
                              hipStream_t stream) {
  const float* x = (const float*)d_in[0];
  const float* w[5]  = {(const float*)d_in[1], (const float*)d_in[4], (const float*)d_in[7],
                        (const float*)d_in[10], (const float*)d_in[13]};
  const float* gg[5] = {(const float*)d_in[2], (const float*)d_in[5], (const float*)d_in[8],
                        (const float*)d_in[11], (const float*)d_in[14]};
  const float* bb[5] = {(const float*)d_in[3], (const float*)d_in[6], (const float*)d_in[9],
                        (const float*)d_in[12], (const float*)d_in[15]};
  float* out = (float*)d_out;

  float* W = (float*)d_ws;
  size_t off = 0;
  float* feat0   = W + off; off += (size_t)B_SZ * N_PTS * 4;   // stride-4 padded
  float* catbuf  = W + off; off += (size_t)8192 * CAT_C;
  int*   idxbuf  = (int*)(W + off); off += (size_t)8192 * KNN_K;
  float* aybuf   = W + off; off += (size_t)8192 * 1024;
  float* mxbuf   = W + off; off += (size_t)8192 * 256;
  float* mnbuf   = W + off; off += (size_t)8192 * 256;
  float* wcbuf   = W + off; off += (size_t)512 * 1024;
  float* sumsbin = W + off; off += (size_t)64 * 512;
  float* sums    = W + off; off += 512;
  float* parts   = W + off; off += (size_t)4 * 64 * 1024;
  float* x2buf   = W + off; off += 8192;
  bf16*  packH   = (bf16*)(W + off); off += (size_t)8192 * 128 / 2;   // 2MB
  bf16*  packM   = (bf16*)(W + off); off += (size_t)8192 * 128 / 2;   // 2MB
  bf16*  packL   = (bf16*)(W + off); off += (size_t)8192 * 128 / 2;   // 2MB

  hipMemsetAsync(feat0, 0, (size_t)B_SZ * N_PTS * 4 * sizeof(float), stream);
  transpose_x<<<(B_SZ * 3 * N_PTS + 255) / 256, 256, 0, stream>>>(x, feat0);

  const int Cs[4] = {4, 64, 64, 128};   // layer-0 padded to 4 (pad=0, values unchanged)
  const int Ks[4] = {3, 64, 64, 128};   // true K for the edge GEMM
  const int Os[4] = {64, 64, 128, 256};
  const int osh[4] = {6, 6, 7, 8};
  const int segin[4] = {0, 0, 64, 128};
  const int segout[4] = {0, 64, 128, 256};

  for (int l = 0; l < 4; ++l) {
    int C = Cs[l], O = Os[l], twoO = 2 * O;
    const float* featin = (l == 0) ? feat0 : (catbuf + segin[l]);
    int lda = (l == 0) ? 4 : CAT_C;
    int nks = (C + 31) / 32;            // 1,2,2,4

    xnorm_kernel<<<32, 256, 0, stream>>>(featin, lda, C, x2buf);
    split_pack<<<512, 256, 0, stream>>>(featin, lda, C, packH, packM, packL);
    knn_mfma<<<512, 1024, 0, stream>>>(packH, packM, packL, x2buf, nks, idxbuf);

    if (l == 0) {
      build_wc<<<(Ks[l] * twoO + 255) / 256, 256, 0, stream>>>(w[l], Ks[l], O, wcbuf);
      gemm_kernel<<<dim3(twoO / 64, 8192 / 64), 256, 0, stream>>>(featin, lda, wcbuf, aybuf,
                                                                  8192, twoO, Ks[l]);
    } else {
      build_wcT<<<(twoO * Ks[l] + 255) / 256, 256, 0, stream>>>(w[l], Ks[l], O, wcbuf);
      gemm_split<<<dim3(twoO / 128, 8192 / 128), 256, 0, stream>>>(featin, lda, wcbuf,
                                                                   Ks[l], aybuf, twoO, Ks[l]);
    }
    hipMemsetAsync(sumsbin, 0, (size_t)64 * 512 * sizeof(float), stream);
    if (O == 256)
      aggregate_t<4><<<2048, 256, 0, stream>>>(aybuf, idxbuf, O, mxbuf, mnbuf, sumsbin);
    else if (O == 128)
      aggregate_t<2><<<2048, 256, 0, stream>>>(aybuf, idxbuf, O, mxbuf, mnbuf, sumsbin);
    else
      aggregate_t<1><<<2048, 256, 0, stream>>>(aybuf, idxbuf, O, mxbuf, mnbuf, sumsbin);
    reduce_bins<<<1, 256, 0, stream>>>(sumsbin, sums, O);
    finalize_edge<<<(8192 * O) / 256, 256, 0, stream>>>(mxbuf, mnbuf, sums, gg[l], bb[l],
                                                        osh[l], catbuf + segout[l],
                                                        1.0f / (8192.0f * KNN_K));
  }

  // layer 5: h5 = cat * w5^T via split-bf16 MFMA with fused per-tile reduction
  gemm_split_red<<<dim3(1024 / 128, 8192 / 128), 256, 0, stream>>>(catbuf, CAT_C, w[4], 512,
                                                                   parts, 512);
  finalize5_fused<<<8192 / 256, 256, 0, stream>>>(parts, gg[4], bb[4], out);
}

// Round 22
// 359.640 us; speedup vs baseline: 1.5429x; 1.0313x over previous
//
#include <hip/hip_runtime.h>
#include <cstddef>

#define B_SZ 8
#define N_PTS 1024
#define KNN_K 20
#define CAT_C 512
#define BN_EPS 1e-5f

typedef unsigned short u16;
typedef unsigned int u32;
typedef __bf16 bf16;
typedef __bf16 bf16x8 __attribute__((ext_vector_type(8)));
typedef float f32x4 __attribute__((ext_vector_type(4)));

// ---------------- transpose x (B,3,N) -> feat0 (B,N,4), pad col 3 = 0 ----------------
__global__ __launch_bounds__(256) void transpose_x(const float* __restrict__ x,
                                                   float* __restrict__ feat0) {
  int t = blockIdx.x * 256 + threadIdx.x;
  if (t >= B_SZ * 4 * N_PTS) return;
  int b = t >> 12;
  int r = t & 4095;
  int c = r >> 10;
  int n = r & 1023;
  feat0[((size_t)(b * N_PTS + n)) * 4 + c] =
      (c < 3) ? x[(size_t)b * 3 * N_PTS + c * N_PTS + n] : 0.f;
}

// ---------------- squared norms per point (exact fp32) ----------------
__global__ __launch_bounds__(256) void xnorm_kernel(const float* __restrict__ feat, int lda,
                                                    int C, float* __restrict__ x2) {
  int p = blockIdx.x * 256 + threadIdx.x;
  if (p >= 8192) return;
  const float* r = feat + (size_t)p * lda;
  float s = 0.f;
  for (int c = 0; c < C; c += 4) {
    float4 v = *(const float4*)(r + c);
    s = fmaf(v.x, v.x, s); s = fmaf(v.y, v.y, s);
    s = fmaf(v.z, v.z, s); s = fmaf(v.w, v.w, s);
  }
  x2[p] = s;
}

// ---------------- triple-split features, B-coalesced layout --------------------------
__global__ __launch_bounds__(256) void split_pack(const float* __restrict__ feat, int lda,
                                                  int C, bf16* __restrict__ packH,
                                                  bf16* __restrict__ packM,
                                                  bf16* __restrict__ packL) {
  int t = blockIdx.x * 256 + threadIdx.x;     // 8192*16 threads, 8 k's each
  if (t >= 8192 * 16) return;
  int p = t >> 4, c = t & 15;                 // p = global point, c = q plane
  int b = p >> 10, col = p & 1023;
  int k0 = c * 8;
  bf16x8 h, m, l;
  #pragma unroll
  for (int e = 0; e < 8; ++e) {
    int k = k0 + e;
    float v = (k < C) ? feat[(size_t)p * lda + k] : 0.f;
    bf16 hb = (bf16)v;       float r1 = v - (float)hb;
    bf16 mb = (bf16)r1;      float r2 = r1 - (float)mb;
    bf16 lb = (bf16)r2;
    h[e] = hb; m[e] = mb; l[e] = lb;
  }
  size_t dst = ((size_t)(b * 16 + c) * 1024 + col) * 8;
  *(bf16x8*)(packH + dst) = h;
  *(bf16x8*)(packM + dst) = m;
  *(bf16x8*)(packL + dst) = l;
}

// ---- DPP value-reduce stages (tree verified bit-exact in R10/R11/R16) ----
#define DPP_MAX_STAGE(CTRL)                                                          \
  {                                                                                  \
    int nb = __builtin_amdgcn_update_dpp((int)0xFF800000, __float_as_int(mx),        \
                                         (CTRL), 0xF, 0xF, false);                   \
    mx = fmaxf(mx, __int_as_float(nb));                                              \
  }
#define DPP_MIN_STAGE(CTRL)                                                          \
  {                                                                                  \
    int nb = __builtin_amdgcn_update_dpp((int)0x7fffffff, mc,                        \
                                         (CTRL), 0xF, 0xF, false);                   \
    mc = (nb < mc) ? nb : mc;                                                        \
  }

// ---------------- KNN: triple-split MFMA distances + R16 DPP selection ----------------
__global__ __launch_bounds__(1024) void knn_mfma(const bf16* __restrict__ packH,
                                                 const bf16* __restrict__ packM,
                                                 const bf16* __restrict__ packL,
                                                 const float* __restrict__ x2,
                                                 int nks,
                                                 int* __restrict__ idxout) {
  __shared__ u16 Ah[16 * 128];        // 4KB each, row stride 256B, XOR-swizzled
  __shared__ u16 Am[16 * 128];
  __shared__ u16 Al[16 * 128];
  __shared__ float Ds[16 * 1028];     // 65.8KB, padded stride
  int tid = threadIdx.x;
  int w = tid >> 6, lane = tid & 63;
  int bid = blockIdx.x;
  int swz = (bid & 7) * 64 + (bid >> 3);   // 512 blocks -> batch = bid&7
  int row0 = swz * 16;
  int b = row0 >> 10;
  int col0 = row0 & 1023;

  if (tid < 256) {
    int r = tid >> 4, c = tid & 15;   // c = q plane
    int byte = r * 256 + ((c * 16) ^ ((r & 7) << 4));
    size_t src = ((size_t)(b * 16 + c) * 1024 + col0 + r) * 8;
    *(bf16x8*)((char*)Ah + byte) = *(const bf16x8*)(packH + src);
    *(bf16x8*)((char*)Am + byte) = *(const bf16x8*)(packM + src);
    *(bf16x8*)((char*)Al + byte) = *(const bf16x8*)(packL + src);
  }
  __syncthreads();

  int lrow = lane & 15, kgrp = lane >> 4;
  int abase = lrow * 256;

  f32x4 acc[4];
  #pragma unroll
  for (int f = 0; f < 4; ++f) acc[f] = (f32x4){0.f, 0.f, 0.f, 0.f};

  for (int ks = 0; ks < nks; ++ks) {
    int kb = (ks * 32 + kgrp * 8) * 2;
    int aoff = abase + (kb ^ ((lrow & 7) << 4));
    bf16x8 a_h = *(const bf16x8*)((const char*)Ah + aoff);
    bf16x8 a_m = *(const bf16x8*)((const char*)Am + aoff);
    bf16x8 a_l = *(const bf16x8*)((const char*)Al + aoff);
    int q = ks * 4 + kgrp;
    size_t pbase = (size_t)(b * 16 + q) * 1024;
    #pragma unroll
    for (int f = 0; f < 4; ++f) {
      int col = w * 64 + f * 16 + lrow;
      bf16x8 b_h = *(const bf16x8*)(packH + (pbase + col) * 8);
      bf16x8 b_m = *(const bf16x8*)(packM + (pbase + col) * 8);
      bf16x8 b_l = *(const bf16x8*)(packL + (pbase + col) * 8);
      acc[f] = __builtin_amdgcn_mfma_f32_16x16x32_bf16(a_h, b_h, acc[f], 0, 0, 0);
      acc[f] = __builtin_amdgcn_mfma_f32_16x16x32_bf16(a_h, b_m, acc[f], 0, 0, 0);
      acc[f] = __builtin_amdgcn_mfma_f32_16x16x32_bf16(a_m, b_h, acc[f], 0, 0, 0);
      acc[f] = __builtin_amdgcn_mfma_f32_16x16x32_bf16(a_m, b_m, acc[f], 0, 0, 0);
      acc[f] = __builtin_amdgcn_mfma_f32_16x16x32_bf16(a_h, b_l, acc[f], 0, 0, 0);
      acc[f] = __builtin_amdgcn_mfma_f32_16x16x32_bf16(a_l, b_h, acc[f], 0, 0, 0);
      acc[f] = __builtin_amdgcn_mfma_f32_16x16x32_bf16(a_m, b_l, acc[f], 0, 0, 0);
      acc[f] = __builtin_amdgcn_mfma_f32_16x16x32_bf16(a_l, b_m, acc[f], 0, 0, 0);
    }
  }
  // D epilogue (m89-verified layout: row=(lane>>4)*4+r, col=lane&15)
  #pragma unroll
  for (int f = 0; f < 4; ++f) {
    int col = w * 64 + f * 16 + lrow;
    #pragma unroll
    for (int r = 0; r < 4; ++r)
      Ds[(kgrp * 4 + r) * 1028 + col] = acc[f][r];
  }
  __syncthreads();

  // selection: wave w handles row w (R16 passer, verbatim semantics)
  const float* x2b = x2 + b * N_PTS;
  int row = row0 + w;
  float x2n = x2[row];
  float accv[16];
  #pragma unroll
  for (int j = 0; j < 16; ++j) {
    float d = Ds[w * 1028 + j * 64 + lane];
    accv[j] = (2.f * d - x2n) - x2b[j * 64 + lane];
  }

  for (int rr = 0; rr < KNN_K; ++rr) {
    float m01 = fmaxf(accv[0], accv[1]),   m23 = fmaxf(accv[2], accv[3]);
    float m45 = fmaxf(accv[4], accv[5]),   m67 = fmaxf(accv[6], accv[7]);
    float m89 = fmaxf(accv[8], accv[9]),   mab = fmaxf(accv[10], accv[11]);
    float mcd = fmaxf(accv[12], accv[13]), mef = fmaxf(accv[14], accv[15]);
    float mx = fmaxf(fmaxf(fmaxf(m01, m23), fmaxf(m45, m67)),
                     fmaxf(fmaxf(m89, mab), fmaxf(mcd, mef)));
    DPP_MAX_STAGE(0x111)
    DPP_MAX_STAGE(0x112)
    DPP_MAX_STAGE(0x114)
    DPP_MAX_STAGE(0x118)
    DPP_MAX_STAGE(0x142)
    DPP_MAX_STAGE(0x143)
    mx = __int_as_float(__builtin_amdgcn_readlane(__float_as_int(mx), 63));

    int jloc = 16;
    #pragma unroll
    for (int j = 15; j >= 0; --j)
      if (accv[j] == mx) jloc = j;
    int mc = (jloc < 16) ? ((jloc << 6) | lane) : 0x7fffffff;
    DPP_MIN_STAGE(0x111)
    DPP_MIN_STAGE(0x112)
    DPP_MIN_STAGE(0x114)
    DPP_MIN_STAGE(0x118)
    DPP_MIN_STAGE(0x142)
    DPP_MIN_STAGE(0x143)
    int si = __builtin_amdgcn_readlane(mc, 63);

    int jj = si >> 6, ln = si & 63;
    bool isln = (lane == ln);
    #pragma unroll
    for (int j = 0; j < 16; ++j)
      if (j == jj && isln) accv[j] = -3.4e38f;
    if (lane == 0) idxout[row * KNN_K + rr] = si;
  }
}

// ---------------- build combined weight Wc (fp32): [w1-w2 | w2] (layer 0 only) ---------
__global__ __launch_bounds__(256) void build_wc(const float* __restrict__ w, int C, int O,
                                                float* __restrict__ wc) {
  int t = blockIdx.x * 256 + threadIdx.x;
  int twoO = 2 * O;
  if (t >= C * twoO) return;
  int c = t / twoO, j = t - c * twoO;
  float v;
  if (j < O) v = w[j * (2 * C) + c] - w[j * (2 * C) + C + c];
  else       v = w[(j - O) * (2 * C) + C + c];
  wc[t] = v;
}

// ---------------- fp32 GEMM (layer 0 only, K=3): C[M,N] = A[M,K](lda) * B[K,N] ---------
__global__ __launch_bounds__(256) void gemm_kernel(const float* __restrict__ A, int lda,
                                                   const float* __restrict__ Bm,
                                                   float* __restrict__ Cm,
                                                   int M, int N, int K) {
  __shared__ float As[16][64];
  __shared__ float Bs[16][68];
  int tx = threadIdx.x & 15, ty = threadIdx.x >> 4;
  int bn0 = blockIdx.x * 64, bm0 = blockIdx.y * 64;
  float acc[4][4];
  #pragma unroll
  for (int i = 0; i < 4; ++i)
    #pragma unroll
    for (int j = 0; j < 4; ++j) acc[i][j] = 0.f;

  for (int k0 = 0; k0 < K; k0 += 16) {
    {
      int t = threadIdx.x;
      int m = t >> 2, kb = (t & 3) * 4;
      const float* ap = A + (size_t)(bm0 + m) * lda + k0 + kb;
      #pragma unroll
      for (int i = 0; i < 4; ++i) As[kb + i][m] = (k0 + kb + i < K) ? ap[i] : 0.f;
      int r = t >> 4, c4 = (t & 15) * 4;
      float4 bv = make_float4(0.f, 0.f, 0.f, 0.f);
      if (k0 + r < K) bv = *(const float4*)(Bm + (size_t)(k0 + r) * N + bn0 + c4);
      *(float4*)&Bs[r][c4] = bv;
    }
    __syncthreads();
    #pragma unroll
    for (int k = 0; k < 16; ++k) {
      float a0[4];
      #pragma unroll
      for (int i = 0; i < 4; ++i) a0[i] = As[k][ty * 4 + i];
      float4 bv = *(const float4*)&Bs[k][tx * 4];
      float b0[4] = {bv.x, bv.y, bv.z, bv.w};
      #pragma unroll
      for (int i = 0; i < 4; ++i)
        #pragma unroll
        for (int j = 0; j < 4; ++j) acc[i][j] = fmaf(a0[i], b0[j], acc[i][j]);
    }
    __syncthreads();
  }
  #pragma unroll
  for (int i = 0; i < 4; ++i) {
    float4 v = make_float4(acc[i][0], acc[i][1], acc[i][2], acc[i][3]);
    *(float4*)(Cm + (size_t)(bm0 + ty * 4 + i) * N + bn0 + tx * 4) = v;
  }
}

// ---------------- split fp32 -> bf16 hi/lo helpers ----------------
__device__ inline void split8(const float* __restrict__ p, bf16x8* hv, bf16x8* lv) {
  float4 a0 = *(const float4*)p, a1 = *(const float4*)(p + 4);
  float v[8] = {a0.x, a0.y, a0.z, a0.w, a1.x, a1.y, a1.z, a1.w};
  bf16x8 h, l;
  #pragma unroll
  for (int j = 0; j < 8; ++j) {
    bf16 hj = (bf16)v[j];
    h[j] = hj;
    l[j] = (bf16)(v[j] - (float)hj);
  }
  *hv = h; *lv = l;
}

__device__ inline void split8v(const float* __restrict__ v, bf16x8* hv, bf16x8* lv) {
  bf16x8 h, l;
  #pragma unroll
  for (int j = 0; j < 8; ++j) {
    bf16 hj = (bf16)v[j];
    h[j] = hj;
    l[j] = (bf16)(v[j] - (float)hj);
  }
  *hv = h; *lv = l;
}

// ---------------- split-bf16 MFMA GEMM for edge layers, inline combined-weight B -------
// C[M,2O] = A[M,K](lda) * Wc^T, where Wc row j = (j<O ? w[j][0:K]-w[j][K:2K] : w[j-O][K:2K])
// (bitwise-identical expression to the old build_wcT). K%64==0, M%128==0, 2O%128==0.
__global__ __launch_bounds__(256) void gemm_split(const float* __restrict__ A, int lda,
                                                  const float* __restrict__ w, int O,
                                                  float* __restrict__ C, int N, int K) {
  __shared__ u16 Ah[128 * 64];
  __shared__ u16 Al[128 * 64];
  __shared__ u16 Bh[128 * 64];
  __shared__ u16 Bl[128 * 64];
  int tid = threadIdx.x;
  int wave = tid >> 6, lane = tid & 63;
  int wr = wave >> 1, wc = wave & 1;
  int bn0 = blockIdx.x * 128, bm0 = blockIdx.y * 128;
  int lrow = lane & 15;
  int kgrp = lane >> 4;

  f32x4 acc[4][4];
  #pragma unroll
  for (int i = 0; i < 4; ++i)
    #pragma unroll
    for (int j = 0; j < 4; ++j) acc[i][j] = (f32x4){0.f, 0.f, 0.f, 0.f};

  for (int k0 = 0; k0 < K; k0 += 64) {
    #pragma unroll
    for (int i = 0; i < 4; ++i) {
      int chunk = tid + i * 256;
      int row = chunk >> 3;
      int cc = (chunk & 7) * 8;
      int byte = row * 128 + ((cc * 2) ^ ((row & 7) << 4));
      bf16x8 h, l;
      split8(A + (size_t)(bm0 + row) * lda + k0 + cc, &h, &l);
      *(bf16x8*)((char*)Ah + byte) = h;
      *(bf16x8*)((char*)Al + byte) = l;
      // combined weight, computed inline (same fp expression as build_wcT)
      int j = bn0 + row;
      const float* base = w + (size_t)(j < O ? j : j - O) * (2 * K) + k0 + cc;
      float bv[8];
      if (j < O) {
        #pragma unroll
        for (int e = 0; e < 8; ++e) bv[e] = base[e] - base[K + e];
      } else {
        #pragma unroll
        for (int e = 0; e < 8; ++e) bv[e] = base[K + e];
      }
      split8v(bv, &h, &l);
      *(bf16x8*)((char*)Bh + byte) = h;
      *(bf16x8*)((char*)Bl + byte) = l;
    }
    __syncthreads();
    #pragma unroll
    for (int kk = 0; kk < 64; kk += 32) {
      int kb = (kk + kgrp * 8) * 2;
      bf16x8 afh[4], afl[4], bfh[4], bfl[4];
      #pragma unroll
      for (int f = 0; f < 4; ++f) {
        int arow = wr * 64 + f * 16 + lrow;
        int abyte = arow * 128 + (kb ^ ((arow & 7) << 4));
        afh[f] = *(const bf16x8*)((const char*)Ah + abyte);
        afl[f] = *(const bf16x8*)((const char*)Al + abyte);
        int brow = wc * 64 + f * 16 + lrow;
        int bbyte = brow * 128 + (kb ^ ((brow & 7) << 4));
        bfh[f] = *(const bf16x8*)((const char*)Bh + bbyte);
        bfl[f] = *(const bf16x8*)((const char*)Bl + bbyte);
      }
      #pragma unroll
      for (int fm = 0; fm < 4; ++fm)
        #pragma unroll
        for (int fn = 0; fn < 4; ++fn) {
          acc[fm][fn] = __builtin_amdgcn_mfma_f32_16x16x32_bf16(afh[fm], bfh[fn], acc[fm][fn], 0, 0, 0);
          acc[fm][fn] = __builtin_amdgcn_mfma_f32_16x16x32_bf16(afl[fm], bfh[fn], acc[fm][fn], 0, 0, 0);
          acc[fm][fn] = __builtin_amdgcn_mfma_f32_16x16x32_bf16(afh[fm], bfl[fn], acc[fm][fn], 0, 0, 0);
        }
    }
    __syncthreads();
  }
  // epilogue: D row=(lane>>4)*4+r, col=lane&15 (m89-verified; R4/R21 passer)
  #pragma unroll
  for (int fm = 0; fm < 4; ++fm) {
    int mrow = bm0 + wr * 64 + fm * 16 + kgrp * 4;
    #pragma unroll
    for (int fn = 0; fn < 4; ++fn) {
      int ncol = bn0 + wc * 64 + fn * 16 + lrow;
      #pragma unroll
      for (int r = 0; r < 4; ++r)
        C[(size_t)(mrow + r) * N + ncol] = acc[fm][fn][r];
    }
  }
}

// ---------------- split-bf16 MFMA GEMM for layer 5 with fused reduction ---------------
__global__ __launch_bounds__(256) void gemm_split_red(const float* __restrict__ A, int lda,
                                                      const float* __restrict__ Bt, int ldb,
                                                      float* __restrict__ parts, int K) {
  __shared__ u16 Ah[128 * 64];
  __shared__ u16 Al[128 * 64];
  __shared__ u16 Bh[128 * 64];
  __shared__ u16 Bl[128 * 64];
  int tid = threadIdx.x;
  int wave = tid >> 6, lane = tid & 63;
  int wr = wave >> 1, wc = wave & 1;
  int bn0 = blockIdx.x * 128, bm0 = blockIdx.y * 128;
  int lrow = lane & 15;
  int kgrp = lane >> 4;

  f32x4 acc[4][4];
  #pragma unroll
  for (int i = 0; i < 4; ++i)
    #pragma unroll
    for (int j = 0; j < 4; ++j) acc[i][j] = (f32x4){0.f, 0.f, 0.f, 0.f};

  for (int k0 = 0; k0 < K; k0 += 64) {
    #pragma unroll
    for (int i = 0; i < 4; ++i) {
      int chunk = tid + i * 256;
      int row = chunk >> 3;
      int cc = (chunk & 7) * 8;
      int byte = row * 128 + ((cc * 2) ^ ((row & 7) << 4));
      bf16x8 h, l;
      split8(A + (size_t)(bm0 + row) * lda + k0 + cc, &h, &l);
      *(bf16x8*)((char*)Ah + byte) = h;
      *(bf16x8*)((char*)Al + byte) = l;
      split8(Bt + (size_t)(bn0 + row) * ldb + k0 + cc, &h, &l);
      *(bf16x8*)((char*)Bh + byte) = h;
      *(bf16x8*)((char*)Bl + byte) = l;
    }
    __syncthreads();
    #pragma unroll
    for (int kk = 0; kk < 64; kk += 32) {
      int kb = (kk + kgrp * 8) * 2;
      bf16x8 afh[4], afl[4], bfh[4], bfl[4];
      #pragma unroll
      for (int f = 0; f < 4; ++f) {
        int arow = wr * 64 + f * 16 + lrow;
        int abyte = arow * 128 + (kb ^ ((arow & 7) << 4));
        afh[f] = *(const bf16x8*)((const char*)Ah + abyte);
        afl[f] = *(const bf16x8*)((const char*)Al + abyte);
        int brow = wc * 64 + f * 16 + lrow;
        int bbyte = brow * 128 + (kb ^ ((brow & 7) << 4));
        bfh[f] = *(const bf16x8*)((const char*)Bh + bbyte);
        bfl[f] = *(const bf16x8*)((const char*)Bl + bbyte);
      }
      #pragma unroll
      for (int fm = 0; fm < 4; ++fm)
        #pragma unroll
        for (int fn = 0; fn < 4; ++fn) {
          acc[fm][fn] = __builtin_amdgcn_mfma_f32_16x16x32_bf16(afh[fm], bfh[fn], acc[fm][fn], 0, 0, 0);
          acc[fm][fn] = __builtin_amdgcn_mfma_f32_16x16x32_bf16(afl[fm], bfh[fn], acc[fm][fn], 0, 0, 0);
          acc[fm][fn] = __builtin_amdgcn_mfma_f32_16x16x32_bf16(afh[fm], bfl[fn], acc[fm][fn], 0, 0, 0);
        }
    }
    __syncthreads();
  }

  float* scratch = (float*)Ah;
  int contrib = wr * 4 + kgrp;
  #pragma unroll
  for (int fn = 0; fn < 4; ++fn) {
    float mx = -3.4e38f, mn = 3.4e38f, s1 = 0.f, s2 = 0.f;
    #pragma unroll
    for (int fm = 0; fm < 4; ++fm)
      #pragma unroll
      for (int r = 0; r < 4; ++r) {
        float v = acc[fm][fn][r];
        mx = fmaxf(mx, v); mn = fminf(mn, v);
        s1 += v; s2 = fmaf(v, v, s2);
      }
    int col = wc * 64 + fn * 16 + lrow;
    float* sp = scratch + (contrib * 128 + col) * 4;
    sp[0] = mx; sp[1] = mn; sp[2] = s1; sp[3] = s2;
  }
  __syncthreads();
  if (tid < 128) {
    float mx = -3.4e38f, mn = 3.4e38f, s1 = 0.f, s2 = 0.f;
    #pragma unroll
    for (int c2 = 0; c2 < 8; ++c2) {
      const float* sp = scratch + (c2 * 128 + tid) * 4;
      mx = fmaxf(mx, sp[0]); mn = fminf(mn, sp[1]);
      s1 += sp[2]; s2 += sp[3];
    }
    size_t o = (size_t)blockIdx.y * 1024 + bn0 + tid;
    parts[o] = mx;
    parts[65536 + o] = mn;
    parts[131072 + o] = s1;
    parts[196608 + o] = s2;
  }
}

// ---------------- edge aggregation (vectorized): lane owns VW=O/64 channels ----------
template<int VW>
__global__ __launch_bounds__(256) void aggregate_t(const float* __restrict__ ay,
                                                   const int* __restrict__ idxb, int O,
                                                   float* __restrict__ mx,
                                                   float* __restrict__ mn,
                                                   float* __restrict__ sumsbin) {
  __shared__ float ls1[4][256];
  __shared__ float ls2[4][256];
  int warp = threadIdx.x >> 6, lane = threadIdx.x & 63;
  int bid = blockIdx.x;
  int swz = (bid & 7) * 256 + (bid >> 3);   // 2048 blocks -> batch = bid&7
  int pt = swz * 4 + warp;                  // 0..8191
  int b = pt >> 10;
  int twoO = 2 * O;
  int o0 = lane * VW;
  const float* ayrow = ay + (size_t)pt * twoO;

  int idxs[KNN_K];
  const int* ip = idxb + pt * KNN_K;
  #pragma unroll
  for (int k = 0; k < KNN_K; ++k) idxs[k] = ip[k];

  float s1[VW], s2[VW], vmx[VW], vmn[VW];
  #pragma unroll
  for (int u = 0; u < VW; ++u) { s1[u] = 0.f; s2[u] = 0.f; vmx[u] = -3.4e38f; vmn[u] = 3.4e38f; }

  #pragma unroll
  for (int k = 0; k < KNN_K; ++k) {
    const float* yp = ay + (size_t)(b * N_PTS + idxs[k]) * twoO + O + o0;
    float v[VW];
    if (VW == 4)      { float4 t = *(const float4*)yp; v[0] = t.x; v[1] = t.y; v[2] = t.z; v[3] = t.w; }
    else if (VW == 2) { float2 t = *(const float2*)yp; v[0] = t.x; v[1] = t.y; }
    else              { v[0] = yp[0]; }
    #pragma unroll
    for (int u = 0; u < VW; ++u) {
      s1[u] += v[u]; s2[u] = fmaf(v[u], v[u], s2[u]);
      vmx[u] = fmaxf(vmx[u], v[u]); vmn[u] = fminf(vmn[u], v[u]);
    }
  }

  float a[VW], omx[VW], omn[VW];
  if (VW == 4)      { float4 t = *(const float4*)(ayrow + o0); a[0] = t.x; a[1] = t.y; a[2] = t.z; a[3] = t.w; }
  else if (VW == 2) { float2 t = *(const float2*)(ayrow + o0); a[0] = t.x; a[1] = t.y; }
  else              { a[0] = ayrow[o0]; }
  #pragma unroll
  for (int u = 0; u < VW; ++u) {
    omx[u] = a[u] + vmx[u];
    omn[u] = a[u] + vmn[u];
    ls1[warp][o0 + u] = fmaf(20.f, a[u], s1[u]);
    ls2[warp][o0 + u] = s2[u] + a[u] * fmaf(20.f, a[u], 2.f * s1[u]);
  }
  if (VW == 4) {
    *(float4*)(mx + (size_t)pt * O + o0) = make_float4(omx[0], omx[1], omx[2], omx[3]);
    *(float4*)(mn + (size_t)pt * O + o0) = make_float4(omn[0], omn[1], omn[2], omn[3]);
  } else if (VW == 2) {
    *(float2*)(mx + (size_t)pt * O + o0) = make_float2(omx[0], omx[1]);
    *(float2*)(mn + (size_t)pt * O + o0) = make_float2(omn[0], omn[1]);
  } else {
    mx[(size_t)pt * O + o0] = omx[0];
    mn[(size_t)pt * O + o0] = omn[0];
  }
  __syncthreads();
  int bin = blockIdx.x & 63;
  float* gb = sumsbin + (size_t)bin * 512;
  for (int o = threadIdx.x; o < O; o += 256) {
    float t1 = ls1[0][o] + ls1[1][o] + ls1[2][o] + ls1[3][o];
    float t2 = ls2[0][o] + ls2[1][o] + ls2[2][o] + ls2[3][o];
    atomicAdd(&gb[o], t1);
    atomicAdd(&gb[256 + o], t2);
  }
}

// ---------------- reduce bins -> sums; zero bins afterward (replaces per-layer memset) --
__global__ __launch_bounds__(256) void reduce_bins(float* __restrict__ sumsbin,
                                                   float* __restrict__ sums, int O) {
  int o = threadIdx.x;
  if (o >= O) return;
  float a = 0.f, c = 0.f;
  for (int bin = 0; bin < 64; ++bin) {
    a += sumsbin[bin * 512 + o];
    c += sumsbin[bin * 512 + 256 + o];
    sumsbin[bin * 512 + o] = 0.f;
    sumsbin[bin * 512 + 256 + o] = 0.f;
  }
  sums[o] = a;
  sums[256 + o] = c;
}

// ---------------- finalize edge layer: BN + relu on (max or min depending on sign) ----------------
__global__ __launch_bounds__(256) void finalize_edge(const float* __restrict__ mx,
                                                     const float* __restrict__ mn,
                                                     const float* __restrict__ sums,
                                                     const float* __restrict__ g,
                                                     const float* __restrict__ beta,
                                                     int oshift,
                                                     float* __restrict__ outseg,
                                                     float cnt_inv) {
  int tid = blockIdx.x * 256 + threadIdx.x;
  int pt = tid >> oshift;
  int o = tid & ((1 << oshift) - 1);
  float s1 = sums[o], s2 = sums[256 + o];
  float mean = s1 * cnt_inv;
  float var = s2 * cnt_inv - mean * mean;
  float rstd = rsqrtf(var + BN_EPS);
  float sc = g[o] * rstd;
  float sel = (sc >= 0.f) ? mx[tid] : mn[tid];
  float v = (sel - mean) * sc + beta[o];
  outseg[(size_t)pt * CAT_C + o] = fmaxf(v, 0.f);
}

// ---------------- layer 5 finalize from tile partials ----------------
__global__ __launch_bounds__(256) void finalize5_fused(const float* __restrict__ parts,
                                                       const float* __restrict__ g,
                                                       const float* __restrict__ beta,
                                                       float* __restrict__ out) {
  int tid = blockIdx.x * 256 + threadIdx.x;
  int b = tid >> 10, o = tid & 1023;
  const float* pmx = parts;
  const float* pmn = parts + 65536;
  const float* ps1 = parts + 131072;
  const float* ps2 = parts + 196608;
  float s1 = 0.f, s2 = 0.f;
  for (int t = 0; t < 64; ++t) { s1 += ps1[t * 1024 + o]; s2 += ps2[t * 1024 + o]; }
  float mx = -3.4e38f, mn = 3.4e38f;
  #pragma unroll
  for (int t = 0; t < 8; ++t) {
    mx = fmaxf(mx, pmx[(b * 8 + t) * 1024 + o]);
    mn = fminf(mn, pmn[(b * 8 + t) * 1024 + o]);
  }
  float mean = s1 * (1.0f / 8192.0f);
  float var = s2 * (1.0f / 8192.0f) - mean * mean;
  float rstd = rsqrtf(var + BN_EPS);
  float sc = g[o] * rstd;
  float sel = (sc >= 0.f) ? mx : mn;
  float v = (sel - mean) * sc + beta[o];
  out[tid] = fmaxf(v, 0.f);
}

extern "C" void kernel_launch(void* const* d_in, const int* in_sizes, int n_in,
                              void* d_out, int out_size, void* d_ws, size_t ws_size,
                              hipStream_t stream) {
  const float* x = (const float*)d_in[0];
  const float* w[5]  = {(const float*)d_in[1], (const float*)d_in[4], (const float*)d_in[7],
                        (const float*)d_in[10], (const float*)d_in[13]};
  const float* gg[5] = {(const float*)d_in[2], (const float*)d_in[5], (const float*)d_in[8],
                        (const float*)d_in[11], (const float*)d_in[14]};
  const float* bb[5] = {(const float*)d_in[3], (const float*)d_in[6], (const float*)d_in[9],
                        (const float*)d_in[12], (const float*)d_in[15]};
  float* out = (float*)d_out;

  float* W = (float*)d_ws;
  size_t off = 0;
  float* feat0   = W + off; off += (size_t)B_SZ * N_PTS * 4;   // stride-4 padded
  float* catbuf  = W + off; off += (size_t)8192 * CAT_C;
  int*   idxbuf  = (int*)(W + off); off += (size_t)8192 * KNN_K;
  float* aybuf   = W + off; off += (size_t)8192 * 1024;
  float* mxbuf   = W + off; off += (size_t)8192 * 256;
  float* mnbuf   = W + off; off += (size_t)8192 * 256;
  float* wcbuf   = W + off; off += (size_t)512 * 1024;
  float* sumsbin = W + off; off += (size_t)64 * 512;
  float* sums    = W + off; off += 512;
  float* parts   = W + off; off += (size_t)4 * 64 * 1024;
  float* x2buf   = W + off; off += 8192;
  bf16*  packH   = (bf16*)(W + off); off += (size_t)8192 * 128 / 2;   // 2MB
  bf16*  packM   = (bf16*)(W + off); off += (size_t)8192 * 128 / 2;   // 2MB
  bf16*  packL   = (bf16*)(W + off); off += (size_t)8192 * 128 / 2;   // 2MB

  transpose_x<<<(B_SZ * 4 * N_PTS + 255) / 256, 256, 0, stream>>>(x, feat0);
  hipMemsetAsync(sumsbin, 0, (size_t)64 * 512 * sizeof(float), stream);  // first-launch poison clear

  const int Cs[4] = {4, 64, 64, 128};   // layer-0 padded to 4 (pad=0, values unchanged)
  const int Ks[4] = {3, 64, 64, 128};   // true K for the edge GEMM
  const int Os[4] = {64, 64, 128, 256};
  const int osh[4] = {6, 6, 7, 8};
  const int segin[4] = {0, 0, 64, 128};
  const int segout[4] = {0, 64, 128, 256};

  for (int l = 0; l < 4; ++l) {
    int C = Cs[l], O = Os[l], twoO = 2 * O;
    const float* featin = (l == 0) ? feat0 : (catbuf + segin[l]);
    int lda = (l == 0) ? 4 : CAT_C;
    int nks = (C + 31) / 32;            // 1,2,2,4

    xnorm_kernel<<<32, 256, 0, stream>>>(featin, lda, C, x2buf);
    split_pack<<<512, 256, 0, stream>>>(featin, lda, C, packH, packM, packL);
    knn_mfma<<<512, 1024, 0, stream>>>(packH, packM, packL, x2buf, nks, idxbuf);

    if (l == 0) {
      build_wc<<<(Ks[l] * twoO + 255) / 256, 256, 0, stream>>>(w[l], Ks[l], O, wcbuf);
      gemm_kernel<<<dim3(twoO / 64, 8192 / 64), 256, 0, stream>>>(featin, lda, wcbuf, aybuf,
                                                                  8192, twoO, Ks[l]);
    } else {
      gemm_split<<<dim3(twoO / 128, 8192 / 128), 256, 0, stream>>>(featin, lda, w[l], O,
                                                                   aybuf, twoO, Ks[l]);
    }
    if (O == 256)
      aggregate_t<4><<<2048, 256, 0, stream>>>(aybuf, idxbuf, O, mxbuf, mnbuf, sumsbin);
    else if (O == 128)
      aggregate_t<2><<<2048, 256, 0, stream>>>(aybuf, idxbuf, O, mxbuf, mnbuf, sumsbin);
    else
      aggregate_t<1><<<2048, 256, 0, stream>>>(aybuf, idxbuf, O, mxbuf, mnbuf, sumsbin);
    reduce_bins<<<1, 256, 0, stream>>>(sumsbin, sums, O);
    finalize_edge<<<(8192 * O) / 256, 256, 0, stream>>>(mxbuf, mnbuf, sums, gg[l], bb[l],
                                                        osh[l], catbuf + segout[l],
                                                        1.0f / (8192.0f * KNN_K));
  }

  // layer 5: h5 = cat * w5^T via split-bf16 MFMA with fused per-tile reduction
  gemm_split_red<<<dim3(1024 / 128, 8192 / 128), 256, 0, stream>>>(catbuf, CAT_C, w[4], 512,
                                                                   parts, 512);
  finalize5_fused<<<8192 / 256, 256, 0, stream>>>(parts, gg[4], bb[4], out);
}

// Round 23
// 350.222 us; speedup vs baseline: 1.5844x; 1.0269x over previous
//
#include <hip/hip_runtime.h>
#include <cstddef>

#define B_SZ 8
#define N_PTS 1024
#define KNN_K 20
#define CAT_C 512
#define BN_EPS 1e-5f

typedef unsigned short u16;
typedef unsigned int u32;
typedef __bf16 bf16;
typedef __bf16 bf16x8 __attribute__((ext_vector_type(8)));
typedef float f32x4 __attribute__((ext_vector_type(4)));

// ---------------- transpose x (B,3,N) -> feat0 (B,N,4), pad col 3 = 0 ----------------
__global__ __launch_bounds__(256) void transpose_x(const float* __restrict__ x,
                                                   float* __restrict__ feat0) {
  int t = blockIdx.x * 256 + threadIdx.x;
  if (t >= B_SZ * 4 * N_PTS) return;
  int b = t >> 12;
  int r = t & 4095;
  int c = r >> 10;
  int n = r & 1023;
  feat0[((size_t)(b * N_PTS + n)) * 4 + c] =
      (c < 3) ? x[(size_t)b * 3 * N_PTS + c * N_PTS + n] : 0.f;
}

// ---------------- squared norms per point (exact fp32) ----------------
__global__ __launch_bounds__(256) void xnorm_kernel(const float* __restrict__ feat, int lda,
                                                    int C, float* __restrict__ x2) {
  int p = blockIdx.x * 256 + threadIdx.x;
  if (p >= 8192) return;
  const float* r = feat + (size_t)p * lda;
  float s = 0.f;
  for (int c = 0; c < C; c += 4) {
    float4 v = *(const float4*)(r + c);
    s = fmaf(v.x, v.x, s); s = fmaf(v.y, v.y, s);
    s = fmaf(v.z, v.z, s); s = fmaf(v.w, v.w, s);
  }
  x2[p] = s;
}

// ---------------- triple-split features, B-coalesced layout (layer 0 only) -----------
__global__ __launch_bounds__(256) void split_pack(const float* __restrict__ feat, int lda,
                                                  int C, bf16* __restrict__ packH,
                                                  bf16* __restrict__ packM,
                                                  bf16* __restrict__ packL) {
  int t = blockIdx.x * 256 + threadIdx.x;     // 8192*16 threads, 8 k's each
  if (t >= 8192 * 16) return;
  int p = t >> 4, c = t & 15;                 // p = global point, c = q plane
  int b = p >> 10, col = p & 1023;
  int k0 = c * 8;
  bf16x8 h, m, l;
  #pragma unroll
  for (int e = 0; e < 8; ++e) {
    int k = k0 + e;
    float v = (k < C) ? feat[(size_t)p * lda + k] : 0.f;
    bf16 hb = (bf16)v;       float r1 = v - (float)hb;
    bf16 mb = (bf16)r1;      float r2 = r1 - (float)mb;
    bf16 lb = (bf16)r2;
    h[e] = hb; m[e] = mb; l[e] = lb;
  }
  size_t dst = ((size_t)(b * 16 + c) * 1024 + col) * 8;
  *(bf16x8*)(packH + dst) = h;
  *(bf16x8*)(packM + dst) = m;
  *(bf16x8*)(packL + dst) = l;
}

// ---- DPP value-reduce stages (tree verified bit-exact in R10/R11/R16) ----
#define DPP_MAX_STAGE(CTRL)                                                          \
  {                                                                                  \
    int nb = __builtin_amdgcn_update_dpp((int)0xFF800000, __float_as_int(mx),        \
                                         (CTRL), 0xF, 0xF, false);                   \
    mx = fmaxf(mx, __int_as_float(nb));                                              \
  }
#define DPP_MIN_STAGE(CTRL)                                                          \
  {                                                                                  \
    int nb = __builtin_amdgcn_update_dpp((int)0x7fffffff, mc,                        \
                                         (CTRL), 0xF, 0xF, false);                   \
    mc = (nb < mc) ? nb : mc;                                                        \
  }

// ---------------- KNN: triple-split MFMA distances + R16 DPP selection ----------------
__global__ __launch_bounds__(1024) void knn_mfma(const bf16* __restrict__ packH,
                                                 const bf16* __restrict__ packM,
                                                 const bf16* __restrict__ packL,
                                                 const float* __restrict__ x2,
                                                 int nks,
                                                 int* __restrict__ idxout) {
  __shared__ u16 Ah[16 * 128];        // 4KB each, row stride 256B, XOR-swizzled
  __shared__ u16 Am[16 * 128];
  __shared__ u16 Al[16 * 128];
  __shared__ float Ds[16 * 1028];     // 65.8KB, padded stride
  int tid = threadIdx.x;
  int w = tid >> 6, lane = tid & 63;
  int bid = blockIdx.x;
  int swz = (bid & 7) * 64 + (bid >> 3);   // 512 blocks -> batch = bid&7
  int row0 = swz * 16;
  int b = row0 >> 10;
  int col0 = row0 & 1023;

  if (tid < 256) {
    int r = tid >> 4, c = tid & 15;   // c = q plane
    int byte = r * 256 + ((c * 16) ^ ((r & 7) << 4));
    size_t src = ((size_t)(b * 16 + c) * 1024 + col0 + r) * 8;
    *(bf16x8*)((char*)Ah + byte) = *(const bf16x8*)(packH + src);
    *(bf16x8*)((char*)Am + byte) = *(const bf16x8*)(packM + src);
    *(bf16x8*)((char*)Al + byte) = *(const bf16x8*)(packL + src);
  }
  __syncthreads();

  int lrow = lane & 15, kgrp = lane >> 4;
  int abase = lrow * 256;

  f32x4 acc[4];
  #pragma unroll
  for (int f = 0; f < 4; ++f) acc[f] = (f32x4){0.f, 0.f, 0.f, 0.f};

  for (int ks = 0; ks < nks; ++ks) {
    int kb = (ks * 32 + kgrp * 8) * 2;
    int aoff = abase + (kb ^ ((lrow & 7) << 4));
    bf16x8 a_h = *(const bf16x8*)((const char*)Ah + aoff);
    bf16x8 a_m = *(const bf16x8*)((const char*)Am + aoff);
    bf16x8 a_l = *(const bf16x8*)((const char*)Al + aoff);
    int q = ks * 4 + kgrp;
    size_t pbase = (size_t)(b * 16 + q) * 1024;
    #pragma unroll
    for (int f = 0; f < 4; ++f) {
      int col = w * 64 + f * 16 + lrow;
      bf16x8 b_h = *(const bf16x8*)(packH + (pbase + col) * 8);
      bf16x8 b_m = *(const bf16x8*)(packM + (pbase + col) * 8);
      bf16x8 b_l = *(const bf16x8*)(packL + (pbase + col) * 8);
      acc[f] = __builtin_amdgcn_mfma_f32_16x16x32_bf16(a_h, b_h, acc[f], 0, 0, 0);
      acc[f] = __builtin_amdgcn_mfma_f32_16x16x32_bf16(a_h, b_m, acc[f], 0, 0, 0);
      acc[f] = __builtin_amdgcn_mfma_f32_16x16x32_bf16(a_m, b_h, acc[f], 0, 0, 0);
      acc[f] = __builtin_amdgcn_mfma_f32_16x16x32_bf16(a_m, b_m, acc[f], 0, 0, 0);
      acc[f] = __builtin_amdgcn_mfma_f32_16x16x32_bf16(a_h, b_l, acc[f], 0, 0, 0);
      acc[f] = __builtin_amdgcn_mfma_f32_16x16x32_bf16(a_l, b_h, acc[f], 0, 0, 0);
      acc[f] = __builtin_amdgcn_mfma_f32_16x16x32_bf16(a_m, b_l, acc[f], 0, 0, 0);
      acc[f] = __builtin_amdgcn_mfma_f32_16x16x32_bf16(a_l, b_m, acc[f], 0, 0, 0);
    }
  }
  // D epilogue (m89-verified layout: row=(lane>>4)*4+r, col=lane&15)
  #pragma unroll
  for (int f = 0; f < 4; ++f) {
    int col = w * 64 + f * 16 + lrow;
    #pragma unroll
    for (int r = 0; r < 4; ++r)
      Ds[(kgrp * 4 + r) * 1028 + col] = acc[f][r];
  }
  __syncthreads();

  // selection: wave w handles row w (R16 passer, verbatim semantics)
  const float* x2b = x2 + b * N_PTS;
  int row = row0 + w;
  float x2n = x2[row];
  float accv[16];
  #pragma unroll
  for (int j = 0; j < 16; ++j) {
    float d = Ds[w * 1028 + j * 64 + lane];
    accv[j] = (2.f * d - x2n) - x2b[j * 64 + lane];
  }

  for (int rr = 0; rr < KNN_K; ++rr) {
    float m01 = fmaxf(accv[0], accv[1]),   m23 = fmaxf(accv[2], accv[3]);
    float m45 = fmaxf(accv[4], accv[5]),   m67 = fmaxf(accv[6], accv[7]);
    float m89 = fmaxf(accv[8], accv[9]),   mab = fmaxf(accv[10], accv[11]);
    float mcd = fmaxf(accv[12], accv[13]), mef = fmaxf(accv[14], accv[15]);
    float mx = fmaxf(fmaxf(fmaxf(m01, m23), fmaxf(m45, m67)),
                     fmaxf(fmaxf(m89, mab), fmaxf(mcd, mef)));
    DPP_MAX_STAGE(0x111)
    DPP_MAX_STAGE(0x112)
    DPP_MAX_STAGE(0x114)
    DPP_MAX_STAGE(0x118)
    DPP_MAX_STAGE(0x142)
    DPP_MAX_STAGE(0x143)
    mx = __int_as_float(__builtin_amdgcn_readlane(__float_as_int(mx), 63));

    int jloc = 16;
    #pragma unroll
    for (int j = 15; j >= 0; --j)
      if (accv[j] == mx) jloc = j;
    int mc = (jloc < 16) ? ((jloc << 6) | lane) : 0x7fffffff;
    DPP_MIN_STAGE(0x111)
    DPP_MIN_STAGE(0x112)
    DPP_MIN_STAGE(0x114)
    DPP_MIN_STAGE(0x118)
    DPP_MIN_STAGE(0x142)
    DPP_MIN_STAGE(0x143)
    int si = __builtin_amdgcn_readlane(mc, 63);

    int jj = si >> 6, ln = si & 63;
    bool isln = (lane == ln);
    #pragma unroll
    for (int j = 0; j < 16; ++j)
      if (j == jj && isln) accv[j] = -3.4e38f;
    if (lane == 0) idxout[row * KNN_K + rr] = si;
  }
}

// ---------------- build combined weight Wc (fp32): [w1-w2 | w2] (layer 0 only) ---------
__global__ __launch_bounds__(256) void build_wc(const float* __restrict__ w, int C, int O,
                                                float* __restrict__ wc) {
  int t = blockIdx.x * 256 + threadIdx.x;
  int twoO = 2 * O;
  if (t >= C * twoO) return;
  int c = t / twoO, j = t - c * twoO;
  float v;
  if (j < O) v = w[j * (2 * C) + c] - w[j * (2 * C) + C + c];
  else       v = w[(j - O) * (2 * C) + C + c];
  wc[t] = v;
}

// ---------------- fp32 GEMM (layer 0 only, K=3): C[M,N] = A[M,K](lda) * B[K,N] ---------
__global__ __launch_bounds__(256) void gemm_kernel(const float* __restrict__ A, int lda,
                                                   const float* __restrict__ Bm,
                                                   float* __restrict__ Cm,
                                                   int M, int N, int K) {
  __shared__ float As[16][64];
  __shared__ float Bs[16][68];
  int tx = threadIdx.x & 15, ty = threadIdx.x >> 4;
  int bn0 = blockIdx.x * 64, bm0 = blockIdx.y * 64;
  float acc[4][4];
  #pragma unroll
  for (int i = 0; i < 4; ++i)
    #pragma unroll
    for (int j = 0; j < 4; ++j) acc[i][j] = 0.f;

  for (int k0 = 0; k0 < K; k0 += 16) {
    {
      int t = threadIdx.x;
      int m = t >> 2, kb = (t & 3) * 4;
      const float* ap = A + (size_t)(bm0 + m) * lda + k0 + kb;
      #pragma unroll
      for (int i = 0; i < 4; ++i) As[kb + i][m] = (k0 + kb + i < K) ? ap[i] : 0.f;
      int r = t >> 4, c4 = (t & 15) * 4;
      float4 bv = make_float4(0.f, 0.f, 0.f, 0.f);
      if (k0 + r < K) bv = *(const float4*)(Bm + (size_t)(k0 + r) * N + bn0 + c4);
      *(float4*)&Bs[r][c4] = bv;
    }
    __syncthreads();
    #pragma unroll
    for (int k = 0; k < 16; ++k) {
      float a0[4];
      #pragma unroll
      for (int i = 0; i < 4; ++i) a0[i] = As[k][ty * 4 + i];
      float4 bv = *(const float4*)&Bs[k][tx * 4];
      float b0[4] = {bv.x, bv.y, bv.z, bv.w};
      #pragma unroll
      for (int i = 0; i < 4; ++i)
        #pragma unroll
        for (int j = 0; j < 4; ++j) acc[i][j] = fmaf(a0[i], b0[j], acc[i][j]);
    }
    __syncthreads();
  }
  #pragma unroll
  for (int i = 0; i < 4; ++i) {
    float4 v = make_float4(acc[i][0], acc[i][1], acc[i][2], acc[i][3]);
    *(float4*)(Cm + (size_t)(bm0 + ty * 4 + i) * N + bn0 + tx * 4) = v;
  }
}

// ---------------- split fp32 -> bf16 hi/lo helpers ----------------
__device__ inline void split8(const float* __restrict__ p, bf16x8* hv, bf16x8* lv) {
  float4 a0 = *(const float4*)p, a1 = *(const float4*)(p + 4);
  float v[8] = {a0.x, a0.y, a0.z, a0.w, a1.x, a1.y, a1.z, a1.w};
  bf16x8 h, l;
  #pragma unroll
  for (int j = 0; j < 8; ++j) {
    bf16 hj = (bf16)v[j];
    h[j] = hj;
    l[j] = (bf16)(v[j] - (float)hj);
  }
  *hv = h; *lv = l;
}

__device__ inline void split8v(const float* __restrict__ v, bf16x8* hv, bf16x8* lv) {
  bf16x8 h, l;
  #pragma unroll
  for (int j = 0; j < 8; ++j) {
    bf16 hj = (bf16)v[j];
    h[j] = hj;
    l[j] = (bf16)(v[j] - (float)hj);
  }
  *hv = h; *lv = l;
}

// ---------------- split-bf16 MFMA GEMM for edge layers, inline combined-weight B -------
__global__ __launch_bounds__(256) void gemm_split(const float* __restrict__ A, int lda,
                                                  const float* __restrict__ w, int O,
                                                  float* __restrict__ C, int N, int K) {
  __shared__ u16 Ah[128 * 64];
  __shared__ u16 Al[128 * 64];
  __shared__ u16 Bh[128 * 64];
  __shared__ u16 Bl[128 * 64];
  int tid = threadIdx.x;
  int wave = tid >> 6, lane = tid & 63;
  int wr = wave >> 1, wc = wave & 1;
  int bn0 = blockIdx.x * 128, bm0 = blockIdx.y * 128;
  int lrow = lane & 15;
  int kgrp = lane >> 4;

  f32x4 acc[4][4];
  #pragma unroll
  for (int i = 0; i < 4; ++i)
    #pragma unroll
    for (int j = 0; j < 4; ++j) acc[i][j] = (f32x4){0.f, 0.f, 0.f, 0.f};

  for (int k0 = 0; k0 < K; k0 += 64) {
    #pragma unroll
    for (int i = 0; i < 4; ++i) {
      int chunk = tid + i * 256;
      int row = chunk >> 3;
      int cc = (chunk & 7) * 8;
      int byte = row * 128 + ((cc * 2) ^ ((row & 7) << 4));
      bf16x8 h, l;
      split8(A + (size_t)(bm0 + row) * lda + k0 + cc, &h, &l);
      *(bf16x8*)((char*)Ah + byte) = h;
      *(bf16x8*)((char*)Al + byte) = l;
      int j = bn0 + row;
      const float* base = w + (size_t)(j < O ? j : j - O) * (2 * K) + k0 + cc;
      float bv[8];
      if (j < O) {
        #pragma unroll
        for (int e = 0; e < 8; ++e) bv[e] = base[e] - base[K + e];
      } else {
        #pragma unroll
        for (int e = 0; e < 8; ++e) bv[e] = base[K + e];
      }
      split8v(bv, &h, &l);
      *(bf16x8*)((char*)Bh + byte) = h;
      *(bf16x8*)((char*)Bl + byte) = l;
    }
    __syncthreads();
    #pragma unroll
    for (int kk = 0; kk < 64; kk += 32) {
      int kb = (kk + kgrp * 8) * 2;
      bf16x8 afh[4], afl[4], bfh[4], bfl[4];
      #pragma unroll
      for (int f = 0; f < 4; ++f) {
        int arow = wr * 64 + f * 16 + lrow;
        int abyte = arow * 128 + (kb ^ ((arow & 7) << 4));
        afh[f] = *(const bf16x8*)((const char*)Ah + abyte);
        afl[f] = *(const bf16x8*)((const char*)Al + abyte);
        int brow = wc * 64 + f * 16 + lrow;
        int bbyte = brow * 128 + (kb ^ ((brow & 7) << 4));
        bfh[f] = *(const bf16x8*)((const char*)Bh + bbyte);
        bfl[f] = *(const bf16x8*)((const char*)Bl + bbyte);
      }
      #pragma unroll
      for (int fm = 0; fm < 4; ++fm)
        #pragma unroll
        for (int fn = 0; fn < 4; ++fn) {
          acc[fm][fn] = __builtin_amdgcn_mfma_f32_16x16x32_bf16(afh[fm], bfh[fn], acc[fm][fn], 0, 0, 0);
          acc[fm][fn] = __builtin_amdgcn_mfma_f32_16x16x32_bf16(afl[fm], bfh[fn], acc[fm][fn], 0, 0, 0);
          acc[fm][fn] = __builtin_amdgcn_mfma_f32_16x16x32_bf16(afh[fm], bfl[fn], acc[fm][fn], 0, 0, 0);
        }
    }
    __syncthreads();
  }
  #pragma unroll
  for (int fm = 0; fm < 4; ++fm) {
    int mrow = bm0 + wr * 64 + fm * 16 + kgrp * 4;
    #pragma unroll
    for (int fn = 0; fn < 4; ++fn) {
      int ncol = bn0 + wc * 64 + fn * 16 + lrow;
      #pragma unroll
      for (int r = 0; r < 4; ++r)
        C[(size_t)(mrow + r) * N + ncol] = acc[fm][fn][r];
    }
  }
}

// ---------------- split-bf16 MFMA GEMM for layer 5 with fused reduction ---------------
__global__ __launch_bounds__(256) void gemm_split_red(const float* __restrict__ A, int lda,
                                                      const float* __restrict__ Bt, int ldb,
                                                      float* __restrict__ parts, int K) {
  __shared__ u16 Ah[128 * 64];
  __shared__ u16 Al[128 * 64];
  __shared__ u16 Bh[128 * 64];
  __shared__ u16 Bl[128 * 64];
  int tid = threadIdx.x;
  int wave = tid >> 6, lane = tid & 63;
  int wr = wave >> 1, wc = wave & 1;
  int bn0 = blockIdx.x * 128, bm0 = blockIdx.y * 128;
  int lrow = lane & 15;
  int kgrp = lane >> 4;

  f32x4 acc[4][4];
  #pragma unroll
  for (int i = 0; i < 4; ++i)
    #pragma unroll
    for (int j = 0; j < 4; ++j) acc[i][j] = (f32x4){0.f, 0.f, 0.f, 0.f};

  for (int k0 = 0; k0 < K; k0 += 64) {
    #pragma unroll
    for (int i = 0; i < 4; ++i) {
      int chunk = tid + i * 256;
      int row = chunk >> 3;
      int cc = (chunk & 7) * 8;
      int byte = row * 128 + ((cc * 2) ^ ((row & 7) << 4));
      bf16x8 h, l;
      split8(A + (size_t)(bm0 + row) * lda + k0 + cc, &h, &l);
      *(bf16x8*)((char*)Ah + byte) = h;
      *(bf16x8*)((char*)Al + byte) = l;
      split8(Bt + (size_t)(bn0 + row) * ldb + k0 + cc, &h, &l);
      *(bf16x8*)((char*)Bh + byte) = h;
      *(bf16x8*)((char*)Bl + byte) = l;
    }
    __syncthreads();
    #pragma unroll
    for (int kk = 0; kk < 64; kk += 32) {
      int kb = (kk + kgrp * 8) * 2;
      bf16x8 afh[4], afl[4], bfh[4], bfl[4];
      #pragma unroll
      for (int f = 0; f < 4; ++f) {
        int arow = wr * 64 + f * 16 + lrow;
        int abyte = arow * 128 + (kb ^ ((arow & 7) << 4));
        afh[f] = *(const bf16x8*)((const char*)Ah + abyte);
        afl[f] = *(const bf16x8*)((const char*)Al + abyte);
        int brow = wc * 64 + f * 16 + lrow;
        int bbyte = brow * 128 + (kb ^ ((brow & 7) << 4));
        bfh[f] = *(const bf16x8*)((const char*)Bh + bbyte);
        bfl[f] = *(const bf16x8*)((const char*)Bl + bbyte);
      }
      #pragma unroll
      for (int fm = 0; fm < 4; ++fm)
        #pragma unroll
        for (int fn = 0; fn < 4; ++fn) {
          acc[fm][fn] = __builtin_amdgcn_mfma_f32_16x16x32_bf16(afh[fm], bfh[fn], acc[fm][fn], 0, 0, 0);
          acc[fm][fn] = __builtin_amdgcn_mfma_f32_16x16x32_bf16(afl[fm], bfh[fn], acc[fm][fn], 0, 0, 0);
          acc[fm][fn] = __builtin_amdgcn_mfma_f32_16x16x32_bf16(afh[fm], bfl[fn], acc[fm][fn], 0, 0, 0);
        }
    }
    __syncthreads();
  }

  float* scratch = (float*)Ah;
  int contrib = wr * 4 + kgrp;
  #pragma unroll
  for (int fn = 0; fn < 4; ++fn) {
    float mx = -3.4e38f, mn = 3.4e38f, s1 = 0.f, s2 = 0.f;
    #pragma unroll
    for (int fm = 0; fm < 4; ++fm)
      #pragma unroll
      for (int r = 0; r < 4; ++r) {
        float v = acc[fm][fn][r];
        mx = fmaxf(mx, v); mn = fminf(mn, v);
        s1 += v; s2 = fmaf(v, v, s2);
      }
    int col = wc * 64 + fn * 16 + lrow;
    float* sp = scratch + (contrib * 128 + col) * 4;
    sp[0] = mx; sp[1] = mn; sp[2] = s1; sp[3] = s2;
  }
  __syncthreads();
  if (tid < 128) {
    float mx = -3.4e38f, mn = 3.4e38f, s1 = 0.f, s2 = 0.f;
    #pragma unroll
    for (int c2 = 0; c2 < 8; ++c2) {
      const float* sp = scratch + (c2 * 128 + tid) * 4;
      mx = fmaxf(mx, sp[0]); mn = fminf(mn, sp[1]);
      s1 += sp[2]; s2 += sp[3];
    }
    size_t o = (size_t)blockIdx.y * 1024 + bn0 + tid;
    parts[o] = mx;
    parts[65536 + o] = mn;
    parts[131072 + o] = s1;
    parts[196608 + o] = s2;
  }
}

// ---------------- edge aggregation (vectorized): lane owns VW=O/64 channels ----------
template<int VW>
__global__ __launch_bounds__(256) void aggregate_t(const float* __restrict__ ay,
                                                   const int* __restrict__ idxb, int O,
                                                   float* __restrict__ mx,
                                                   float* __restrict__ mn,
                                                   float* __restrict__ sumsbin) {
  __shared__ float ls1[4][256];
  __shared__ float ls2[4][256];
  int warp = threadIdx.x >> 6, lane = threadIdx.x & 63;
  int bid = blockIdx.x;
  int swz = (bid & 7) * 256 + (bid >> 3);   // 2048 blocks -> batch = bid&7
  int pt = swz * 4 + warp;                  // 0..8191
  int b = pt >> 10;
  int twoO = 2 * O;
  int o0 = lane * VW;
  const float* ayrow = ay + (size_t)pt * twoO;

  int idxs[KNN_K];
  const int* ip = idxb + pt * KNN_K;
  #pragma unroll
  for (int k = 0; k < KNN_K; ++k) idxs[k] = ip[k];

  float s1[VW], s2[VW], vmx[VW], vmn[VW];
  #pragma unroll
  for (int u = 0; u < VW; ++u) { s1[u] = 0.f; s2[u] = 0.f; vmx[u] = -3.4e38f; vmn[u] = 3.4e38f; }

  #pragma unroll
  for (int k = 0; k < KNN_K; ++k) {
    const float* yp = ay + (size_t)(b * N_PTS + idxs[k]) * twoO + O + o0;
    float v[VW];
    if (VW == 4)      { float4 t = *(const float4*)yp; v[0] = t.x; v[1] = t.y; v[2] = t.z; v[3] = t.w; }
    else if (VW == 2) { float2 t = *(const float2*)yp; v[0] = t.x; v[1] = t.y; }
    else              { v[0] = yp[0]; }
    #pragma unroll
    for (int u = 0; u < VW; ++u) {
      s1[u] += v[u]; s2[u] = fmaf(v[u], v[u], s2[u]);
      vmx[u] = fmaxf(vmx[u], v[u]); vmn[u] = fminf(vmn[u], v[u]);
    }
  }

  float a[VW], omx[VW], omn[VW];
  if (VW == 4)      { float4 t = *(const float4*)(ayrow + o0); a[0] = t.x; a[1] = t.y; a[2] = t.z; a[3] = t.w; }
  else if (VW == 2) { float2 t = *(const float2*)(ayrow + o0); a[0] = t.x; a[1] = t.y; }
  else              { a[0] = ayrow[o0]; }
  #pragma unroll
  for (int u = 0; u < VW; ++u) {
    omx[u] = a[u] + vmx[u];
    omn[u] = a[u] + vmn[u];
    ls1[warp][o0 + u] = fmaf(20.f, a[u], s1[u]);
    ls2[warp][o0 + u] = s2[u] + a[u] * fmaf(20.f, a[u], 2.f * s1[u]);
  }
  if (VW == 4) {
    *(float4*)(mx + (size_t)pt * O + o0) = make_float4(omx[0], omx[1], omx[2], omx[3]);
    *(float4*)(mn + (size_t)pt * O + o0) = make_float4(omn[0], omn[1], omn[2], omn[3]);
  } else if (VW == 2) {
    *(float2*)(mx + (size_t)pt * O + o0) = make_float2(omx[0], omx[1]);
    *(float2*)(mn + (size_t)pt * O + o0) = make_float2(omn[0], omn[1]);
  } else {
    mx[(size_t)pt * O + o0] = omx[0];
    mn[(size_t)pt * O + o0] = omn[0];
  }
  __syncthreads();
  int bin = blockIdx.x & 63;
  float* gb = sumsbin + (size_t)bin * 512;
  for (int o = threadIdx.x; o < O; o += 256) {
    float t1 = ls1[0][o] + ls1[1][o] + ls1[2][o] + ls1[3][o];
    float t2 = ls2[0][o] + ls2[1][o] + ls2[2][o] + ls2[3][o];
    atomicAdd(&gb[o], t1);
    atomicAdd(&gb[256 + o], t2);
  }
}

// ---------------- reduce bins -> sums; zero bins afterward ----------------------------
__global__ __launch_bounds__(256) void reduce_bins(float* __restrict__ sumsbin,
                                                   float* __restrict__ sums, int O) {
  int o = threadIdx.x;
  if (o >= O) return;
  float a = 0.f, c = 0.f;
  for (int bin = 0; bin < 64; ++bin) {
    a += sumsbin[bin * 512 + o];
    c += sumsbin[bin * 512 + 256 + o];
    sumsbin[bin * 512 + o] = 0.f;
    sumsbin[bin * 512 + 256 + o] = 0.f;
  }
  sums[o] = a;
  sums[256 + o] = c;
}

// ---------------- finalize edge layer: BN + relu; optionally writes next layer's packs -
// Pack write is bitwise-identical to split_pack on the same v (verified: next layer's
// feature channel k == this layer's o; segin[l+1]==segout[l]). writePack=0 for l=3
// (O=256 exceeds the 16-plane pack layout; L5 doesn't use packs).
__global__ __launch_bounds__(256) void finalize_edge(const float* __restrict__ mx,
                                                     const float* __restrict__ mn,
                                                     const float* __restrict__ sums,
                                                     const float* __restrict__ g,
                                                     const float* __restrict__ beta,
                                                     int oshift,
                                                     float* __restrict__ outseg,
                                                     float cnt_inv,
                                                     bf16* __restrict__ packH,
                                                     bf16* __restrict__ packM,
                                                     bf16* __restrict__ packL,
                                                     int writePack) {
  int tid = blockIdx.x * 256 + threadIdx.x;
  int pt = tid >> oshift;
  int o = tid & ((1 << oshift) - 1);
  float s1 = sums[o], s2 = sums[256 + o];
  float mean = s1 * cnt_inv;
  float var = s2 * cnt_inv - mean * mean;
  float rstd = rsqrtf(var + BN_EPS);
  float sc = g[o] * rstd;
  float sel = (sc >= 0.f) ? mx[tid] : mn[tid];
  float v = fmaxf((sel - mean) * sc + beta[o], 0.f);
  outseg[(size_t)pt * CAT_C + o] = v;
  if (writePack) {
    bf16 hb = (bf16)v;       float r1 = v - (float)hb;
    bf16 mb = (bf16)r1;      float r2 = r1 - (float)mb;
    bf16 lb = (bf16)r2;
    int b = pt >> 10, col = pt & 1023;
    size_t dst = ((size_t)(b * 16 + (o >> 3)) * 1024 + col) * 8 + (o & 7);
    packH[dst] = hb;
    packM[dst] = mb;
    packL[dst] = lb;
  }
}

// ---------------- layer 5 finalize from tile partials ----------------
__global__ __launch_bounds__(256) void finalize5_fused(const float* __restrict__ parts,
                                                       const float* __restrict__ g,
                                                       const float* __restrict__ beta,
                                                       float* __restrict__ out) {
  int tid = blockIdx.x * 256 + threadIdx.x;
  int b = tid >> 10, o = tid & 1023;
  const float* pmx = parts;
  const float* pmn = parts + 65536;
  const float* ps1 = parts + 131072;
  const float* ps2 = parts + 196608;
  float s1 = 0.f, s2 = 0.f;
  for (int t = 0; t < 64; ++t) { s1 += ps1[t * 1024 + o]; s2 += ps2[t * 1024 + o]; }
  float mx = -3.4e38f, mn = 3.4e38f;
  #pragma unroll
  for (int t = 0; t < 8; ++t) {
    mx = fmaxf(mx, pmx[(b * 8 + t) * 1024 + o]);
    mn = fminf(mn, pmn[(b * 8 + t) * 1024 + o]);
  }
  float mean = s1 * (1.0f / 8192.0f);
  float var = s2 * (1.0f / 8192.0f) - mean * mean;
  float rstd = rsqrtf(var + BN_EPS);
  float sc = g[o] * rstd;
  float sel = (sc >= 0.f) ? mx : mn;
  float v = (sel - mean) * sc + beta[o];
  out[tid] = fmaxf(v, 0.f);
}

extern "C" void kernel_launch(void* const* d_in, const int* in_sizes, int n_in,
                              void* d_out, int out_size, void* d_ws, size_t ws_size,
                              hipStream_t stream) {
  const float* x = (const float*)d_in[0];
  const float* w[5]  = {(const float*)d_in[1], (const float*)d_in[4], (const float*)d_in[7],
                        (const float*)d_in[10], (const float*)d_in[13]};
  const float* gg[5] = {(const float*)d_in[2], (const float*)d_in[5], (const float*)d_in[8],
                        (const float*)d_in[11], (const float*)d_in[14]};
  const float* bb[5] = {(const float*)d_in[3], (const float*)d_in[6], (const float*)d_in[9],
                        (const float*)d_in[12], (const float*)d_in[15]};
  float* out = (float*)d_out;

  float* W = (float*)d_ws;
  size_t off = 0;
  float* feat0   = W + off; off += (size_t)B_SZ * N_PTS * 4;   // stride-4 padded
  float* catbuf  = W + off; off += (size_t)8192 * CAT_C;
  int*   idxbuf  = (int*)(W + off); off += (size_t)8192 * KNN_K;
  float* aybuf   = W + off; off += (size_t)8192 * 1024;
  float* mxbuf   = W + off; off += (size_t)8192 * 256;
  float* mnbuf   = W + off; off += (size_t)8192 * 256;
  float* wcbuf   = W + off; off += (size_t)512 * 1024;
  float* sumsbin = W + off; off += (size_t)64 * 512;
  float* sums    = W + off; off += 512;
  float* parts   = W + off; off += (size_t)4 * 64 * 1024;
  float* x2buf   = W + off; off += 8192;
  bf16*  packH   = (bf16*)(W + off); off += (size_t)8192 * 128 / 2;   // 2MB
  bf16*  packM   = (bf16*)(W + off); off += (size_t)8192 * 128 / 2;   // 2MB
  bf16*  packL   = (bf16*)(W + off); off += (size_t)8192 * 128 / 2;   // 2MB

  transpose_x<<<(B_SZ * 4 * N_PTS + 255) / 256, 256, 0, stream>>>(x, feat0);
  hipMemsetAsync(sumsbin, 0, (size_t)64 * 512 * sizeof(float), stream);  // first-launch poison clear

  const int Cs[4] = {4, 64, 64, 128};   // layer-0 padded to 4 (pad=0, values unchanged)
  const int Ks[4] = {3, 64, 64, 128};   // true K for the edge GEMM
  const int Os[4] = {64, 64, 128, 256};
  const int osh[4] = {6, 6, 7, 8};
  const int segin[4] = {0, 0, 64, 128};
  const int segout[4] = {0, 64, 128, 256};

  for (int l = 0; l < 4; ++l) {
    int C = Cs[l], O = Os[l], twoO = 2 * O;
    const float* featin = (l == 0) ? feat0 : (catbuf + segin[l]);
    int lda = (l == 0) ? 4 : CAT_C;
    int nks = (C + 31) / 32;            // 1,2,2,4

    xnorm_kernel<<<32, 256, 0, stream>>>(featin, lda, C, x2buf);
    if (l == 0)   // layers 1-3: packs already written by previous finalize_edge
      split_pack<<<512, 256, 0, stream>>>(featin, lda, C, packH, packM, packL);
    knn_mfma<<<512, 1024, 0, stream>>>(packH, packM, packL, x2buf, nks, idxbuf);

    if (l == 0) {
      build_wc<<<(Ks[l] * twoO + 255) / 256, 256, 0, stream>>>(w[l], Ks[l], O, wcbuf);
      gemm_kernel<<<dim3(twoO / 64, 8192 / 64), 256, 0, stream>>>(featin, lda, wcbuf, aybuf,
                                                                  8192, twoO, Ks[l]);
    } else {
      gemm_split<<<dim3(twoO / 128, 8192 / 128), 256, 0, stream>>>(featin, lda, w[l], O,
                                                                   aybuf, twoO, Ks[l]);
    }
    if (O == 256)
      aggregate_t<4><<<2048, 256, 0, stream>>>(aybuf, idxbuf, O, mxbuf, mnbuf, sumsbin);
    else if (O == 128)
      aggregate_t<2><<<2048, 256, 0, stream>>>(aybuf, idxbuf, O, mxbuf, mnbuf, sumsbin);
    else
      aggregate_t<1><<<2048, 256, 0, stream>>>(aybuf, idxbuf, O, mxbuf, mnbuf, sumsbin);
    reduce_bins<<<1, 256, 0, stream>>>(sumsbin, sums, O);
    finalize_edge<<<(8192 * O) / 256, 256, 0, stream>>>(mxbuf, mnbuf, sums, gg[l], bb[l],
                                                        osh[l], catbuf + segout[l],
                                                        1.0f / (8192.0f * KNN_K),
                                                        packH, packM, packL,
                                                        (l < 3) ? 1 : 0);
  }

  // layer 5: h5 = cat * w5^T via split-bf16 MFMA with fused per-tile reduction
  gemm_split_red<<<dim3(1024 / 128, 8192 / 128), 256, 0, stream>>>(catbuf, CAT_C, w[4], 512,
                                                                   parts, 512);
  finalize5_fused<<<8192 / 256, 256, 0, stream>>>(parts, gg[4], bb[4], out);
}

// Round 24
// 337.587 us; speedup vs baseline: 1.6437x; 1.0374x over previous
//
#include <hip/hip_runtime.h>
#include <cstddef>

#define B_SZ 8
#define N_PTS 1024
#define KNN_K 20
#define CAT_C 512
#define BN_EPS 1e-5f

typedef unsigned short u16;
typedef unsigned int u32;
typedef __bf16 bf16;
typedef __bf16 bf16x8 __attribute__((ext_vector_type(8)));
typedef float f32x4 __attribute__((ext_vector_type(4)));

// ---------------- transpose x (B,3,N) -> feat0 (B,N,4), pad col 3 = 0 ----------------
__global__ __launch_bounds__(256) void transpose_x(const float* __restrict__ x,
                                                   float* __restrict__ feat0) {
  int t = blockIdx.x * 256 + threadIdx.x;
  if (t >= B_SZ * 4 * N_PTS) return;
  int b = t >> 12;
  int r = t & 4095;
  int c = r >> 10;
  int n = r & 1023;
  feat0[((size_t)(b * N_PTS + n)) * 4 + c] =
      (c < 3) ? x[(size_t)b * 3 * N_PTS + c * N_PTS + n] : 0.f;
}

// ---------------- squared norms per point (layer 0 only, exact fp32) ----------------
__global__ __launch_bounds__(256) void xnorm_kernel(const float* __restrict__ feat, int lda,
                                                    int C, float* __restrict__ x2) {
  int p = blockIdx.x * 256 + threadIdx.x;
  if (p >= 8192) return;
  const float* r = feat + (size_t)p * lda;
  float s = 0.f;
  for (int c = 0; c < C; c += 4) {
    float4 v = *(const float4*)(r + c);
    s = fmaf(v.x, v.x, s); s = fmaf(v.y, v.y, s);
    s = fmaf(v.z, v.z, s); s = fmaf(v.w, v.w, s);
  }
  x2[p] = s;
}

// ---------------- triple-split features, B-coalesced layout (layer 0 only) -----------
__global__ __launch_bounds__(256) void split_pack(const float* __restrict__ feat, int lda,
                                                  int C, bf16* __restrict__ packH,
                                                  bf16* __restrict__ packM,
                                                  bf16* __restrict__ packL) {
  int t = blockIdx.x * 256 + threadIdx.x;     // 8192*16 threads, 8 k's each
  if (t >= 8192 * 16) return;
  int p = t >> 4, c = t & 15;                 // p = global point, c = q plane
  int b = p >> 10, col = p & 1023;
  int k0 = c * 8;
  bf16x8 h, m, l;
  #pragma unroll
  for (int e = 0; e < 8; ++e) {
    int k = k0 + e;
    float v = (k < C) ? feat[(size_t)p * lda + k] : 0.f;
    bf16 hb = (bf16)v;       float r1 = v - (float)hb;
    bf16 mb = (bf16)r1;      float r2 = r1 - (float)mb;
    bf16 lb = (bf16)r2;
    h[e] = hb; m[e] = mb; l[e] = lb;
  }
  size_t dst = ((size_t)(b * 16 + c) * 1024 + col) * 8;
  *(bf16x8*)(packH + dst) = h;
  *(bf16x8*)(packM + dst) = m;
  *(bf16x8*)(packL + dst) = l;
}

// ---- DPP value-reduce stages (tree verified bit-exact in R10/R11/R16) ----
#define DPP_MAX_STAGE(CTRL)                                                          \
  {                                                                                  \
    int nb = __builtin_amdgcn_update_dpp((int)0xFF800000, __float_as_int(mx),        \
                                         (CTRL), 0xF, 0xF, false);                   \
    mx = fmaxf(mx, __int_as_float(nb));                                              \
  }
#define DPP_MIN_STAGE(CTRL)                                                          \
  {                                                                                  \
    int nb = __builtin_amdgcn_update_dpp((int)0x7fffffff, mc,                        \
                                         (CTRL), 0xF, 0xF, false);                   \
    mc = (nb < mc) ? nb : mc;                                                        \
  }

// ---------------- KNN: triple-split MFMA distances + R16 DPP selection ----------------
__global__ __launch_bounds__(1024) void knn_mfma(const bf16* __restrict__ packH,
                                                 const bf16* __restrict__ packM,
                                                 const bf16* __restrict__ packL,
                                                 const float* __restrict__ x2,
                                                 int nks,
                                                 int* __restrict__ idxout) {
  __shared__ u16 Ah[16 * 128];        // 4KB each, row stride 256B, XOR-swizzled
  __shared__ u16 Am[16 * 128];
  __shared__ u16 Al[16 * 128];
  __shared__ float Ds[16 * 1028];     // 65.8KB, padded stride
  int tid = threadIdx.x;
  int w = tid >> 6, lane = tid & 63;
  int bid = blockIdx.x;
  int swz = (bid & 7) * 64 + (bid >> 3);   // 512 blocks -> batch = bid&7
  int row0 = swz * 16;
  int b = row0 >> 10;
  int col0 = row0 & 1023;

  if (tid < 256) {
    int r = tid >> 4, c = tid & 15;   // c = q plane
    int byte = r * 256 + ((c * 16) ^ ((r & 7) << 4));
    size_t src = ((size_t)(b * 16 + c) * 1024 + col0 + r) * 8;
    *(bf16x8*)((char*)Ah + byte) = *(const bf16x8*)(packH + src);
    *(bf16x8*)((char*)Am + byte) = *(const bf16x8*)(packM + src);
    *(bf16x8*)((char*)Al + byte) = *(const bf16x8*)(packL + src);
  }
  __syncthreads();

  int lrow = lane & 15, kgrp = lane >> 4;
  int abase = lrow * 256;

  f32x4 acc[4];
  #pragma unroll
  for (int f = 0; f < 4; ++f) acc[f] = (f32x4){0.f, 0.f, 0.f, 0.f};

  for (int ks = 0; ks < nks; ++ks) {
    int kb = (ks * 32 + kgrp * 8) * 2;
    int aoff = abase + (kb ^ ((lrow & 7) << 4));
    bf16x8 a_h = *(const bf16x8*)((const char*)Ah + aoff);
    bf16x8 a_m = *(const bf16x8*)((const char*)Am + aoff);
    bf16x8 a_l = *(const bf16x8*)((const char*)Al + aoff);
    int q = ks * 4 + kgrp;
    size_t pbase = (size_t)(b * 16 + q) * 1024;
    #pragma unroll
    for (int f = 0; f < 4; ++f) {
      int col = w * 64 + f * 16 + lrow;
      bf16x8 b_h = *(const bf16x8*)(packH + (pbase + col) * 8);
      bf16x8 b_m = *(const bf16x8*)(packM + (pbase + col) * 8);
      bf16x8 b_l = *(const bf16x8*)(packL + (pbase + col) * 8);
      acc[f] = __builtin_amdgcn_mfma_f32_16x16x32_bf16(a_h, b_h, acc[f], 0, 0, 0);
      acc[f] = __builtin_amdgcn_mfma_f32_16x16x32_bf16(a_h, b_m, acc[f], 0, 0, 0);
      acc[f] = __builtin_amdgcn_mfma_f32_16x16x32_bf16(a_m, b_h, acc[f], 0, 0, 0);
      acc[f] = __builtin_amdgcn_mfma_f32_16x16x32_bf16(a_m, b_m, acc[f], 0, 0, 0);
      acc[f] = __builtin_amdgcn_mfma_f32_16x16x32_bf16(a_h, b_l, acc[f], 0, 0, 0);
      acc[f] = __builtin_amdgcn_mfma_f32_16x16x32_bf16(a_l, b_h, acc[f], 0, 0, 0);
      acc[f] = __builtin_amdgcn_mfma_f32_16x16x32_bf16(a_m, b_l, acc[f], 0, 0, 0);
      acc[f] = __builtin_amdgcn_mfma_f32_16x16x32_bf16(a_l, b_m, acc[f], 0, 0, 0);
    }
  }
  // D epilogue (m89-verified layout: row=(lane>>4)*4+r, col=lane&15)
  #pragma unroll
  for (int f = 0; f < 4; ++f) {
    int col = w * 64 + f * 16 + lrow;
    #pragma unroll
    for (int r = 0; r < 4; ++r)
      Ds[(kgrp * 4 + r) * 1028 + col] = acc[f][r];
  }
  __syncthreads();

  // selection: wave w handles row w (R16 passer, verbatim semantics)
  const float* x2b = x2 + b * N_PTS;
  int row = row0 + w;
  float x2n = x2[row];
  float accv[16];
  #pragma unroll
  for (int j = 0; j < 16; ++j) {
    float d = Ds[w * 1028 + j * 64 + lane];
    accv[j] = (2.f * d - x2n) - x2b[j * 64 + lane];
  }

  for (int rr = 0; rr < KNN_K; ++rr) {
    float m01 = fmaxf(accv[0], accv[1]),   m23 = fmaxf(accv[2], accv[3]);
    float m45 = fmaxf(accv[4], accv[5]),   m67 = fmaxf(accv[6], accv[7]);
    float m89 = fmaxf(accv[8], accv[9]),   mab = fmaxf(accv[10], accv[11]);
    float mcd = fmaxf(accv[12], accv[13]), mef = fmaxf(accv[14], accv[15]);
    float mx = fmaxf(fmaxf(fmaxf(m01, m23), fmaxf(m45, m67)),
                     fmaxf(fmaxf(m89, mab), fmaxf(mcd, mef)));
    DPP_MAX_STAGE(0x111)
    DPP_MAX_STAGE(0x112)
    DPP_MAX_STAGE(0x114)
    DPP_MAX_STAGE(0x118)
    DPP_MAX_STAGE(0x142)
    DPP_MAX_STAGE(0x143)
    mx = __int_as_float(__builtin_amdgcn_readlane(__float_as_int(mx), 63));

    int jloc = 16;
    #pragma unroll
    for (int j = 15; j >= 0; --j)
      if (accv[j] == mx) jloc = j;
    int mc = (jloc < 16) ? ((jloc << 6) | lane) : 0x7fffffff;
    DPP_MIN_STAGE(0x111)
    DPP_MIN_STAGE(0x112)
    DPP_MIN_STAGE(0x114)
    DPP_MIN_STAGE(0x118)
    DPP_MIN_STAGE(0x142)
    DPP_MIN_STAGE(0x143)
    int si = __builtin_amdgcn_readlane(mc, 63);

    int jj = si >> 6, ln = si & 63;
    bool isln = (lane == ln);
    #pragma unroll
    for (int j = 0; j < 16; ++j)
      if (j == jj && isln) accv[j] = -3.4e38f;
    if (lane == 0) idxout[row * KNN_K + rr] = si;
  }
}

// ---------------- build combined weight Wc (fp32): [w1-w2 | w2] (layer 0 only) ---------
__global__ __launch_bounds__(256) void build_wc(const float* __restrict__ w, int C, int O,
                                                float* __restrict__ wc) {
  int t = blockIdx.x * 256 + threadIdx.x;
  int twoO = 2 * O;
  if (t >= C * twoO) return;
  int c = t / twoO, j = t - c * twoO;
  float v;
  if (j < O) v = w[j * (2 * C) + c] - w[j * (2 * C) + C + c];
  else       v = w[(j - O) * (2 * C) + C + c];
  wc[t] = v;
}

// ---------------- fp32 GEMM (layer 0 only, K=3): C[M,N] = A[M,K](lda) * B[K,N] ---------
__global__ __launch_bounds__(256) void gemm_kernel(const float* __restrict__ A, int lda,
                                                   const float* __restrict__ Bm,
                                                   float* __restrict__ Cm,
                                                   int M, int N, int K) {
  __shared__ float As[16][64];
  __shared__ float Bs[16][68];
  int tx = threadIdx.x & 15, ty = threadIdx.x >> 4;
  int bn0 = blockIdx.x * 64, bm0 = blockIdx.y * 64;
  float acc[4][4];
  #pragma unroll
  for (int i = 0; i < 4; ++i)
    #pragma unroll
    for (int j = 0; j < 4; ++j) acc[i][j] = 0.f;

  for (int k0 = 0; k0 < K; k0 += 16) {
    {
      int t = threadIdx.x;
      int m = t >> 2, kb = (t & 3) * 4;
      const float* ap = A + (size_t)(bm0 + m) * lda + k0 + kb;
      #pragma unroll
      for (int i = 0; i < 4; ++i) As[kb + i][m] = (k0 + kb + i < K) ? ap[i] : 0.f;
      int r = t >> 4, c4 = (t & 15) * 4;
      float4 bv = make_float4(0.f, 0.f, 0.f, 0.f);
      if (k0 + r < K) bv = *(const float4*)(Bm + (size_t)(k0 + r) * N + bn0 + c4);
      *(float4*)&Bs[r][c4] = bv;
    }
    __syncthreads();
    #pragma unroll
    for (int k = 0; k < 16; ++k) {
      float a0[4];
      #pragma unroll
      for (int i = 0; i < 4; ++i) a0[i] = As[k][ty * 4 + i];
      float4 bv = *(const float4*)&Bs[k][tx * 4];
      float b0[4] = {bv.x, bv.y, bv.z, bv.w};
      #pragma unroll
      for (int i = 0; i < 4; ++i)
        #pragma unroll
        for (int j = 0; j < 4; ++j) acc[i][j] = fmaf(a0[i], b0[j], acc[i][j]);
    }
    __syncthreads();
  }
  #pragma unroll
  for (int i = 0; i < 4; ++i) {
    float4 v = make_float4(acc[i][0], acc[i][1], acc[i][2], acc[i][3]);
    *(float4*)(Cm + (size_t)(bm0 + ty * 4 + i) * N + bn0 + tx * 4) = v;
  }
}

// ---------------- split fp32 -> bf16 hi/lo helpers ----------------
__device__ inline void split8(const float* __restrict__ p, bf16x8* hv, bf16x8* lv) {
  float4 a0 = *(const float4*)p, a1 = *(const float4*)(p + 4);
  float v[8] = {a0.x, a0.y, a0.z, a0.w, a1.x, a1.y, a1.z, a1.w};
  bf16x8 h, l;
  #pragma unroll
  for (int j = 0; j < 8; ++j) {
    bf16 hj = (bf16)v[j];
    h[j] = hj;
    l[j] = (bf16)(v[j] - (float)hj);
  }
  *hv = h; *lv = l;
}

__device__ inline void split8v(const float* __restrict__ v, bf16x8* hv, bf16x8* lv) {
  bf16x8 h, l;
  #pragma unroll
  for (int j = 0; j < 8; ++j) {
    bf16 hj = (bf16)v[j];
    h[j] = hj;
    l[j] = (bf16)(v[j] - (float)hj);
  }
  *hv = h; *lv = l;
}

// ---------------- split-bf16 MFMA GEMM for edge layers, inline combined-weight B -------
__global__ __launch_bounds__(256) void gemm_split(const float* __restrict__ A, int lda,
                                                  const float* __restrict__ w, int O,
                                                  float* __restrict__ C, int N, int K) {
  __shared__ u16 Ah[128 * 64];
  __shared__ u16 Al[128 * 64];
  __shared__ u16 Bh[128 * 64];
  __shared__ u16 Bl[128 * 64];
  int tid = threadIdx.x;
  int wave = tid >> 6, lane = tid & 63;
  int wr = wave >> 1, wc = wave & 1;
  int bn0 = blockIdx.x * 128, bm0 = blockIdx.y * 128;
  int lrow = lane & 15;
  int kgrp = lane >> 4;

  f32x4 acc[4][4];
  #pragma unroll
  for (int i = 0; i < 4; ++i)
    #pragma unroll
    for (int j = 0; j < 4; ++j) acc[i][j] = (f32x4){0.f, 0.f, 0.f, 0.f};

  for (int k0 = 0; k0 < K; k0 += 64) {
    #pragma unroll
    for (int i = 0; i < 4; ++i) {
      int chunk = tid + i * 256;
      int row = chunk >> 3;
      int cc = (chunk & 7) * 8;
      int byte = row * 128 + ((cc * 2) ^ ((row & 7) << 4));
      bf16x8 h, l;
      split8(A + (size_t)(bm0 + row) * lda + k0 + cc, &h, &l);
      *(bf16x8*)((char*)Ah + byte) = h;
      *(bf16x8*)((char*)Al + byte) = l;
      int j = bn0 + row;
      const float* base = w + (size_t)(j < O ? j : j - O) * (2 * K) + k0 + cc;
      float bv[8];
      if (j < O) {
        #pragma unroll
        for (int e = 0; e < 8; ++e) bv[e] = base[e] - base[K + e];
      } else {
        #pragma unroll
        for (int e = 0; e < 8; ++e) bv[e] = base[K + e];
      }
      split8v(bv, &h, &l);
      *(bf16x8*)((char*)Bh + byte) = h;
      *(bf16x8*)((char*)Bl + byte) = l;
    }
    __syncthreads();
    #pragma unroll
    for (int kk = 0; kk < 64; kk += 32) {
      int kb = (kk + kgrp * 8) * 2;
      bf16x8 afh[4], afl[4], bfh[4], bfl[4];
      #pragma unroll
      for (int f = 0; f < 4; ++f) {
        int arow = wr * 64 + f * 16 + lrow;
        int abyte = arow * 128 + (kb ^ ((arow & 7) << 4));
        afh[f] = *(const bf16x8*)((const char*)Ah + abyte);
        afl[f] = *(const bf16x8*)((const char*)Al + abyte);
        int brow = wc * 64 + f * 16 + lrow;
        int bbyte = brow * 128 + (kb ^ ((brow & 7) << 4));
        bfh[f] = *(const bf16x8*)((const char*)Bh + bbyte);
        bfl[f] = *(const bf16x8*)((const char*)Bl + bbyte);
      }
      #pragma unroll
      for (int fm = 0; fm < 4; ++fm)
        #pragma unroll
        for (int fn = 0; fn < 4; ++fn) {
          acc[fm][fn] = __builtin_amdgcn_mfma_f32_16x16x32_bf16(afh[fm], bfh[fn], acc[fm][fn], 0, 0, 0);
          acc[fm][fn] = __builtin_amdgcn_mfma_f32_16x16x32_bf16(afl[fm], bfh[fn], acc[fm][fn], 0, 0, 0);
          acc[fm][fn] = __builtin_amdgcn_mfma_f32_16x16x32_bf16(afh[fm], bfl[fn], acc[fm][fn], 0, 0, 0);
        }
    }
    __syncthreads();
  }
  #pragma unroll
  for (int fm = 0; fm < 4; ++fm) {
    int mrow = bm0 + wr * 64 + fm * 16 + kgrp * 4;
    #pragma unroll
    for (int fn = 0; fn < 4; ++fn) {
      int ncol = bn0 + wc * 64 + fn * 16 + lrow;
      #pragma unroll
      for (int r = 0; r < 4; ++r)
        C[(size_t)(mrow + r) * N + ncol] = acc[fm][fn][r];
    }
  }
}

// ---------------- split-bf16 MFMA GEMM for layer 5 with fused reduction ---------------
__global__ __launch_bounds__(256) void gemm_split_red(const float* __restrict__ A, int lda,
                                                      const float* __restrict__ Bt, int ldb,
                                                      float* __restrict__ parts, int K) {
  __shared__ u16 Ah[128 * 64];
  __shared__ u16 Al[128 * 64];
  __shared__ u16 Bh[128 * 64];
  __shared__ u16 Bl[128 * 64];
  int tid = threadIdx.x;
  int wave = tid >> 6, lane = tid & 63;
  int wr = wave >> 1, wc = wave & 1;
  int bn0 = blockIdx.x * 128, bm0 = blockIdx.y * 128;
  int lrow = lane & 15;
  int kgrp = lane >> 4;

  f32x4 acc[4][4];
  #pragma unroll
  for (int i = 0; i < 4; ++i)
    #pragma unroll
    for (int j = 0; j < 4; ++j) acc[i][j] = (f32x4){0.f, 0.f, 0.f, 0.f};

  for (int k0 = 0; k0 < K; k0 += 64) {
    #pragma unroll
    for (int i = 0; i < 4; ++i) {
      int chunk = tid + i * 256;
      int row = chunk >> 3;
      int cc = (chunk & 7) * 8;
      int byte = row * 128 + ((cc * 2) ^ ((row & 7) << 4));
      bf16x8 h, l;
      split8(A + (size_t)(bm0 + row) * lda + k0 + cc, &h, &l);
      *(bf16x8*)((char*)Ah + byte) = h;
      *(bf16x8*)((char*)Al + byte) = l;
      split8(Bt + (size_t)(bn0 + row) * ldb + k0 + cc, &h, &l);
      *(bf16x8*)((char*)Bh + byte) = h;
      *(bf16x8*)((char*)Bl + byte) = l;
    }
    __syncthreads();
    #pragma unroll
    for (int kk = 0; kk < 64; kk += 32) {
      int kb = (kk + kgrp * 8) * 2;
      bf16x8 afh[4], afl[4], bfh[4], bfl[4];
      #pragma unroll
      for (int f = 0; f < 4; ++f) {
        int arow = wr * 64 + f * 16 + lrow;
        int abyte = arow * 128 + (kb ^ ((arow & 7) << 4));
        afh[f] = *(const bf16x8*)((const char*)Ah + abyte);
        afl[f] = *(const bf16x8*)((const char*)Al + abyte);
        int brow = wc * 64 + f * 16 + lrow;
        int bbyte = brow * 128 + (kb ^ ((brow & 7) << 4));
        bfh[f] = *(const bf16x8*)((const char*)Bh + bbyte);
        bfl[f] = *(const bf16x8*)((const char*)Bl + bbyte);
      }
      #pragma unroll
      for (int fm = 0; fm < 4; ++fm)
        #pragma unroll
        for (int fn = 0; fn < 4; ++fn) {
          acc[fm][fn] = __builtin_amdgcn_mfma_f32_16x16x32_bf16(afh[fm], bfh[fn], acc[fm][fn], 0, 0, 0);
          acc[fm][fn] = __builtin_amdgcn_mfma_f32_16x16x32_bf16(afl[fm], bfh[fn], acc[fm][fn], 0, 0, 0);
          acc[fm][fn] = __builtin_amdgcn_mfma_f32_16x16x32_bf16(afh[fm], bfl[fn], acc[fm][fn], 0, 0, 0);
        }
    }
    __syncthreads();
  }

  float* scratch = (float*)Ah;
  int contrib = wr * 4 + kgrp;
  #pragma unroll
  for (int fn = 0; fn < 4; ++fn) {
    float mx = -3.4e38f, mn = 3.4e38f, s1 = 0.f, s2 = 0.f;
    #pragma unroll
    for (int fm = 0; fm < 4; ++fm)
      #pragma unroll
      for (int r = 0; r < 4; ++r) {
        float v = acc[fm][fn][r];
        mx = fmaxf(mx, v); mn = fminf(mn, v);
        s1 += v; s2 = fmaf(v, v, s2);
      }
    int col = wc * 64 + fn * 16 + lrow;
    float* sp = scratch + (contrib * 128 + col) * 4;
    sp[0] = mx; sp[1] = mn; sp[2] = s1; sp[3] = s2;
  }
  __syncthreads();
  if (tid < 128) {
    float mx = -3.4e38f, mn = 3.4e38f, s1 = 0.f, s2 = 0.f;
    #pragma unroll
    for (int c2 = 0; c2 < 8; ++c2) {
      const float* sp = scratch + (c2 * 128 + tid) * 4;
      mx = fmaxf(mx, sp[0]); mn = fminf(mn, sp[1]);
      s1 += sp[2]; s2 += sp[3];
    }
    size_t o = (size_t)blockIdx.y * 1024 + bn0 + tid;
    parts[o] = mx;
    parts[65536 + o] = mn;
    parts[131072 + o] = s1;
    parts[196608 + o] = s2;
  }
}

// ---------------- edge aggregation (vectorized): lane owns VW=O/64 channels ----------
template<int VW>
__global__ __launch_bounds__(256) void aggregate_t(const float* __restrict__ ay,
                                                   const int* __restrict__ idxb, int O,
                                                   float* __restrict__ mx,
                                                   float* __restrict__ mn,
                                                   float* __restrict__ sumsbin) {
  __shared__ float ls1[4][256];
  __shared__ float ls2[4][256];
  int warp = threadIdx.x >> 6, lane = threadIdx.x & 63;
  int bid = blockIdx.x;
  int swz = (bid & 7) * 256 + (bid >> 3);   // 2048 blocks -> batch = bid&7
  int pt = swz * 4 + warp;                  // 0..8191
  int b = pt >> 10;
  int twoO = 2 * O;
  int o0 = lane * VW;
  const float* ayrow = ay + (size_t)pt * twoO;

  int idxs[KNN_K];
  const int* ip = idxb + pt * KNN_K;
  #pragma unroll
  for (int k = 0; k < KNN_K; ++k) idxs[k] = ip[k];

  float s1[VW], s2[VW], vmx[VW], vmn[VW];
  #pragma unroll
  for (int u = 0; u < VW; ++u) { s1[u] = 0.f; s2[u] = 0.f; vmx[u] = -3.4e38f; vmn[u] = 3.4e38f; }

  #pragma unroll
  for (int k = 0; k < KNN_K; ++k) {
    const float* yp = ay + (size_t)(b * N_PTS + idxs[k]) * twoO + O + o0;
    float v[VW];
    if (VW == 4)      { float4 t = *(const float4*)yp; v[0] = t.x; v[1] = t.y; v[2] = t.z; v[3] = t.w; }
    else if (VW == 2) { float2 t = *(const float2*)yp; v[0] = t.x; v[1] = t.y; }
    else              { v[0] = yp[0]; }
    #pragma unroll
    for (int u = 0; u < VW; ++u) {
      s1[u] += v[u]; s2[u] = fmaf(v[u], v[u], s2[u]);
      vmx[u] = fmaxf(vmx[u], v[u]); vmn[u] = fminf(vmn[u], v[u]);
    }
  }

  float a[VW], omx[VW], omn[VW];
  if (VW == 4)      { float4 t = *(const float4*)(ayrow + o0); a[0] = t.x; a[1] = t.y; a[2] = t.z; a[3] = t.w; }
  else if (VW == 2) { float2 t = *(const float2*)(ayrow + o0); a[0] = t.x; a[1] = t.y; }
  else              { a[0] = ayrow[o0]; }
  #pragma unroll
  for (int u = 0; u < VW; ++u) {
    omx[u] = a[u] + vmx[u];
    omn[u] = a[u] + vmn[u];
    ls1[warp][o0 + u] = fmaf(20.f, a[u], s1[u]);
    ls2[warp][o0 + u] = s2[u] + a[u] * fmaf(20.f, a[u], 2.f * s1[u]);
  }
  if (VW == 4) {
    *(float4*)(mx + (size_t)pt * O + o0) = make_float4(omx[0], omx[1], omx[2], omx[3]);
    *(float4*)(mn + (size_t)pt * O + o0) = make_float4(omn[0], omn[1], omn[2], omn[3]);
  } else if (VW == 2) {
    *(float2*)(mx + (size_t)pt * O + o0) = make_float2(omx[0], omx[1]);
    *(float2*)(mn + (size_t)pt * O + o0) = make_float2(omn[0], omn[1]);
  } else {
    mx[(size_t)pt * O + o0] = omx[0];
    mn[(size_t)pt * O + o0] = omn[0];
  }
  __syncthreads();
  int bin = blockIdx.x & 63;
  float* gb = sumsbin + (size_t)bin * 512;
  for (int o = threadIdx.x; o < O; o += 256) {
    float t1 = ls1[0][o] + ls1[1][o] + ls1[2][o] + ls1[3][o];
    float t2 = ls2[0][o] + ls2[1][o] + ls2[2][o] + ls2[3][o];
    atomicAdd(&gb[o], t1);
    atomicAdd(&gb[256 + o], t2);
  }
}

// ---------------- reduce bins -> sums; zero bins afterward ----------------------------
__global__ __launch_bounds__(256) void reduce_bins(float* __restrict__ sumsbin,
                                                   float* __restrict__ sums, int O) {
  int o = threadIdx.x;
  if (o >= O) return;
  float a = 0.f, c = 0.f;
  for (int bin = 0; bin < 64; ++bin) {
    a += sumsbin[bin * 512 + o];
    c += sumsbin[bin * 512 + 256 + o];
    sumsbin[bin * 512 + o] = 0.f;
    sumsbin[bin * 512 + 256 + o] = 0.f;
  }
  sums[o] = a;
  sums[256 + o] = c;
}

// ---------------- finalize edge layer: BN + relu; writes next layer's packs + x2 -------
// Pack write bitwise-identical to split_pack on the same v; x2 = sum_o v^2 per point
// via LDS tree reduction (block covers whole points: O | 256). writeAux=0 for l=3.
__global__ __launch_bounds__(256) void finalize_edge(const float* __restrict__ mx,
                                                     const float* __restrict__ mn,
                                                     const float* __restrict__ sums,
                                                     const float* __restrict__ g,
                                                     const float* __restrict__ beta,
                                                     int oshift,
                                                     float* __restrict__ outseg,
                                                     float cnt_inv,
                                                     bf16* __restrict__ packH,
                                                     bf16* __restrict__ packM,
                                                     bf16* __restrict__ packL,
                                                     float* __restrict__ x2out,
                                                     int writeAux) {
  __shared__ float red[256];
  int tid = blockIdx.x * 256 + threadIdx.x;
  int pt = tid >> oshift;
  int o = tid & ((1 << oshift) - 1);
  float s1 = sums[o], s2 = sums[256 + o];
  float mean = s1 * cnt_inv;
  float var = s2 * cnt_inv - mean * mean;
  float rstd = rsqrtf(var + BN_EPS);
  float sc = g[o] * rstd;
  float sel = (sc >= 0.f) ? mx[tid] : mn[tid];
  float v = fmaxf((sel - mean) * sc + beta[o], 0.f);
  outseg[(size_t)pt * CAT_C + o] = v;
  if (writeAux) {
    bf16 hb = (bf16)v;       float r1 = v - (float)hb;
    bf16 mb = (bf16)r1;      float r2 = r1 - (float)mb;
    bf16 lb = (bf16)r2;
    int b = pt >> 10, col = pt & 1023;
    size_t dst = ((size_t)(b * 16 + (o >> 3)) * 1024 + col) * 8 + (o & 7);
    packH[dst] = hb;
    packM[dst] = mb;
    packL[dst] = lb;
    // per-point x2 = sum of v^2 over this layer's O channels (tree order)
    red[threadIdx.x] = v * v;
    __syncthreads();
    int O = 1 << oshift;
    for (int s = O >> 1; s >= 1; s >>= 1) {
      if (o < s) red[threadIdx.x] += red[threadIdx.x + s];
      __syncthreads();
    }
    if (o == 0) x2out[pt] = red[threadIdx.x];
  }
}

// ---------------- layer 5 finalize from tile partials ----------------
__global__ __launch_bounds__(256) void finalize5_fused(const float* __restrict__ parts,
                                                       const float* __restrict__ g,
                                                       const float* __restrict__ beta,
                                                       float* __restrict__ out) {
  int tid = blockIdx.x * 256 + threadIdx.x;
  int b = tid >> 10, o = tid & 1023;
  const float* pmx = parts;
  const float* pmn = parts + 65536;
  const float* ps1 = parts + 131072;
  const float* ps2 = parts + 196608;
  float s1 = 0.f, s2 = 0.f;
  for (int t = 0; t < 64; ++t) { s1 += ps1[t * 1024 + o]; s2 += ps2[t * 1024 + o]; }
  float mx = -3.4e38f, mn = 3.4e38f;
  #pragma unroll
  for (int t = 0; t < 8; ++t) {
    mx = fmaxf(mx, pmx[(b * 8 + t) * 1024 + o]);
    mn = fminf(mn, pmn[(b * 8 + t) * 1024 + o]);
  }
  float mean = s1 * (1.0f / 8192.0f);
  float var = s2 * (1.0f / 8192.0f) - mean * mean;
  float rstd = rsqrtf(var + BN_EPS);
  float sc = g[o] * rstd;
  float sel = (sc >= 0.f) ? mx : mn;
  float v = (sel - mean) * sc + beta[o];
  out[tid] = fmaxf(v, 0.f);
}

extern "C" void kernel_launch(void* const* d_in, const int* in_sizes, int n_in,
                              void* d_out, int out_size, void* d_ws, size_t ws_size,
                              hipStream_t stream) {
  const float* x = (const float*)d_in[0];
  const float* w[5]  = {(const float*)d_in[1], (const float*)d_in[4], (const float*)d_in[7],
                        (const float*)d_in[10], (const float*)d_in[13]};
  const float* gg[5] = {(const float*)d_in[2], (const float*)d_in[5], (const float*)d_in[8],
                        (const float*)d_in[11], (const float*)d_in[14]};
  const float* bb[5] = {(const float*)d_in[3], (const float*)d_in[6], (const float*)d_in[9],
                        (const float*)d_in[12], (const float*)d_in[15]};
  float* out = (float*)d_out;

  float* W = (float*)d_ws;
  size_t off = 0;
  float* feat0   = W + off; off += (size_t)B_SZ * N_PTS * 4;   // stride-4 padded
  float* catbuf  = W + off; off += (size_t)8192 * CAT_C;
  int*   idxbuf  = (int*)(W + off); off += (size_t)8192 * KNN_K;
  float* aybuf   = W + off; off += (size_t)8192 * 1024;
  float* mxbuf   = W + off; off += (size_t)8192 * 256;
  float* mnbuf   = W + off; off += (size_t)8192 * 256;
  float* wcbuf   = W + off; off += (size_t)512 * 1024;
  float* sumsbin = W + off; off += (size_t)64 * 512;
  float* sums    = W + off; off += 512;
  float* parts   = W + off; off += (size_t)4 * 64 * 1024;
  float* x2buf   = W + off; off += 8192;
  bf16*  packH   = (bf16*)(W + off); off += (size_t)8192 * 128 / 2;   // 2MB
  bf16*  packM   = (bf16*)(W + off); off += (size_t)8192 * 128 / 2;   // 2MB
  bf16*  packL   = (bf16*)(W + off); off += (size_t)8192 * 128 / 2;   // 2MB

  transpose_x<<<(B_SZ * 4 * N_PTS + 255) / 256, 256, 0, stream>>>(x, feat0);
  hipMemsetAsync(sumsbin, 0, (size_t)64 * 512 * sizeof(float), stream);  // first-launch poison clear

  const int Cs[4] = {4, 64, 64, 128};   // layer-0 padded to 4 (pad=0, values unchanged)
  const int Ks[4] = {3, 64, 64, 128};   // true K for the edge GEMM
  const int Os[4] = {64, 64, 128, 256};
  const int osh[4] = {6, 6, 7, 8};
  const int segin[4] = {0, 0, 64, 128};
  const int segout[4] = {0, 64, 128, 256};

  for (int l = 0; l < 4; ++l) {
    int C = Cs[l], O = Os[l], twoO = 2 * O;
    const float* featin = (l == 0) ? feat0 : (catbuf + segin[l]);
    int lda = (l == 0) ? 4 : CAT_C;
    int nks = (C + 31) / 32;            // 1,2,2,4

    if (l == 0) {   // layers 1-3: packs + x2 already written by previous finalize_edge
      xnorm_kernel<<<32, 256, 0, stream>>>(featin, lda, C, x2buf);
      split_pack<<<512, 256, 0, stream>>>(featin, lda, C, packH, packM, packL);
    }
    knn_mfma<<<512, 1024, 0, stream>>>(packH, packM, packL, x2buf, nks, idxbuf);

    if (l == 0) {
      build_wc<<<(Ks[l] * twoO + 255) / 256, 256, 0, stream>>>(w[l], Ks[l], O, wcbuf);
      gemm_kernel<<<dim3(twoO / 64, 8192 / 64), 256, 0, stream>>>(featin, lda, wcbuf, aybuf,
                                                                  8192, twoO, Ks[l]);
    } else {
      gemm_split<<<dim3(twoO / 128, 8192 / 128), 256, 0, stream>>>(featin, lda, w[l], O,
                                                                   aybuf, twoO, Ks[l]);
    }
    if (O == 256)
      aggregate_t<4><<<2048, 256, 0, stream>>>(aybuf, idxbuf, O, mxbuf, mnbuf, sumsbin);
    else if (O == 128)
      aggregate_t<2><<<2048, 256, 0, stream>>>(aybuf, idxbuf, O, mxbuf, mnbuf, sumsbin);
    else
      aggregate_t<1><<<2048, 256, 0, stream>>>(aybuf, idxbuf, O, mxbuf, mnbuf, sumsbin);
    reduce_bins<<<1, 256, 0, stream>>>(sumsbin, sums, O);
    finalize_edge<<<(8192 * O) / 256, 256, 0, stream>>>(mxbuf, mnbuf, sums, gg[l], bb[l],
                                                        osh[l], catbuf + segout[l],
                                                        1.0f / (8192.0f * KNN_K),
                                                        packH, packM, packL, x2buf,
                                                        (l < 3) ? 1 : 0);
  }

  // layer 5: h5 = cat * w5^T via split-bf16 MFMA with fused per-tile reduction
  gemm_split_red<<<dim3(1024 / 128, 8192 / 128), 256, 0, stream>>>(catbuf, CAT_C, w[4], 512,
                                                                   parts, 512);
  finalize5_fused<<<8192 / 256, 256, 0, stream>>>(parts, gg[4], bb[4], out);
}